// Round 4
// baseline (1698.716 us; speedup 1.0000x reference)
//
#include <hip/hip_runtime.h>
#include <hip/hip_bf16.h>

// Problem constants (fixed by reference)
#define LSEQ   1024
#define BATCH  8
#define MTOT   8192      // B*L
#define DMODEL 512
#define EDIM   1024      // EXPAND*D_MODEL
#define DSTATE 16
#define DTRANK 32
#define DFF    1024
#define EPSLN  1e-5f

// ---------------------------------------------------------------------------
// Generic fp32 GEMM: C[M,N] = act(A[M,K] @ W[N,K]^T + bias)
// A row-major with row stride lda; W row-major (ldw == K); C row stride ldc.
// Tile 64x64, BK=32, 256 threads, 4x4 outputs/thread.
// flip!=0: A row r is remapped to (b, L-1-t) — used for the backward direction
// act: 0 none, 1 relu, 2 softplus
// ---------------------------------------------------------------------------
__device__ __forceinline__ float softplusf(float v) {
    return fmaxf(v, 0.f) + log1pf(__expf(-fabsf(v)));
}

#define LDST 76  // LDS row stride (floats): mult of 4 (b128-aligned), 4-way max conflict

__global__ __launch_bounds__(256) void gemm_f32(
    const float* __restrict__ A, int lda,
    const float* __restrict__ W,
    const float* __restrict__ bias,
    float* __restrict__ C, int ldc,
    int N, int K, int act, int flip)
{
    __shared__ float As[32][LDST];
    __shared__ float Ws[32][LDST];

    const int tid = threadIdx.x;
    const int tx = tid & 15;          // n-subtile
    const int ty = tid >> 4;          // m-subtile
    const int rowbase = blockIdx.y * 64;
    const int colbase = blockIdx.x * 64;

    float c[4][4] = {};

    for (int k0 = 0; k0 < K; k0 += 32) {
#pragma unroll
        for (int it = 0; it < 2; ++it) {
            int q  = tid + it * 256;
            int r  = q >> 3;
            int kc = (q & 7) << 2;
            int ar = rowbase + r;
            if (flip) ar = (ar & ~(LSEQ - 1)) + (LSEQ - 1 - (ar & (LSEQ - 1)));
            float4 av = *(const float4*)&A[(size_t)ar * lda + k0 + kc];
            As[kc + 0][r] = av.x; As[kc + 1][r] = av.y;
            As[kc + 2][r] = av.z; As[kc + 3][r] = av.w;
            int wr = colbase + r;
            float4 wv = *(const float4*)&W[(size_t)wr * K + k0 + kc];
            Ws[kc + 0][r] = wv.x; Ws[kc + 1][r] = wv.y;
            Ws[kc + 2][r] = wv.z; Ws[kc + 3][r] = wv.w;
        }
        __syncthreads();
#pragma unroll
        for (int k = 0; k < 32; ++k) {
            float4 a4 = *(const float4*)&As[k][ty << 2];
            float4 w4 = *(const float4*)&Ws[k][tx << 2];
            float av[4] = {a4.x, a4.y, a4.z, a4.w};
            float wv[4] = {w4.x, w4.y, w4.z, w4.w};
#pragma unroll
            for (int i = 0; i < 4; ++i)
#pragma unroll
                for (int j = 0; j < 4; ++j)
                    c[i][j] = fmaf(av[i], wv[j], c[i][j]);
        }
        __syncthreads();
    }

    float4 bv = make_float4(0.f, 0.f, 0.f, 0.f);
    if (bias) bv = *(const float4*)&bias[colbase + (tx << 2)];
#pragma unroll
    for (int i = 0; i < 4; ++i) {
        float o[4] = {c[i][0] + bv.x, c[i][1] + bv.y, c[i][2] + bv.z, c[i][3] + bv.w};
        if (act == 1) {
#pragma unroll
            for (int j = 0; j < 4; ++j) o[j] = fmaxf(o[j], 0.f);
        } else if (act == 2) {
#pragma unroll
            for (int j = 0; j < 4; ++j) o[j] = softplusf(o[j]);
        }
        float4 ov = make_float4(o[0], o[1], o[2], o[3]);
        *(float4*)&C[(size_t)(rowbase + (ty << 2) + i) * ldc + colbase + (tx << 2)] = ov;
    }
}

// ---------------------------------------------------------------------------
// Depthwise causal conv (D_CONV=4) + bias + silu.
// xi lives in xz columns [0,1024), row stride 2048. Output xc[M,1024].
// ---------------------------------------------------------------------------
__global__ __launch_bounds__(256) void conv_silu(
    const float* __restrict__ xz, const float* __restrict__ cw,
    const float* __restrict__ cb, float* __restrict__ xc)
{
    int e = blockIdx.x * 256 + threadIdx.x;   // 0..1023
    int m = blockIdx.y;                       // 0..8191
    int t = m & (LSEQ - 1);

    float4 w = *(const float4*)&cw[e * 4];
    float wk[4] = {w.x, w.y, w.z, w.w};
    float acc = cb[e];
#pragma unroll
    for (int k = 0; k < 4; ++k) {
        int tt = t - 3 + k;
        if (tt >= 0)
            acc = fmaf(wk[k], xz[(size_t)(m - 3 + k) * 2048 + e], acc);
    }
    float s = 1.f / (1.f + __expf(-acc));
    xc[(size_t)m * EDIM + e] = acc * s;
}

// ---------------------------------------------------------------------------
// Selective scan + gating, fused.
// Block: 256 threads = 4 waves; wave = 4 groups of 16 lanes (lane n = state).
// Block covers 16 channels e of one batch b. Chunked LDS staging, CH=64 steps.
// Writes gated output g into xz columns [0,1024) (xi slot, no longer needed).
// ---------------------------------------------------------------------------
__global__ __launch_bounds__(256) void scan_kernel(
    const float* __restrict__ delta, const float* __restrict__ xc,
    const float* __restrict__ dbc, const float* __restrict__ Alog,
    const float* __restrict__ Dvec, float* __restrict__ xzbuf)
{
    __shared__ float sd[64][16], sx[64][16], sz[64][16], sB[64][16], sC[64][16];

    const int b  = blockIdx.y;
    const int e0 = blockIdx.x * 16;
    const int tid  = threadIdx.x;
    const int lane = tid & 63;
    const int n    = lane & 15;
    const int wave = tid >> 6;
    const int egl  = wave * 4 + (lane >> 4);  // local channel 0..15
    const int e    = e0 + egl;

    const float Aen = -__expf(Alog[e * DSTATE + n]);
    const float Dv  = Dvec[e];
    float h = 0.f;

    const int tld = tid >> 2;
    const int q   = (tid & 3) << 2;

    for (int t0 = 0; t0 < LSEQ; t0 += 64) {
        size_t grow = (size_t)(b * LSEQ + t0 + tld);
        *(float4*)&sd[tld][q] = *(const float4*)&delta[grow * EDIM + e0 + q];
        *(float4*)&sx[tld][q] = *(const float4*)&xc[grow * EDIM + e0 + q];
        *(float4*)&sz[tld][q] = *(const float4*)&xzbuf[grow * 2048 + 1024 + e0 + q];
        *(float4*)&sB[tld][q] = *(const float4*)&dbc[grow * 64 + 32 + q];
        *(float4*)&sC[tld][q] = *(const float4*)&dbc[grow * 64 + 48 + q];
        __syncthreads();

        for (int t = 0; t < 64; ++t) {
            float d   = sd[t][egl];
            float xcv = sx[t][egl];
            float Bv  = sB[t][n];
            float Cv  = sC[t][n];
            float da  = __expf(d * Aen);
            h = fmaf(da, h, d * Bv * xcv);
            float p = h * Cv;
            p += __shfl_xor(p, 1);
            p += __shfl_xor(p, 2);
            p += __shfl_xor(p, 4);
            p += __shfl_xor(p, 8);
            if (n == 0) {
                float zv  = sz[t][egl];
                float y   = p + Dv * xcv;
                float sig = 1.f / (1.f + __expf(-zv));
                float zz  = zv * sig;
                xzbuf[(size_t)(b * LSEQ + t0 + t) * 2048 + e] = fmaf(zz, y - xcv, xcv);
            }
        }
        __syncthreads();
    }
}

// ---------------------------------------------------------------------------
// Block reduction helper (sum of 4 floats across 256 threads)
// ---------------------------------------------------------------------------
__device__ __forceinline__ void block_reduce4(float4& s, float4* red, int tid)
{
#pragma unroll
    for (int off = 1; off < 64; off <<= 1) {
        s.x += __shfl_xor(s.x, off);
        s.y += __shfl_xor(s.y, off);
        s.z += __shfl_xor(s.z, off);
        s.w += __shfl_xor(s.w, off);
    }
    if ((tid & 63) == 0) red[tid >> 6] = s;
    __syncthreads();
    float4 a = red[0], b = red[1], c = red[2], d = red[3];
    s.x = a.x + b.x + c.x + d.x;
    s.y = a.y + b.y + c.y + d.y;
    s.z = a.z + b.z + c.z + d.z;
    s.w = a.w + b.w + c.w + d.w;
}

// Dual layernorm + combine: xs = LN(yf+x)*g1+b1 + LN(yb+x)*g2+b2
__global__ __launch_bounds__(256) void ln_combine(
    const float* __restrict__ yproj, const float* __restrict__ x,
    const float* __restrict__ g1, const float* __restrict__ b1,
    const float* __restrict__ g2, const float* __restrict__ b2,
    float* __restrict__ xs)
{
    __shared__ float4 red[4];
    const int row = blockIdx.x, tid = threadIdx.x;
    const float* yf = yproj + (size_t)row * DMODEL;
    const float* yb = yproj + (size_t)(MTOT + row) * DMODEL;
    const float* xr = x + (size_t)row * DMODEL;

    float vf[2], vb[2];
#pragma unroll
    for (int j = 0; j < 2; ++j) {
        int i = tid + j * 256;
        float xi = xr[i];
        vf[j] = yf[i] + xi;
        vb[j] = yb[i] + xi;
    }
    float4 s = make_float4(vf[0] + vf[1], vf[0] * vf[0] + vf[1] * vf[1],
                           vb[0] + vb[1], vb[0] * vb[0] + vb[1] * vb[1]);
    block_reduce4(s, red, tid);
    const float inv = 1.f / DMODEL;
    float mf = s.x * inv, mb = s.z * inv;
    float rf = rsqrtf(s.y * inv - mf * mf + EPSLN);
    float rb = rsqrtf(s.w * inv - mb * mb + EPSLN);
#pragma unroll
    for (int j = 0; j < 2; ++j) {
        int i = tid + j * 256;
        float a  = (vf[j] - mf) * rf * g1[i] + b1[i];
        float bb = (vb[j] - mb) * rb * g2[i] + b2[i];
        xs[(size_t)row * DMODEL + i] = a + bb;
    }
}

// Final layernorm: out = LN(h2 + xs)*g3 + b3
__global__ __launch_bounds__(256) void ln_final(
    const float* __restrict__ h2, const float* __restrict__ xs,
    const float* __restrict__ g3, const float* __restrict__ b3,
    float* __restrict__ out)
{
    __shared__ float4 red[4];
    const int row = blockIdx.x, tid = threadIdx.x;
    float v[2];
#pragma unroll
    for (int j = 0; j < 2; ++j) {
        int i = tid + j * 256;
        v[j] = h2[(size_t)row * DMODEL + i] + xs[(size_t)row * DMODEL + i];
    }
    float4 s = make_float4(v[0] + v[1], v[0] * v[0] + v[1] * v[1], 0.f, 0.f);
    block_reduce4(s, red, tid);
    const float inv = 1.f / DMODEL;
    float m  = s.x * inv;
    float rs = rsqrtf(s.y * inv - m * m + EPSLN);
#pragma unroll
    for (int j = 0; j < 2; ++j) {
        int i = tid + j * 256;
        out[(size_t)row * DMODEL + i] = (v[j] - m) * rs * g3[i] + b3[i];
    }
}

// ---------------------------------------------------------------------------
extern "C" void kernel_launch(void* const* d_in, const int* in_sizes, int n_in,
                              void* d_out, int out_size, void* d_ws, size_t ws_size,
                              hipStream_t stream)
{
    (void)in_sizes; (void)n_in; (void)out_size;

    const float* x    = (const float*)d_in[28];
    const float* n1g  = (const float*)d_in[18];
    const float* n1b  = (const float*)d_in[19];
    const float* n2g  = (const float*)d_in[20];
    const float* n2b  = (const float*)d_in[21];
    const float* n3g  = (const float*)d_in[22];
    const float* n3b  = (const float*)d_in[23];
    const float* ff1w = (const float*)d_in[24];
    const float* ff1b = (const float*)d_in[25];
    const float* ff2w = (const float*)d_in[26];
    const float* ff2b = (const float*)d_in[27];

    // Workspace layout (floats). Total requirement:
    //   xz 16M + xc 8M + delta 8M + dbc 0.5M + yproj 8M + xs 4M = 44.5M floats
    //   = 178 MB. h1 reuses delta (dead after last scan); h2 reuses xc.
    const size_t need_floats =
        (size_t)MTOT * 2048 + (size_t)MTOT * 1024 + (size_t)MTOT * 1024 +
        (size_t)MTOT * 64 + (size_t)2 * MTOT * 512 + (size_t)MTOT * 512;
    if (ws_size < need_floats * sizeof(float)) {
        // Insufficient scratch: skip launches -> clean validation failure
        // instead of OOB writes that could wedge the GPU.
        return;
    }

    float* ws    = (float*)d_ws;
    float* xz    = ws;                          // MTOT*2048 (xi|z; scan overwrites xi with g)
    float* xc    = xz    + (size_t)MTOT * 2048; // MTOT*1024
    float* delta = xc    + (size_t)MTOT * 1024; // MTOT*1024
    float* dbc   = delta + (size_t)MTOT * 1024; // MTOT*64
    float* yproj = dbc   + (size_t)MTOT * 64;   // 2*MTOT*512
    float* xs    = yproj + (size_t)2 * MTOT * 512; // MTOT*512
    float* h1    = delta;                       // reuse delta after both dirs done
    float* h2    = xc;                          // reuse xc after both dirs done

    for (int dir = 0; dir < 2; ++dir) {
        const float* in_w  = (const float*)d_in[dir * 9 + 0];
        const float* cw    = (const float*)d_in[dir * 9 + 1];
        const float* cb    = (const float*)d_in[dir * 9 + 2];
        const float* xpw   = (const float*)d_in[dir * 9 + 3];
        const float* dtw   = (const float*)d_in[dir * 9 + 4];
        const float* dtb   = (const float*)d_in[dir * 9 + 5];
        const float* Alog  = (const float*)d_in[dir * 9 + 6];
        const float* Dvec  = (const float*)d_in[dir * 9 + 7];
        const float* outw  = (const float*)d_in[dir * 9 + 8];

        // xz = x(d) @ in_w^T   (M=8192, N=2048, K=512)
        gemm_f32<<<dim3(2048 / 64, MTOT / 64), 256, 0, stream>>>(
            x, DMODEL, in_w, nullptr, xz, 2048, 2048, DMODEL, 0, dir);
        // xc = silu(depthwise_conv(xi) + cb)
        conv_silu<<<dim3(EDIM / 256, MTOT), 256, 0, stream>>>(xz, cw, cb, xc);
        // dbc = xc @ xproj^T   (N=64, K=1024)
        gemm_f32<<<dim3(64 / 64, MTOT / 64), 256, 0, stream>>>(
            xc, EDIM, xpw, nullptr, dbc, 64, 64, EDIM, 0, 0);
        // delta = softplus(dbc[:, :32] @ dt_w^T + dt_b)   (N=1024, K=32)
        gemm_f32<<<dim3(EDIM / 64, MTOT / 64), 256, 0, stream>>>(
            dbc, 64, dtw, dtb, delta, EDIM, EDIM, DTRANK, 2, 0);
        // selective scan + gating -> g written into xz[:, 0:1024)
        scan_kernel<<<dim3(EDIM / 16, BATCH), 256, 0, stream>>>(
            delta, xc, dbc, Alog, Dvec, xz);
        // yproj[dir] = g @ out_w^T   (N=512, K=1024)
        gemm_f32<<<dim3(DMODEL / 64, MTOT / 64), 256, 0, stream>>>(
            xz, 2048, outw, nullptr, yproj + (size_t)dir * MTOT * DMODEL, DMODEL,
            DMODEL, EDIM, 0, 0);
    }

    // xs = LN(yf+x)*g1+b1 + LN(yb+x)*g2+b2
    ln_combine<<<MTOT, 256, 0, stream>>>(yproj, x, n1g, n1b, n2g, n2b, xs);
    // h1 = relu(xs @ ff1^T + ff1b)   (N=1024, K=512)
    gemm_f32<<<dim3(DFF / 64, MTOT / 64), 256, 0, stream>>>(
        xs, DMODEL, ff1w, ff1b, h1, DFF, DFF, DMODEL, 1, 0);
    // h2 = h1 @ ff2^T + ff2b        (N=512, K=1024)
    gemm_f32<<<dim3(DMODEL / 64, MTOT / 64), 256, 0, stream>>>(
        h1, DFF, ff2w, ff2b, h2, DMODEL, DMODEL, DFF, 0, 0);
    // out = LN(h2 + xs)*g3 + b3
    ln_final<<<MTOT, 256, 0, stream>>>(h2, xs, n3g, n3b, (float*)d_out);
}

// Round 5
// 950.556 us; speedup vs baseline: 1.7871x; 1.7871x over previous
//
#include <hip/hip_runtime.h>
#include <hip/hip_bf16.h>

// Problem constants (fixed by reference)
#define LSEQ   1024
#define BATCH  8
#define MTOT   8192      // B*L
#define DMODEL 512
#define EDIM   1024      // EXPAND*D_MODEL
#define DSTATE 16
#define DTRANK 32
#define DFF    1024
#define EPSLN  1e-5f

typedef __attribute__((ext_vector_type(8))) short bf16x8;
typedef __attribute__((ext_vector_type(4))) float f32x4;

__device__ __forceinline__ unsigned short f2bf(float f) {
    __hip_bfloat16 h = __float2bfloat16(f);   // RNE
    unsigned short u;
    __builtin_memcpy(&u, &h, 2);
    return u;
}

__device__ __forceinline__ float softplusf(float v) {
    return fmaxf(v, 0.f) + log1pf(__expf(-fabsf(v)));
}

// ---------------------------------------------------------------------------
// bf16 MFMA GEMM: C[M,N] = act(A[M,K] @ W[N,K]^T + bias)
// Tile 128x128, 256 threads = 4 waves (2x2), each wave 64x64 via 4x4 16x16x32
// MFMA fragments. A: f32 (cast in staging) or bf16 per a_f32. W: always f32,
// cast in staging. C: f32 or bf16 per c_bf16. flip: remap A rows (b, L-1-t).
// act: 0 none, 1 relu. M,N multiples of 128; K multiple of 32.
// Fragment layouts (m89/m93-verified): A/B lane l: row/col = l&15,
// k = (l>>4)*8 + j (j=0..7). C/D lane l: col = l&15, row = (l>>4)*4 + reg.
// LDS row stride 56 ushorts = 112 B: 16B-aligned, 2-way bank alias (free).
// ---------------------------------------------------------------------------
#define BSTRIDE 56

__global__ __launch_bounds__(256) void gemm_bf16(
    const void* __restrict__ Ap, int lda, int a_f32,
    const float* __restrict__ Wf,
    const float* __restrict__ bias,
    void* __restrict__ Cp, int ldc, int c_bf16,
    int K, int act, int flip)
{
    __shared__ unsigned short As[128][BSTRIDE];
    __shared__ unsigned short Ws[128][BSTRIDE];

    const int tid = threadIdx.x;
    const int rowbase = blockIdx.y * 128;
    const int colbase = blockIdx.x * 128;
    const int wave = tid >> 6, lane = tid & 63;
    const int wm = wave >> 1, wn = wave & 1;
    const int lr = lane & 15;
    const int lk = (lane >> 4) << 3;      // k-offset 0,8,16,24

    f32x4 acc[4][4];
#pragma unroll
    for (int i = 0; i < 4; ++i)
#pragma unroll
        for (int j = 0; j < 4; ++j)
            acc[i][j] = (f32x4){0.f, 0.f, 0.f, 0.f};

    for (int k0 = 0; k0 < K; k0 += 32) {
        __syncthreads();   // previous iteration's LDS reads complete
#pragma unroll
        for (int it = 0; it < 2; ++it) {
            int idx = tid + it * 256;     // 0..511
            int r = idx >> 2;             // 0..127
            int c = (idx & 3) << 3;       // 0,8,16,24
            // A tile
            {
                int ar = rowbase + r;
                if (flip) ar = (ar & ~(LSEQ - 1)) + (LSEQ - 1 - (ar & (LSEQ - 1)));
                unsigned short av[8];
                if (a_f32) {
                    const float* A = (const float*)Ap;
                    float4 f0 = *(const float4*)&A[(size_t)ar * lda + k0 + c];
                    float4 f1 = *(const float4*)&A[(size_t)ar * lda + k0 + c + 4];
                    av[0] = f2bf(f0.x); av[1] = f2bf(f0.y);
                    av[2] = f2bf(f0.z); av[3] = f2bf(f0.w);
                    av[4] = f2bf(f1.x); av[5] = f2bf(f1.y);
                    av[6] = f2bf(f1.z); av[7] = f2bf(f1.w);
                } else {
                    const unsigned short* A = (const unsigned short*)Ap;
                    *(uint4*)av = *(const uint4*)&A[(size_t)ar * lda + k0 + c];
                }
                *(uint4*)&As[r][c] = *(uint4*)av;
            }
            // W tile
            {
                int wr = colbase + r;
                unsigned short wv[8];
                float4 f0 = *(const float4*)&Wf[(size_t)wr * K + k0 + c];
                float4 f1 = *(const float4*)&Wf[(size_t)wr * K + k0 + c + 4];
                wv[0] = f2bf(f0.x); wv[1] = f2bf(f0.y);
                wv[2] = f2bf(f0.z); wv[3] = f2bf(f0.w);
                wv[4] = f2bf(f1.x); wv[5] = f2bf(f1.y);
                wv[6] = f2bf(f1.z); wv[7] = f2bf(f1.w);
                *(uint4*)&Ws[r][c] = *(uint4*)wv;
            }
        }
        __syncthreads();

        bf16x8 af[4], bf[4];
#pragma unroll
        for (int i = 0; i < 4; ++i)
            af[i] = *(const bf16x8*)&As[wm * 64 + i * 16 + lr][lk];
#pragma unroll
        for (int j = 0; j < 4; ++j)
            bf[j] = *(const bf16x8*)&Ws[wn * 64 + j * 16 + lr][lk];
#pragma unroll
        for (int i = 0; i < 4; ++i)
#pragma unroll
            for (int j = 0; j < 4; ++j)
                acc[i][j] = __builtin_amdgcn_mfma_f32_16x16x32_bf16(
                    af[i], bf[j], acc[i][j], 0, 0, 0);
    }

    const int crow0 = rowbase + wm * 64 + ((lane >> 4) << 2);
    const int ccol0 = colbase + wn * 64 + lr;
#pragma unroll
    for (int j = 0; j < 4; ++j) {
        int col = ccol0 + j * 16;
        float bv = bias ? bias[col] : 0.f;
#pragma unroll
        for (int i = 0; i < 4; ++i) {
#pragma unroll
            for (int r = 0; r < 4; ++r) {
                int row = crow0 + i * 16 + r;
                float v = acc[i][j][r] + bv;
                if (act == 1) v = fmaxf(v, 0.f);
                if (c_bf16)
                    ((unsigned short*)Cp)[(size_t)row * ldc + col] = f2bf(v);
                else
                    ((float*)Cp)[(size_t)row * ldc + col] = v;
            }
        }
    }
}

// ---------------------------------------------------------------------------
// fp32 GEMM (kept for small shapes: xproj N=64, dt K=32)
// ---------------------------------------------------------------------------
#define LDST 76

__global__ __launch_bounds__(256) void gemm_f32(
    const float* __restrict__ A, int lda,
    const float* __restrict__ W,
    const float* __restrict__ bias,
    float* __restrict__ C, int ldc,
    int N, int K, int act, int flip)
{
    __shared__ float As[32][LDST];
    __shared__ float Ws[32][LDST];

    const int tid = threadIdx.x;
    const int tx = tid & 15;
    const int ty = tid >> 4;
    const int rowbase = blockIdx.y * 64;
    const int colbase = blockIdx.x * 64;

    float c[4][4] = {};

    for (int k0 = 0; k0 < K; k0 += 32) {
#pragma unroll
        for (int it = 0; it < 2; ++it) {
            int q  = tid + it * 256;
            int r  = q >> 3;
            int kc = (q & 7) << 2;
            int ar = rowbase + r;
            if (flip) ar = (ar & ~(LSEQ - 1)) + (LSEQ - 1 - (ar & (LSEQ - 1)));
            float4 av = *(const float4*)&A[(size_t)ar * lda + k0 + kc];
            As[kc + 0][r] = av.x; As[kc + 1][r] = av.y;
            As[kc + 2][r] = av.z; As[kc + 3][r] = av.w;
            int wr = colbase + r;
            float4 wv = *(const float4*)&W[(size_t)wr * K + k0 + kc];
            Ws[kc + 0][r] = wv.x; Ws[kc + 1][r] = wv.y;
            Ws[kc + 2][r] = wv.z; Ws[kc + 3][r] = wv.w;
        }
        __syncthreads();
#pragma unroll
        for (int k = 0; k < 32; ++k) {
            float4 a4 = *(const float4*)&As[k][ty << 2];
            float4 w4 = *(const float4*)&Ws[k][tx << 2];
            float av[4] = {a4.x, a4.y, a4.z, a4.w};
            float wv[4] = {w4.x, w4.y, w4.z, w4.w};
#pragma unroll
            for (int i = 0; i < 4; ++i)
#pragma unroll
                for (int j = 0; j < 4; ++j)
                    c[i][j] = fmaf(av[i], wv[j], c[i][j]);
        }
        __syncthreads();
    }

    float4 bv = make_float4(0.f, 0.f, 0.f, 0.f);
    if (bias) bv = *(const float4*)&bias[colbase + (tx << 2)];
#pragma unroll
    for (int i = 0; i < 4; ++i) {
        float o[4] = {c[i][0] + bv.x, c[i][1] + bv.y, c[i][2] + bv.z, c[i][3] + bv.w};
        if (act == 2) {
#pragma unroll
            for (int j = 0; j < 4; ++j) o[j] = softplusf(o[j]);
        }
        float4 ov = make_float4(o[0], o[1], o[2], o[3]);
        *(float4*)&C[(size_t)(rowbase + (ty << 2) + i) * ldc + colbase + (tx << 2)] = ov;
    }
}

// ---------------------------------------------------------------------------
// Depthwise causal conv (D_CONV=4) + bias + silu.
// ---------------------------------------------------------------------------
__global__ __launch_bounds__(256) void conv_silu(
    const float* __restrict__ xz, const float* __restrict__ cw,
    const float* __restrict__ cb, float* __restrict__ xc)
{
    int e = blockIdx.x * 256 + threadIdx.x;
    int m = blockIdx.y;
    int t = m & (LSEQ - 1);

    float4 w = *(const float4*)&cw[e * 4];
    float wk[4] = {w.x, w.y, w.z, w.w};
    float acc = cb[e];
#pragma unroll
    for (int k = 0; k < 4; ++k) {
        int tt = t - 3 + k;
        if (tt >= 0)
            acc = fmaf(wk[k], xz[(size_t)(m - 3 + k) * 2048 + e], acc);
    }
    float s = 1.f / (1.f + __expf(-acc));
    xc[(size_t)m * EDIM + e] = acc * s;
}

// ---------------------------------------------------------------------------
// Selective scan + gating. Unroll-4 inner: h-chain stays serial (cheap FMA),
// the 4 shfl-reduction trees are independent (ILP hides DS latency).
// Register prefetch of next chunk's global loads hides HBM/L3 latency under
// the inner loop. Writes gated g into xz cols [0,1024).
// ---------------------------------------------------------------------------
__global__ __launch_bounds__(256) void scan_kernel(
    const float* __restrict__ delta, const float* __restrict__ xc,
    const float* __restrict__ dbc, const float* __restrict__ Alog,
    const float* __restrict__ Dvec, float* __restrict__ xzbuf)
{
    __shared__ float sd[64][16], sx[64][16], sz[64][16], sB[64][16], sC[64][16];

    const int b  = blockIdx.y;
    const int e0 = blockIdx.x * 16;
    const int tid  = threadIdx.x;
    const int lane = tid & 63;
    const int n    = lane & 15;
    const int wave = tid >> 6;
    const int egl  = wave * 4 + (lane >> 4);
    const int e    = e0 + egl;

    const float Aen = -__expf(Alog[e * DSTATE + n]);
    const float Dv  = Dvec[e];
    float h = 0.f;

    const int tld = tid >> 2;
    const int q   = (tid & 3) << 2;

    float4 rd, rx, rz, rB, rC;
    {
        size_t grow = (size_t)(b * LSEQ + tld);
        rd = *(const float4*)&delta[grow * EDIM + e0 + q];
        rx = *(const float4*)&xc[grow * EDIM + e0 + q];
        rz = *(const float4*)&xzbuf[grow * 2048 + 1024 + e0 + q];
        rB = *(const float4*)&dbc[grow * 64 + 32 + q];
        rC = *(const float4*)&dbc[grow * 64 + 48 + q];
    }

    for (int t0 = 0; t0 < LSEQ; t0 += 64) {
        __syncthreads();   // previous chunk's LDS readers done
        *(float4*)&sd[tld][q] = rd;
        *(float4*)&sx[tld][q] = rx;
        *(float4*)&sz[tld][q] = rz;
        *(float4*)&sB[tld][q] = rB;
        *(float4*)&sC[tld][q] = rC;
        __syncthreads();

        if (t0 + 64 < LSEQ) {   // prefetch next chunk (consumed next iter)
            size_t grow = (size_t)(b * LSEQ + t0 + 64 + tld);
            rd = *(const float4*)&delta[grow * EDIM + e0 + q];
            rx = *(const float4*)&xc[grow * EDIM + e0 + q];
            rz = *(const float4*)&xzbuf[grow * 2048 + 1024 + e0 + q];
            rB = *(const float4*)&dbc[grow * 64 + 32 + q];
            rC = *(const float4*)&dbc[grow * 64 + 48 + q];
        }

        for (int tt = 0; tt < 64; tt += 4) {
            float p[4];
#pragma unroll
            for (int u = 0; u < 4; ++u) {
                int t = tt + u;
                float d   = sd[t][egl];
                float xcv = sx[t][egl];
                float da  = __expf(d * Aen);
                h = fmaf(da, h, d * sB[t][n] * xcv);
                p[u] = h * sC[t][n];
            }
#pragma unroll
            for (int off = 1; off < 16; off <<= 1) {
                p[0] += __shfl_xor(p[0], off);
                p[1] += __shfl_xor(p[1], off);
                p[2] += __shfl_xor(p[2], off);
                p[3] += __shfl_xor(p[3], off);
            }
            if (n == 0) {
#pragma unroll
                for (int u = 0; u < 4; ++u) {
                    int t = tt + u;
                    float xcv = sx[t][egl];
                    float zv  = sz[t][egl];
                    float y   = p[u] + Dv * xcv;
                    float sig = 1.f / (1.f + __expf(-zv));
                    float zz  = zv * sig;
                    xzbuf[(size_t)(b * LSEQ + t0 + t) * 2048 + e] =
                        fmaf(zz, y - xcv, xcv);
                }
            }
        }
    }
}

// ---------------------------------------------------------------------------
__device__ __forceinline__ void block_reduce4(float4& s, float4* red, int tid)
{
#pragma unroll
    for (int off = 1; off < 64; off <<= 1) {
        s.x += __shfl_xor(s.x, off);
        s.y += __shfl_xor(s.y, off);
        s.z += __shfl_xor(s.z, off);
        s.w += __shfl_xor(s.w, off);
    }
    if ((tid & 63) == 0) red[tid >> 6] = s;
    __syncthreads();
    float4 a = red[0], b = red[1], c = red[2], d = red[3];
    s.x = a.x + b.x + c.x + d.x;
    s.y = a.y + b.y + c.y + d.y;
    s.z = a.z + b.z + c.z + d.z;
    s.w = a.w + b.w + c.w + d.w;
}

__global__ __launch_bounds__(256) void ln_combine(
    const float* __restrict__ yproj, const float* __restrict__ x,
    const float* __restrict__ g1, const float* __restrict__ b1,
    const float* __restrict__ g2, const float* __restrict__ b2,
    float* __restrict__ xs)
{
    __shared__ float4 red[4];
    const int row = blockIdx.x, tid = threadIdx.x;
    const float* yf = yproj + (size_t)row * DMODEL;
    const float* yb = yproj + (size_t)(MTOT + row) * DMODEL;
    const float* xr = x + (size_t)row * DMODEL;

    float vf[2], vb[2];
#pragma unroll
    for (int j = 0; j < 2; ++j) {
        int i = tid + j * 256;
        float xi = xr[i];
        vf[j] = yf[i] + xi;
        vb[j] = yb[i] + xi;
    }
    float4 s = make_float4(vf[0] + vf[1], vf[0] * vf[0] + vf[1] * vf[1],
                           vb[0] + vb[1], vb[0] * vb[0] + vb[1] * vb[1]);
    block_reduce4(s, red, tid);
    const float inv = 1.f / DMODEL;
    float mf = s.x * inv, mb = s.z * inv;
    float rf = rsqrtf(s.y * inv - mf * mf + EPSLN);
    float rb = rsqrtf(s.w * inv - mb * mb + EPSLN);
#pragma unroll
    for (int j = 0; j < 2; ++j) {
        int i = tid + j * 256;
        float a  = (vf[j] - mf) * rf * g1[i] + b1[i];
        float bb = (vb[j] - mb) * rb * g2[i] + b2[i];
        xs[(size_t)row * DMODEL + i] = a + bb;
    }
}

__global__ __launch_bounds__(256) void ln_final(
    const float* __restrict__ h2, const float* __restrict__ xs,
    const float* __restrict__ g3, const float* __restrict__ b3,
    float* __restrict__ out)
{
    __shared__ float4 red[4];
    const int row = blockIdx.x, tid = threadIdx.x;
    float v[2];
#pragma unroll
    for (int j = 0; j < 2; ++j) {
        int i = tid + j * 256;
        v[j] = h2[(size_t)row * DMODEL + i] + xs[(size_t)row * DMODEL + i];
    }
    float4 s = make_float4(v[0] + v[1], v[0] * v[0] + v[1] * v[1], 0.f, 0.f);
    block_reduce4(s, red, tid);
    const float inv = 1.f / DMODEL;
    float m  = s.x * inv;
    float rs = rsqrtf(s.y * inv - m * m + EPSLN);
#pragma unroll
    for (int j = 0; j < 2; ++j) {
        int i = tid + j * 256;
        out[(size_t)row * DMODEL + i] = (v[j] - m) * rs * g3[i] + b3[i];
    }
}

// ---------------------------------------------------------------------------
extern "C" void kernel_launch(void* const* d_in, const int* in_sizes, int n_in,
                              void* d_out, int out_size, void* d_ws, size_t ws_size,
                              hipStream_t stream)
{
    (void)in_sizes; (void)n_in; (void)out_size;

    const float* x    = (const float*)d_in[28];
    const float* n1g  = (const float*)d_in[18];
    const float* n1b  = (const float*)d_in[19];
    const float* n2g  = (const float*)d_in[20];
    const float* n2b  = (const float*)d_in[21];
    const float* n3g  = (const float*)d_in[22];
    const float* n3b  = (const float*)d_in[23];
    const float* ff1w = (const float*)d_in[24];
    const float* ff1b = (const float*)d_in[25];
    const float* ff2w = (const float*)d_in[26];
    const float* ff2b = (const float*)d_in[27];

    // Workspace (floats): xz 16M + xc 8M + delta 8M + dbc 0.5M + yproj 8M +
    // xs 4M = 44.5M floats = 178 MB (identical to the validated round-4
    // layout). h1bf (bf16, 16MB) overlays delta (dead after both scans);
    // h2 overlays xc.
    const size_t need_floats =
        (size_t)MTOT * 2048 + (size_t)MTOT * 1024 + (size_t)MTOT * 1024 +
        (size_t)MTOT * 64 + (size_t)2 * MTOT * 512 + (size_t)MTOT * 512;
    if (ws_size < need_floats * sizeof(float)) return;

    float* ws    = (float*)d_ws;
    float* xz    = ws;                          // MTOT*2048 (xi|z; scan writes g into xi)
    float* xc    = xz    + (size_t)MTOT * 2048; // MTOT*1024
    float* delta = xc    + (size_t)MTOT * 1024; // MTOT*1024
    float* dbc   = delta + (size_t)MTOT * 1024; // MTOT*64
    float* yproj = dbc   + (size_t)MTOT * 64;   // 2*MTOT*512
    float* xs    = yproj + (size_t)2 * MTOT * 512; // MTOT*512
    unsigned short* h1bf = (unsigned short*)delta; // reuse (dead after scans)
    float* h2    = xc;                             // reuse (dead after scans)

    for (int dir = 0; dir < 2; ++dir) {
        const float* in_w  = (const float*)d_in[dir * 9 + 0];
        const float* cw    = (const float*)d_in[dir * 9 + 1];
        const float* cb    = (const float*)d_in[dir * 9 + 2];
        const float* xpw   = (const float*)d_in[dir * 9 + 3];
        const float* dtw   = (const float*)d_in[dir * 9 + 4];
        const float* dtb   = (const float*)d_in[dir * 9 + 5];
        const float* Alog  = (const float*)d_in[dir * 9 + 6];
        const float* Dvec  = (const float*)d_in[dir * 9 + 7];
        const float* outw  = (const float*)d_in[dir * 9 + 8];

        // xz = x(d) @ in_w^T   (M=8192, N=2048, K=512)  [bf16 MFMA]
        gemm_bf16<<<dim3(2048 / 128, MTOT / 128), 256, 0, stream>>>(
            x, DMODEL, 1, in_w, nullptr, xz, 2048, 0, DMODEL, 0, dir);
        // xc = silu(depthwise_conv(xi) + cb)
        conv_silu<<<dim3(EDIM / 256, MTOT), 256, 0, stream>>>(xz, cw, cb, xc);
        // dbc = xc @ xproj^T   (N=64, K=1024)  [fp32: N too small for 128-tile]
        gemm_f32<<<dim3(64 / 64, MTOT / 64), 256, 0, stream>>>(
            xc, EDIM, xpw, nullptr, dbc, 64, 64, EDIM, 0, 0);
        // delta = softplus(dbc[:, :32] @ dt_w^T + dt_b)   (N=1024, K=32)  [fp32]
        gemm_f32<<<dim3(EDIM / 64, MTOT / 64), 256, 0, stream>>>(
            dbc, 64, dtw, dtb, delta, EDIM, EDIM, DTRANK, 2, 0);
        // selective scan + gating -> g in xz[:, 0:1024)
        scan_kernel<<<dim3(EDIM / 16, BATCH), 256, 0, stream>>>(
            delta, xc, dbc, Alog, Dvec, xz);
        // yproj[dir] = g @ out_w^T   (N=512, K=1024)  [bf16 MFMA]
        gemm_bf16<<<dim3(512 / 128, MTOT / 128), 256, 0, stream>>>(
            xz, 2048, 1, outw, nullptr,
            yproj + (size_t)dir * MTOT * DMODEL, DMODEL, 0, EDIM, 0, 0);
    }

    // xs = LN(yf+x)*g1+b1 + LN(yb+x)*g2+b2
    ln_combine<<<MTOT, 256, 0, stream>>>(yproj, x, n1g, n1b, n2g, n2b, xs);
    // h1bf = relu(xs @ ff1^T + ff1b)  (N=1024, K=512)  [bf16 MFMA, bf16 out]
    gemm_bf16<<<dim3(DFF / 128, MTOT / 128), 256, 0, stream>>>(
        xs, DMODEL, 1, ff1w, ff1b, h1bf, DFF, 1, DMODEL, 1, 0);
    // h2 = h1bf @ ff2^T + ff2b       (N=512, K=1024)  [bf16 MFMA, bf16 A]
    gemm_bf16<<<dim3(DMODEL / 128, MTOT / 128), 256, 0, stream>>>(
        h1bf, DFF, 0, ff2w, ff2b, h2, DMODEL, 0, DFF, 0, 0);
    // out = LN(h2 + xs)*g3 + b3
    ln_final<<<MTOT, 256, 0, stream>>>(h2, xs, n3g, n3b, (float*)d_out);
}

// Round 6
// 777.074 us; speedup vs baseline: 2.1860x; 1.2232x over previous
//
#include <hip/hip_runtime.h>
#include <hip/hip_bf16.h>

// Problem constants (fixed by reference)
#define LSEQ   1024
#define BATCH  8
#define MTOT   8192      // B*L
#define DMODEL 512
#define EDIM   1024      // EXPAND*D_MODEL
#define DSTATE 16
#define DTRANK 32
#define DFF    1024
#define EPSLN  1e-5f
#define NCH    8         // scan chunks
#define CHLEN  128       // LSEQ/NCH

typedef __attribute__((ext_vector_type(8))) short bf16x8;
typedef __attribute__((ext_vector_type(4))) float f32x4;

__device__ __forceinline__ unsigned short f2bf(float f) {
    __hip_bfloat16 h = __float2bfloat16(f);   // RNE
    unsigned short u;
    __builtin_memcpy(&u, &h, 2);
    return u;
}

__device__ __forceinline__ float softplusf(float v) {
    return fmaxf(v, 0.f) + log1pf(__expf(-fabsf(v)));
}

// ---------------------------------------------------------------------------
// f32 -> bf16 cast (8 elems/thread)
// ---------------------------------------------------------------------------
__global__ __launch_bounds__(256) void cast_bf16(
    const float* __restrict__ in, unsigned short* __restrict__ out, int n8)
{
    int i = blockIdx.x * 256 + threadIdx.x;
    if (i >= n8) return;
    float4 f0 = *(const float4*)&in[(size_t)i * 8];
    float4 f1 = *(const float4*)&in[(size_t)i * 8 + 4];
    unsigned short v[8] = {f2bf(f0.x), f2bf(f0.y), f2bf(f0.z), f2bf(f0.w),
                           f2bf(f1.x), f2bf(f1.y), f2bf(f1.z), f2bf(f1.w)};
    *(uint4*)&out[(size_t)i * 8] = *(uint4*)v;
}

// ---------------------------------------------------------------------------
// bf16 MFMA GEMM: C[M,N] = act(A[M,K] @ W[N,K]^T + bias); A,W bf16, acc f32.
// Tile 128x128, 4 waves (2x2), 4x4 16x16x32 fragments per wave.
// A/B frag (lane l): row/col = l&15, k = (l>>4)*8+j. C/D: col=l&15,
// row=(l>>4)*4+reg. LDS stride 56 ushorts (112B): 16B-aligned, 2-way alias.
// ---------------------------------------------------------------------------
#define BSTRIDE 56

__global__ __launch_bounds__(256) void gemm_bf16(
    const unsigned short* __restrict__ A, int lda,
    const unsigned short* __restrict__ W,
    const float* __restrict__ bias,
    void* __restrict__ Cp, int ldc, int c_bf16,
    int K, int act, int flip)
{
    __shared__ unsigned short As[128][BSTRIDE];
    __shared__ unsigned short Ws[128][BSTRIDE];

    const int tid = threadIdx.x;
    const int rowbase = blockIdx.y * 128;
    const int colbase = blockIdx.x * 128;
    const int wave = tid >> 6, lane = tid & 63;
    const int wm = wave >> 1, wn = wave & 1;
    const int lr = lane & 15;
    const int lk = (lane >> 4) << 3;

    f32x4 acc[4][4];
#pragma unroll
    for (int i = 0; i < 4; ++i)
#pragma unroll
        for (int j = 0; j < 4; ++j)
            acc[i][j] = (f32x4){0.f, 0.f, 0.f, 0.f};

    for (int k0 = 0; k0 < K; k0 += 32) {
        __syncthreads();
#pragma unroll
        for (int it = 0; it < 2; ++it) {
            int idx = tid + it * 256;
            int r = idx >> 2;
            int c = (idx & 3) << 3;
            int ar = rowbase + r;
            if (flip) ar = (ar & ~(LSEQ - 1)) + (LSEQ - 1 - (ar & (LSEQ - 1)));
            *(uint4*)&As[r][c] = *(const uint4*)&A[(size_t)ar * lda + k0 + c];
            *(uint4*)&Ws[r][c] = *(const uint4*)&W[(size_t)(colbase + r) * K + k0 + c];
        }
        __syncthreads();

        bf16x8 af[4], bfv[4];
#pragma unroll
        for (int i = 0; i < 4; ++i)
            af[i] = *(const bf16x8*)&As[wm * 64 + i * 16 + lr][lk];
#pragma unroll
        for (int j = 0; j < 4; ++j)
            bfv[j] = *(const bf16x8*)&Ws[wn * 64 + j * 16 + lr][lk];
#pragma unroll
        for (int i = 0; i < 4; ++i)
#pragma unroll
            for (int j = 0; j < 4; ++j)
                acc[i][j] = __builtin_amdgcn_mfma_f32_16x16x32_bf16(
                    af[i], bfv[j], acc[i][j], 0, 0, 0);
    }

    const int crow0 = rowbase + wm * 64 + ((lane >> 4) << 2);
    const int ccol0 = colbase + wn * 64 + lr;
#pragma unroll
    for (int j = 0; j < 4; ++j) {
        int col = ccol0 + j * 16;
        float bv = bias ? bias[col] : 0.f;
#pragma unroll
        for (int i = 0; i < 4; ++i) {
#pragma unroll
            for (int r = 0; r < 4; ++r) {
                int row = crow0 + i * 16 + r;
                float v = acc[i][j][r] + bv;
                if (act == 1) v = fmaxf(v, 0.f);
                if (c_bf16)
                    ((unsigned short*)Cp)[(size_t)row * ldc + col] = f2bf(v);
                else
                    ((float*)Cp)[(size_t)row * ldc + col] = v;
            }
        }
    }
}

// ---------------------------------------------------------------------------
// fp32 GEMM (small shapes: xproj N=64, dt K=32). act: 0 none, 2 softplus.
// ---------------------------------------------------------------------------
#define LDST 76

__global__ __launch_bounds__(256) void gemm_f32(
    const float* __restrict__ A, int lda,
    const float* __restrict__ W,
    const float* __restrict__ bias,
    float* __restrict__ C, int ldc,
    int N, int K, int act, int flip)
{
    __shared__ float As[32][LDST];
    __shared__ float Ws[32][LDST];

    const int tid = threadIdx.x;
    const int tx = tid & 15;
    const int ty = tid >> 4;
    const int rowbase = blockIdx.y * 64;
    const int colbase = blockIdx.x * 64;

    float c[4][4] = {};

    for (int k0 = 0; k0 < K; k0 += 32) {
#pragma unroll
        for (int it = 0; it < 2; ++it) {
            int q  = tid + it * 256;
            int r  = q >> 3;
            int kc = (q & 7) << 2;
            int ar = rowbase + r;
            if (flip) ar = (ar & ~(LSEQ - 1)) + (LSEQ - 1 - (ar & (LSEQ - 1)));
            float4 av = *(const float4*)&A[(size_t)ar * lda + k0 + kc];
            As[kc + 0][r] = av.x; As[kc + 1][r] = av.y;
            As[kc + 2][r] = av.z; As[kc + 3][r] = av.w;
            int wr = colbase + r;
            float4 wv = *(const float4*)&W[(size_t)wr * K + k0 + kc];
            Ws[kc + 0][r] = wv.x; Ws[kc + 1][r] = wv.y;
            Ws[kc + 2][r] = wv.z; Ws[kc + 3][r] = wv.w;
        }
        __syncthreads();
#pragma unroll
        for (int k = 0; k < 32; ++k) {
            float4 a4 = *(const float4*)&As[k][ty << 2];
            float4 w4 = *(const float4*)&Ws[k][tx << 2];
            float av[4] = {a4.x, a4.y, a4.z, a4.w};
            float wv[4] = {w4.x, w4.y, w4.z, w4.w};
#pragma unroll
            for (int i = 0; i < 4; ++i)
#pragma unroll
                for (int j = 0; j < 4; ++j)
                    c[i][j] = fmaf(av[i], wv[j], c[i][j]);
        }
        __syncthreads();
    }

    float4 bv = make_float4(0.f, 0.f, 0.f, 0.f);
    if (bias) bv = *(const float4*)&bias[colbase + (tx << 2)];
#pragma unroll
    for (int i = 0; i < 4; ++i) {
        float o[4] = {c[i][0] + bv.x, c[i][1] + bv.y, c[i][2] + bv.z, c[i][3] + bv.w};
        if (act == 2) {
#pragma unroll
            for (int j = 0; j < 4; ++j) o[j] = softplusf(o[j]);
        }
        float4 ov = make_float4(o[0], o[1], o[2], o[3]);
        *(float4*)&C[(size_t)(rowbase + (ty << 2) + i) * ldc + colbase + (tx << 2)] = ov;
    }
}

// ---------------------------------------------------------------------------
// Depthwise causal conv (D_CONV=4) + bias + silu.
// ---------------------------------------------------------------------------
__global__ __launch_bounds__(256) void conv_silu(
    const float* __restrict__ xz, const float* __restrict__ cw,
    const float* __restrict__ cb, float* __restrict__ xc)
{
    int e = blockIdx.x * 256 + threadIdx.x;
    int m = blockIdx.y;
    int t = m & (LSEQ - 1);

    float4 w = *(const float4*)&cw[e * 4];
    float wk[4] = {w.x, w.y, w.z, w.w};
    float acc = cb[e];
#pragma unroll
    for (int k = 0; k < 4; ++k) {
        int tt = t - 3 + k;
        if (tt >= 0)
            acc = fmaf(wk[k], xz[(size_t)(m - 3 + k) * 2048 + e], acc);
    }
    float s = 1.f / (1.f + __expf(-acc));
    xc[(size_t)m * EDIM + e] = acc * s;
}

// ---------------------------------------------------------------------------
// Chunked selective scan, pass 1: per-chunk (P = prod da, S = end state from 0).
// Grid (EDIM/16, BATCH, NCH). Block: 16 channels x 16 states. Summary layout
// [b][ch][e][n].
// ---------------------------------------------------------------------------
__global__ __launch_bounds__(256) void scan_part1(
    const float* __restrict__ delta, const float* __restrict__ xc,
    const float* __restrict__ dbc, const float* __restrict__ Alog,
    float* __restrict__ Psum, float* __restrict__ Ssum)
{
    __shared__ float sd[64][16], sx[64][16], sB[64][16];

    const int b  = blockIdx.y;
    const int e0 = blockIdx.x * 16;
    const int ch = blockIdx.z;
    const int tid  = threadIdx.x;
    const int lane = tid & 63;
    const int n    = lane & 15;
    const int wave = tid >> 6;
    const int egl  = wave * 4 + (lane >> 4);
    const int e    = e0 + egl;

    const float Aen = -__expf(Alog[e * DSTATE + n]);
    float h = 0.f, Pp = 1.f;

    const int tld = tid >> 2;
    const int q   = (tid & 3) << 2;
    const int tbase = ch * CHLEN;

#pragma unroll
    for (int half = 0; half < 2; ++half) {
        __syncthreads();
        size_t grow = (size_t)(b * LSEQ + tbase + half * 64 + tld);
        *(float4*)&sd[tld][q] = *(const float4*)&delta[grow * EDIM + e0 + q];
        *(float4*)&sx[tld][q] = *(const float4*)&xc[grow * EDIM + e0 + q];
        *(float4*)&sB[tld][q] = *(const float4*)&dbc[grow * 64 + 32 + q];
        __syncthreads();

        for (int t = 0; t < 64; ++t) {
            float d   = sd[t][egl];
            float xcv = sx[t][egl];
            float da  = __expf(d * Aen);
            h  = fmaf(da, h, d * sB[t][n] * xcv);
            Pp *= da;
        }
    }

    size_t idx = ((size_t)((b * NCH + ch) * EDIM + e)) * DSTATE + n;
    Psum[idx] = Pp;
    Ssum[idx] = h;
}

// ---------------------------------------------------------------------------
// Combine: per (b,e,n) serial prefix over NCH chunk summaries.
// ---------------------------------------------------------------------------
__global__ __launch_bounds__(256) void scan_combine(
    const float* __restrict__ Psum, const float* __restrict__ Ssum,
    float* __restrict__ Hstart)
{
    int i = blockIdx.x * 256 + threadIdx.x;       // 0 .. B*ED*DS-1
    int b = i >> 14;
    int r = i & 16383;                            // e*16+n
    float H = 0.f;
#pragma unroll
    for (int ch = 0; ch < NCH; ++ch) {
        size_t idx = ((size_t)(b * NCH + ch) << 14) + r;
        Hstart[idx] = H;
        H = fmaf(Psum[idx], H, Ssum[idx]);
    }
}

// ---------------------------------------------------------------------------
// Pass 2: re-run recurrence from Hstart, reduce over n, gate, write g (bf16).
// ---------------------------------------------------------------------------
__global__ __launch_bounds__(256) void scan_part2(
    const float* __restrict__ delta, const float* __restrict__ xc,
    const float* __restrict__ dbc, const float* __restrict__ Alog,
    const float* __restrict__ Dvec, const float* __restrict__ xzbuf,
    const float* __restrict__ Hstart, unsigned short* __restrict__ gbf)
{
    __shared__ float sd[64][16], sx[64][16], sz[64][16], sB[64][16], sC[64][16];

    const int b  = blockIdx.y;
    const int e0 = blockIdx.x * 16;
    const int ch = blockIdx.z;
    const int tid  = threadIdx.x;
    const int lane = tid & 63;
    const int n    = lane & 15;
    const int wave = tid >> 6;
    const int egl  = wave * 4 + (lane >> 4);
    const int e    = e0 + egl;

    const float Aen = -__expf(Alog[e * DSTATE + n]);
    const float Dv  = Dvec[e];
    float h = Hstart[((size_t)((b * NCH + ch) * EDIM + e)) * DSTATE + n];

    const int tld = tid >> 2;
    const int q   = (tid & 3) << 2;
    const int tbase = ch * CHLEN;

#pragma unroll
    for (int half = 0; half < 2; ++half) {
        __syncthreads();
        size_t grow = (size_t)(b * LSEQ + tbase + half * 64 + tld);
        *(float4*)&sd[tld][q] = *(const float4*)&delta[grow * EDIM + e0 + q];
        *(float4*)&sx[tld][q] = *(const float4*)&xc[grow * EDIM + e0 + q];
        *(float4*)&sz[tld][q] = *(const float4*)&xzbuf[grow * 2048 + 1024 + e0 + q];
        *(float4*)&sB[tld][q] = *(const float4*)&dbc[grow * 64 + 32 + q];
        *(float4*)&sC[tld][q] = *(const float4*)&dbc[grow * 64 + 48 + q];
        __syncthreads();

        for (int tt = 0; tt < 64; tt += 4) {
            float p[4];
#pragma unroll
            for (int u = 0; u < 4; ++u) {
                int t = tt + u;
                float d   = sd[t][egl];
                float xcv = sx[t][egl];
                float da  = __expf(d * Aen);
                h = fmaf(da, h, d * sB[t][n] * xcv);
                p[u] = h * sC[t][n];
            }
#pragma unroll
            for (int off = 1; off < 16; off <<= 1) {
                p[0] += __shfl_xor(p[0], off);
                p[1] += __shfl_xor(p[1], off);
                p[2] += __shfl_xor(p[2], off);
                p[3] += __shfl_xor(p[3], off);
            }
            if (n == 0) {
#pragma unroll
                for (int u = 0; u < 4; ++u) {
                    int t = tt + u;
                    float xcv = sx[t][egl];
                    float zv  = sz[t][egl];
                    float y   = p[u] + Dv * xcv;
                    float sig = 1.f / (1.f + __expf(-zv));
                    float zz  = zv * sig;
                    gbf[(size_t)(b * LSEQ + tbase + half * 64 + t) * EDIM + e] =
                        f2bf(fmaf(zz, y - xcv, xcv));
                }
            }
        }
    }
}

// ---------------------------------------------------------------------------
__device__ __forceinline__ void block_reduce4(float4& s, float4* red, int tid)
{
#pragma unroll
    for (int off = 1; off < 64; off <<= 1) {
        s.x += __shfl_xor(s.x, off);
        s.y += __shfl_xor(s.y, off);
        s.z += __shfl_xor(s.z, off);
        s.w += __shfl_xor(s.w, off);
    }
    if ((tid & 63) == 0) red[tid >> 6] = s;
    __syncthreads();
    float4 a = red[0], b = red[1], c = red[2], d = red[3];
    s.x = a.x + b.x + c.x + d.x;
    s.y = a.y + b.y + c.y + d.y;
    s.z = a.z + b.z + c.z + d.z;
    s.w = a.w + b.w + c.w + d.w;
}

// xs = LN(yf+x)*g1+b1 + LN(yb+x)*g2+b2  (also emits bf16 copy for ff1)
__global__ __launch_bounds__(256) void ln_combine(
    const float* __restrict__ yproj, const float* __restrict__ x,
    const float* __restrict__ g1, const float* __restrict__ b1,
    const float* __restrict__ g2, const float* __restrict__ b2,
    float* __restrict__ xs, unsigned short* __restrict__ xsbf)
{
    __shared__ float4 red[4];
    const int row = blockIdx.x, tid = threadIdx.x;
    const float* yf = yproj + (size_t)row * DMODEL;
    const float* yb = yproj + (size_t)(MTOT + row) * DMODEL;
    const float* xr = x + (size_t)row * DMODEL;

    float vf[2], vb[2];
#pragma unroll
    for (int j = 0; j < 2; ++j) {
        int i = tid + j * 256;
        float xi = xr[i];
        vf[j] = yf[i] + xi;
        vb[j] = yb[i] + xi;
    }
    float4 s = make_float4(vf[0] + vf[1], vf[0] * vf[0] + vf[1] * vf[1],
                           vb[0] + vb[1], vb[0] * vb[0] + vb[1] * vb[1]);
    block_reduce4(s, red, tid);
    const float inv = 1.f / DMODEL;
    float mf = s.x * inv, mb = s.z * inv;
    float rf = rsqrtf(s.y * inv - mf * mf + EPSLN);
    float rb = rsqrtf(s.w * inv - mb * mb + EPSLN);
#pragma unroll
    for (int j = 0; j < 2; ++j) {
        int i = tid + j * 256;
        float a  = (vf[j] - mf) * rf * g1[i] + b1[i];
        float bb = (vb[j] - mb) * rb * g2[i] + b2[i];
        float v = a + bb;
        xs[(size_t)row * DMODEL + i] = v;
        xsbf[(size_t)row * DMODEL + i] = f2bf(v);
    }
}

__global__ __launch_bounds__(256) void ln_final(
    const float* __restrict__ h2, const float* __restrict__ xs,
    const float* __restrict__ g3, const float* __restrict__ b3,
    float* __restrict__ out)
{
    __shared__ float4 red[4];
    const int row = blockIdx.x, tid = threadIdx.x;
    float v[2];
#pragma unroll
    for (int j = 0; j < 2; ++j) {
        int i = tid + j * 256;
        v[j] = h2[(size_t)row * DMODEL + i] + xs[(size_t)row * DMODEL + i];
    }
    float4 s = make_float4(v[0] + v[1], v[0] * v[0] + v[1] * v[1], 0.f, 0.f);
    block_reduce4(s, red, tid);
    const float inv = 1.f / DMODEL;
    float m  = s.x * inv;
    float rs = rsqrtf(s.y * inv - m * m + EPSLN);
#pragma unroll
    for (int j = 0; j < 2; ++j) {
        int i = tid + j * 256;
        out[(size_t)row * DMODEL + i] = (v[j] - m) * rs * g3[i] + b3[i];
    }
}

// ---------------------------------------------------------------------------
extern "C" void kernel_launch(void* const* d_in, const int* in_sizes, int n_in,
                              void* d_out, int out_size, void* d_ws, size_t ws_size,
                              hipStream_t stream)
{
    (void)in_sizes; (void)n_in;

    const float* x    = (const float*)d_in[28];
    const float* n1g  = (const float*)d_in[18];
    const float* n1b  = (const float*)d_in[19];
    const float* n2g  = (const float*)d_in[20];
    const float* n2b  = (const float*)d_in[21];
    const float* n3g  = (const float*)d_in[22];
    const float* n3b  = (const float*)d_in[23];
    const float* ff1w = (const float*)d_in[24];
    const float* ff1b = (const float*)d_in[25];
    const float* ff2w = (const float*)d_in[26];
    const float* ff2b = (const float*)d_in[27];

    // Workspace (same validated footprint as round 5)
    const size_t need_floats =
        (size_t)MTOT * 2048 + (size_t)MTOT * 1024 + (size_t)MTOT * 1024 +
        (size_t)MTOT * 64 + (size_t)2 * MTOT * 512 + (size_t)MTOT * 512;
    if (ws_size < need_floats * sizeof(float)) return;
    if (out_size < MTOT * DMODEL) return;

    float* ws    = (float*)d_ws;
    float* xz    = ws;                          // MTOT*2048 (xi|z)
    float* xc    = xz    + (size_t)MTOT * 2048; // MTOT*1024
    float* delta = xc    + (size_t)MTOT * 1024; // MTOT*1024
    float* dbc   = delta + (size_t)MTOT * 1024; // MTOT*64
    float* yproj = dbc   + (size_t)MTOT * 64;   // 2*MTOT*512
    float* xs    = yproj + (size_t)2 * MTOT * 512; // MTOT*512

    // Overlays (all lifetime-disjoint):
    unsigned short* gbf   = (unsigned short*)xs;            // 8M ush = 16MB (dead before ln_combine)
    float* Psum   = yproj + (size_t)MTOT * 512;             // yproj[1] region: 1M floats
    float* Ssum   = Psum + (size_t)BATCH * NCH * EDIM * DSTATE / NCH; // +1M
    // NOTE: BATCH*NCH*EDIM*DSTATE/NCH == BATCH*EDIM*DSTATE = 131072? No—see below.
    // Correct summary element count = BATCH*NCH*EDIM*DSTATE = 1,048,576 floats.
    unsigned short* h1bf  = (unsigned short*)delta;                 // 8M ush = 16MB
    unsigned short* xsbf  = (unsigned short*)(delta + (size_t)MTOT * 512); // next 16MB region, uses 8MB
    float* h2 = xc;                                                 // reuse after scans

    // Fix summary pointers with explicit counts:
    const size_t SUMN = (size_t)BATCH * NCH * EDIM * DSTATE;        // 1,048,576
    Psum = yproj + (size_t)MTOT * 512;
    Ssum = Psum + SUMN;
    float* Hstart = Ssum + SUMN;                                    // 3M of 4M floats used

    // bf16 cast scratch carved from d_out (dead until ln_final):
    unsigned short* ob     = (unsigned short*)d_out;
    unsigned short* xbf    = ob;                        // 4,194,304
    unsigned short* inwf_b = ob + (size_t)4194304;      // 1,048,576
    unsigned short* inwb_b = ob + (size_t)5242880;      // 1,048,576
    unsigned short* outwf_b= ob + (size_t)6291456;      //   524,288
    unsigned short* outwb_b= ob + (size_t)6815744;      //   524,288
    unsigned short* ff1w_b = ob + (size_t)7340032;      //   524,288
    unsigned short* ff2w_b = ob + (size_t)7864320;      //   524,288

    // One-time casts (graph-replayed each call; deterministic)
    cast_bf16<<<(MTOT * DMODEL / 8 + 255) / 256, 256, 0, stream>>>(x, xbf, MTOT * DMODEL / 8);
    cast_bf16<<<(2048 * 512 / 8 + 255) / 256, 256, 0, stream>>>((const float*)d_in[0], inwf_b, 2048 * 512 / 8);
    cast_bf16<<<(2048 * 512 / 8 + 255) / 256, 256, 0, stream>>>((const float*)d_in[9], inwb_b, 2048 * 512 / 8);
    cast_bf16<<<(512 * 1024 / 8 + 255) / 256, 256, 0, stream>>>((const float*)d_in[8], outwf_b, 512 * 1024 / 8);
    cast_bf16<<<(512 * 1024 / 8 + 255) / 256, 256, 0, stream>>>((const float*)d_in[17], outwb_b, 512 * 1024 / 8);
    cast_bf16<<<(1024 * 512 / 8 + 255) / 256, 256, 0, stream>>>(ff1w, ff1w_b, 1024 * 512 / 8);
    cast_bf16<<<(512 * 1024 / 8 + 255) / 256, 256, 0, stream>>>(ff2w, ff2w_b, 512 * 1024 / 8);

    for (int dir = 0; dir < 2; ++dir) {
        const float* cw    = (const float*)d_in[dir * 9 + 1];
        const float* cb    = (const float*)d_in[dir * 9 + 2];
        const float* xpw   = (const float*)d_in[dir * 9 + 3];
        const float* dtw   = (const float*)d_in[dir * 9 + 4];
        const float* dtb   = (const float*)d_in[dir * 9 + 5];
        const float* Alog  = (const float*)d_in[dir * 9 + 6];
        const float* Dvec  = (const float*)d_in[dir * 9 + 7];
        const unsigned short* inw_b = dir ? inwb_b : inwf_b;
        const unsigned short* outw_b = dir ? outwb_b : outwf_b;

        // xz = x(d) @ in_w^T   (M=8192, N=2048, K=512)  [bf16 MFMA]
        gemm_bf16<<<dim3(2048 / 128, MTOT / 128), 256, 0, stream>>>(
            xbf, DMODEL, inw_b, nullptr, xz, 2048, 0, DMODEL, 0, dir);
        // xc = silu(depthwise_conv(xi) + cb)
        conv_silu<<<dim3(EDIM / 256, MTOT), 256, 0, stream>>>(xz, cw, cb, xc);
        // dbc = xc @ xproj^T   (N=64, K=1024)  [fp32]
        gemm_f32<<<dim3(64 / 64, MTOT / 64), 256, 0, stream>>>(
            xc, EDIM, xpw, nullptr, dbc, 64, 64, EDIM, 0, 0);
        // delta = softplus(dbc[:, :32] @ dt_w^T + dt_b)  (N=1024, K=32)  [fp32]
        gemm_f32<<<dim3(EDIM / 64, MTOT / 64), 256, 0, stream>>>(
            dbc, 64, dtw, dtb, delta, EDIM, EDIM, DTRANK, 2, 0);
        // chunked parallel scan
        scan_part1<<<dim3(EDIM / 16, BATCH, NCH), 256, 0, stream>>>(
            delta, xc, dbc, Alog, Psum, Ssum);
        scan_combine<<<(BATCH * EDIM * DSTATE) / 256, 256, 0, stream>>>(
            Psum, Ssum, Hstart);
        scan_part2<<<dim3(EDIM / 16, BATCH, NCH), 256, 0, stream>>>(
            delta, xc, dbc, Alog, Dvec, xz, Hstart, gbf);
        // yproj[dir] = g @ out_w^T   (N=512, K=1024)  [bf16 MFMA]
        gemm_bf16<<<dim3(512 / 128, MTOT / 128), 256, 0, stream>>>(
            gbf, EDIM, outw_b, nullptr,
            yproj + (size_t)dir * MTOT * DMODEL, DMODEL, 0, EDIM, 0, 0);
    }

    // xs = LN(yf+x)*g1+b1 + LN(yb+x)*g2+b2  (+ bf16 copy)
    ln_combine<<<MTOT, 256, 0, stream>>>(yproj, x, n1g, n1b, n2g, n2b, xs, xsbf);
    // h1bf = relu(xs @ ff1^T + ff1b)  [bf16 MFMA, bf16 out]
    gemm_bf16<<<dim3(DFF / 128, MTOT / 128), 256, 0, stream>>>(
        xsbf, DMODEL, ff1w_b, ff1b, h1bf, DFF, 1, DMODEL, 1, 0);
    // h2 = h1bf @ ff2^T + ff2b  [bf16 MFMA]
    gemm_bf16<<<dim3(DMODEL / 128, MTOT / 128), 256, 0, stream>>>(
        h1bf, DFF, ff2w_b, ff2b, h2, DMODEL, 0, DFF, 0, 0);
    // out = LN(h2 + xs)*g3 + b3
    ln_final<<<MTOT, 256, 0, stream>>>(h2, xs, n3g, n3b, (float*)d_out);
}

// Round 7
// 600.701 us; speedup vs baseline: 2.8279x; 1.2936x over previous
//
#include <hip/hip_runtime.h>
#include <hip/hip_bf16.h>

// Problem constants (fixed by reference)
#define LSEQ   1024
#define BATCH  8
#define MTOT   8192      // B*L
#define DMODEL 512
#define EDIM   1024      // EXPAND*D_MODEL
#define DSTATE 16
#define DTRANK 32
#define DFF    1024
#define EPSLN  1e-5f
#define NCH    16        // scan chunks
#define CHLEN  64        // LSEQ/NCH

typedef __attribute__((ext_vector_type(8))) short bf16x8;
typedef __attribute__((ext_vector_type(4))) float f32x4;

__device__ __forceinline__ unsigned short f2bf(float f) {
    __hip_bfloat16 h = __float2bfloat16(f);   // RNE
    unsigned short u;
    __builtin_memcpy(&u, &h, 2);
    return u;
}

__device__ __forceinline__ float softplusf(float v) {
    return fmaxf(v, 0.f) + log1pf(__expf(-fabsf(v)));
}

// ---------------------------------------------------------------------------
// f32 -> bf16 cast (8 elems/thread)
// ---------------------------------------------------------------------------
__global__ __launch_bounds__(256) void cast_bf16(
    const float* __restrict__ in, unsigned short* __restrict__ out, int n8)
{
    int i = blockIdx.x * 256 + threadIdx.x;
    if (i >= n8) return;
    float4 f0 = *(const float4*)&in[(size_t)i * 8];
    float4 f1 = *(const float4*)&in[(size_t)i * 8 + 4];
    unsigned short v[8] = {f2bf(f0.x), f2bf(f0.y), f2bf(f0.z), f2bf(f0.w),
                           f2bf(f1.x), f2bf(f1.y), f2bf(f1.z), f2bf(f1.w)};
    *(uint4*)&out[(size_t)i * 8] = *(uint4*)v;
}

// ---------------------------------------------------------------------------
// bf16 MFMA GEMM: C[M,N] = act(A[M,K] @ W[N,K]^T + bias); A,W bf16, acc f32.
// Tile 128x128, 4 waves (2x2), 4x4 16x16x32 fragments per wave.
// ---------------------------------------------------------------------------
#define BSTRIDE 56

__global__ __launch_bounds__(256) void gemm_bf16(
    const unsigned short* __restrict__ A, int lda,
    const unsigned short* __restrict__ W,
    const float* __restrict__ bias,
    void* __restrict__ Cp, int ldc, int c_bf16,
    int K, int act, int flip)
{
    __shared__ unsigned short As[128][BSTRIDE];
    __shared__ unsigned short Ws[128][BSTRIDE];

    const int tid = threadIdx.x;
    const int rowbase = blockIdx.y * 128;
    const int colbase = blockIdx.x * 128;
    const int wave = tid >> 6, lane = tid & 63;
    const int wm = wave >> 1, wn = wave & 1;
    const int lr = lane & 15;
    const int lk = (lane >> 4) << 3;

    f32x4 acc[4][4];
#pragma unroll
    for (int i = 0; i < 4; ++i)
#pragma unroll
        for (int j = 0; j < 4; ++j)
            acc[i][j] = (f32x4){0.f, 0.f, 0.f, 0.f};

    for (int k0 = 0; k0 < K; k0 += 32) {
        __syncthreads();
#pragma unroll
        for (int it = 0; it < 2; ++it) {
            int idx = tid + it * 256;
            int r = idx >> 2;
            int c = (idx & 3) << 3;
            int ar = rowbase + r;
            if (flip) ar = (ar & ~(LSEQ - 1)) + (LSEQ - 1 - (ar & (LSEQ - 1)));
            *(uint4*)&As[r][c] = *(const uint4*)&A[(size_t)ar * lda + k0 + c];
            *(uint4*)&Ws[r][c] = *(const uint4*)&W[(size_t)(colbase + r) * K + k0 + c];
        }
        __syncthreads();

        bf16x8 af[4], bfv[4];
#pragma unroll
        for (int i = 0; i < 4; ++i)
            af[i] = *(const bf16x8*)&As[wm * 64 + i * 16 + lr][lk];
#pragma unroll
        for (int j = 0; j < 4; ++j)
            bfv[j] = *(const bf16x8*)&Ws[wn * 64 + j * 16 + lr][lk];
#pragma unroll
        for (int i = 0; i < 4; ++i)
#pragma unroll
            for (int j = 0; j < 4; ++j)
                acc[i][j] = __builtin_amdgcn_mfma_f32_16x16x32_bf16(
                    af[i], bfv[j], acc[i][j], 0, 0, 0);
    }

    const int crow0 = rowbase + wm * 64 + ((lane >> 4) << 2);
    const int ccol0 = colbase + wn * 64 + lr;
#pragma unroll
    for (int j = 0; j < 4; ++j) {
        int col = ccol0 + j * 16;
        float bv = bias ? bias[col] : 0.f;
#pragma unroll
        for (int i = 0; i < 4; ++i) {
#pragma unroll
            for (int r = 0; r < 4; ++r) {
                int row = crow0 + i * 16 + r;
                float v = acc[i][j][r] + bv;
                if (act == 1) v = fmaxf(v, 0.f);
                if (c_bf16)
                    ((unsigned short*)Cp)[(size_t)row * ldc + col] = f2bf(v);
                else
                    ((float*)Cp)[(size_t)row * ldc + col] = v;
            }
        }
    }
}

// ---------------------------------------------------------------------------
// fp32 GEMM (small shapes: xproj N=64, dt K=32). act: 0 none, 2 softplus.
// ---------------------------------------------------------------------------
#define LDST 76

__global__ __launch_bounds__(256) void gemm_f32(
    const float* __restrict__ A, int lda,
    const float* __restrict__ W,
    const float* __restrict__ bias,
    float* __restrict__ C, int ldc,
    int N, int K, int act, int flip)
{
    __shared__ float As[32][LDST];
    __shared__ float Ws[32][LDST];

    const int tid = threadIdx.x;
    const int tx = tid & 15;
    const int ty = tid >> 4;
    const int rowbase = blockIdx.y * 64;
    const int colbase = blockIdx.x * 64;

    float c[4][4] = {};

    for (int k0 = 0; k0 < K; k0 += 32) {
#pragma unroll
        for (int it = 0; it < 2; ++it) {
            int q  = tid + it * 256;
            int r  = q >> 3;
            int kc = (q & 7) << 2;
            int ar = rowbase + r;
            if (flip) ar = (ar & ~(LSEQ - 1)) + (LSEQ - 1 - (ar & (LSEQ - 1)));
            float4 av = *(const float4*)&A[(size_t)ar * lda + k0 + kc];
            As[kc + 0][r] = av.x; As[kc + 1][r] = av.y;
            As[kc + 2][r] = av.z; As[kc + 3][r] = av.w;
            int wr = colbase + r;
            float4 wv = *(const float4*)&W[(size_t)wr * K + k0 + kc];
            Ws[kc + 0][r] = wv.x; Ws[kc + 1][r] = wv.y;
            Ws[kc + 2][r] = wv.z; Ws[kc + 3][r] = wv.w;
        }
        __syncthreads();
#pragma unroll
        for (int k = 0; k < 32; ++k) {
            float4 a4 = *(const float4*)&As[k][ty << 2];
            float4 w4 = *(const float4*)&Ws[k][tx << 2];
            float av[4] = {a4.x, a4.y, a4.z, a4.w};
            float wv[4] = {w4.x, w4.y, w4.z, w4.w};
#pragma unroll
            for (int i = 0; i < 4; ++i)
#pragma unroll
                for (int j = 0; j < 4; ++j)
                    c[i][j] = fmaf(av[i], wv[j], c[i][j]);
        }
        __syncthreads();
    }

    float4 bv = make_float4(0.f, 0.f, 0.f, 0.f);
    if (bias) bv = *(const float4*)&bias[colbase + (tx << 2)];
#pragma unroll
    for (int i = 0; i < 4; ++i) {
        float o[4] = {c[i][0] + bv.x, c[i][1] + bv.y, c[i][2] + bv.z, c[i][3] + bv.w};
        if (act == 2) {
#pragma unroll
            for (int j = 0; j < 4; ++j) o[j] = softplusf(o[j]);
        }
        float4 ov = make_float4(o[0], o[1], o[2], o[3]);
        *(float4*)&C[(size_t)(rowbase + (ty << 2) + i) * ldc + colbase + (tx << 2)] = ov;
    }
}

// ---------------------------------------------------------------------------
// Depthwise causal conv (D_CONV=4) + bias + silu.
// ---------------------------------------------------------------------------
__global__ __launch_bounds__(256) void conv_silu(
    const float* __restrict__ xz, const float* __restrict__ cw,
    const float* __restrict__ cb, float* __restrict__ xc)
{
    int e = blockIdx.x * 256 + threadIdx.x;
    int m = blockIdx.y;
    int t = m & (LSEQ - 1);

    float4 w = *(const float4*)&cw[e * 4];
    float wk[4] = {w.x, w.y, w.z, w.w};
    float acc = cb[e];
#pragma unroll
    for (int k = 0; k < 4; ++k) {
        int tt = t - 3 + k;
        if (tt >= 0)
            acc = fmaf(wk[k], xz[(size_t)(m - 3 + k) * 2048 + e], acc);
    }
    float s = 1.f / (1.f + __expf(-acc));
    xc[(size_t)m * EDIM + e] = acc * s;
}

// ---------------------------------------------------------------------------
// Chunked selective scan, lane = channel e, 16 states in registers.
// Pass 1: per-chunk P[n]=exp(Aen[n]*sum d) and end-state S[n] (from h=0).
// Grid (EDIM/256, BATCH, NCH); d/xc read coalesced per-lane from global,
// B staged in LDS (broadcast reads).  Summary layout [b][ch][e][n].
// ---------------------------------------------------------------------------
__global__ __launch_bounds__(256) void scan_part1(
    const float* __restrict__ delta, const float* __restrict__ xc,
    const float* __restrict__ dbc, const float* __restrict__ Alog,
    float* __restrict__ Psum, float* __restrict__ Ssum)
{
    __shared__ float sB[CHLEN][16];

    const int b  = blockIdx.y;
    const int ch = blockIdx.z;
    const int tid = threadIdx.x;
    const int e  = blockIdx.x * 256 + tid;
    const int row0 = b * LSEQ + ch * CHLEN;

    // stage B[t][n] for the chunk: CHLEN*16 = 1024 elems, 4 per thread
#pragma unroll
    for (int it = 0; it < 4; ++it) {
        int q = tid + it * 256;
        int t = q >> 4, n = q & 15;
        sB[t][n] = dbc[(size_t)(row0 + t) * 64 + 32 + n];
    }

    float Aen[16];
#pragma unroll
    for (int k = 0; k < 4; ++k) {
        float4 a4 = *(const float4*)&Alog[e * DSTATE + k * 4];
        Aen[k * 4 + 0] = -__expf(a4.x);
        Aen[k * 4 + 1] = -__expf(a4.y);
        Aen[k * 4 + 2] = -__expf(a4.z);
        Aen[k * 4 + 3] = -__expf(a4.w);
    }

    float h[16];
#pragma unroll
    for (int n = 0; n < 16; ++n) h[n] = 0.f;
    float sumd = 0.f;

    __syncthreads();

    const size_t base = (size_t)row0 * EDIM + e;
    float dnx = delta[base];
    float xnx = xc[base];

    for (int t = 0; t < CHLEN; ++t) {
        float d = dnx, xcv = xnx;
        if (t + 1 < CHLEN) {
            dnx = delta[base + (size_t)(t + 1) * EDIM];
            xnx = xc[base + (size_t)(t + 1) * EDIM];
        }
        sumd += d;
        float dx = d * xcv;
        float Bt[16];
        *(float4*)&Bt[0]  = *(const float4*)&sB[t][0];
        *(float4*)&Bt[4]  = *(const float4*)&sB[t][4];
        *(float4*)&Bt[8]  = *(const float4*)&sB[t][8];
        *(float4*)&Bt[12] = *(const float4*)&sB[t][12];
#pragma unroll
        for (int n = 0; n < 16; ++n) {
            float da = __expf(d * Aen[n]);
            h[n] = fmaf(da, h[n], dx * Bt[n]);
        }
    }

    size_t idx = ((size_t)((b * NCH + ch) * EDIM + e)) * DSTATE;
    float P[16];
#pragma unroll
    for (int n = 0; n < 16; ++n) P[n] = __expf(Aen[n] * sumd);
#pragma unroll
    for (int k = 0; k < 4; ++k) {
        *(float4*)&Psum[idx + k * 4] = *(float4*)&P[k * 4];
        *(float4*)&Ssum[idx + k * 4] = *(float4*)&h[k * 4];
    }
}

// ---------------------------------------------------------------------------
// Combine: serial prefix over NCH chunks per (b,e,n); writes Hstart IN PLACE
// over Psum (each slot read before overwritten).
// ---------------------------------------------------------------------------
__global__ __launch_bounds__(256) void scan_combine(
    float* __restrict__ Psum, const float* __restrict__ Ssum)
{
    int i = blockIdx.x * 256 + threadIdx.x;       // 0 .. B*ED*DS-1
    int b = i >> 14;
    int r = i & 16383;                            // e*16+n
    float H = 0.f;
#pragma unroll
    for (int ch = 0; ch < NCH; ++ch) {
        size_t idx = ((size_t)(b * NCH + ch) << 14) + r;
        float p = Psum[idx];
        float s = Ssum[idx];
        Psum[idx] = H;                            // Hstart for this chunk
        H = fmaf(p, H, s);
    }
}

// ---------------------------------------------------------------------------
// Pass 2: recurrence from Hstart, in-register n-reduction, gate, write g bf16.
// ---------------------------------------------------------------------------
__global__ __launch_bounds__(256) void scan_part2(
    const float* __restrict__ delta, const float* __restrict__ xc,
    const float* __restrict__ dbc, const float* __restrict__ Alog,
    const float* __restrict__ Dvec, const float* __restrict__ xzbuf,
    const float* __restrict__ Hstart, unsigned short* __restrict__ gbf)
{
    __shared__ float sB[CHLEN][16], sC[CHLEN][16];

    const int b  = blockIdx.y;
    const int ch = blockIdx.z;
    const int tid = threadIdx.x;
    const int e  = blockIdx.x * 256 + tid;
    const int row0 = b * LSEQ + ch * CHLEN;

    // stage B and C: CHLEN*32 = 2048 elems, 8 per thread, coalesced over dbc
#pragma unroll
    for (int it = 0; it < 8; ++it) {
        int q = tid + it * 256;
        int t = q >> 5, c = q & 31;
        float v = dbc[(size_t)(row0 + t) * 64 + 32 + c];
        if (c < 16) sB[t][c] = v; else sC[t][c - 16] = v;
    }

    float Aen[16];
#pragma unroll
    for (int k = 0; k < 4; ++k) {
        float4 a4 = *(const float4*)&Alog[e * DSTATE + k * 4];
        Aen[k * 4 + 0] = -__expf(a4.x);
        Aen[k * 4 + 1] = -__expf(a4.y);
        Aen[k * 4 + 2] = -__expf(a4.z);
        Aen[k * 4 + 3] = -__expf(a4.w);
    }
    const float Dv = Dvec[e];

    float h[16];
    {
        size_t idx = ((size_t)((b * NCH + ch) * EDIM + e)) * DSTATE;
#pragma unroll
        for (int k = 0; k < 4; ++k)
            *(float4*)&h[k * 4] = *(const float4*)&Hstart[idx + k * 4];
    }

    __syncthreads();

    const size_t base = (size_t)row0 * EDIM + e;
    const size_t zbase = (size_t)row0 * 2048 + 1024 + e;
    float dnx = delta[base];
    float xnx = xc[base];
    float znx = xzbuf[zbase];

    for (int t = 0; t < CHLEN; ++t) {
        float d = dnx, xcv = xnx, zv = znx;
        if (t + 1 < CHLEN) {
            dnx = delta[base + (size_t)(t + 1) * EDIM];
            xnx = xc[base + (size_t)(t + 1) * EDIM];
            znx = xzbuf[zbase + (size_t)(t + 1) * 2048];
        }
        float dx = d * xcv;
        float Bt[16], Ct[16];
        *(float4*)&Bt[0]  = *(const float4*)&sB[t][0];
        *(float4*)&Bt[4]  = *(const float4*)&sB[t][4];
        *(float4*)&Bt[8]  = *(const float4*)&sB[t][8];
        *(float4*)&Bt[12] = *(const float4*)&sB[t][12];
        *(float4*)&Ct[0]  = *(const float4*)&sC[t][0];
        *(float4*)&Ct[4]  = *(const float4*)&sC[t][4];
        *(float4*)&Ct[8]  = *(const float4*)&sC[t][8];
        *(float4*)&Ct[12] = *(const float4*)&sC[t][12];
        float y = 0.f;
#pragma unroll
        for (int n = 0; n < 16; ++n) {
            float da = __expf(d * Aen[n]);
            h[n] = fmaf(da, h[n], dx * Bt[n]);
            y = fmaf(h[n], Ct[n], y);
        }
        y = fmaf(Dv, xcv, y);
        float sig = 1.f / (1.f + __expf(-zv));
        float zz  = zv * sig;
        gbf[(size_t)(row0 + t) * EDIM + e] = f2bf(fmaf(zz, y - xcv, xcv));
    }
}

// ---------------------------------------------------------------------------
__device__ __forceinline__ void block_reduce4(float4& s, float4* red, int tid)
{
#pragma unroll
    for (int off = 1; off < 64; off <<= 1) {
        s.x += __shfl_xor(s.x, off);
        s.y += __shfl_xor(s.y, off);
        s.z += __shfl_xor(s.z, off);
        s.w += __shfl_xor(s.w, off);
    }
    if ((tid & 63) == 0) red[tid >> 6] = s;
    __syncthreads();
    float4 a = red[0], b = red[1], c = red[2], d = red[3];
    s.x = a.x + b.x + c.x + d.x;
    s.y = a.y + b.y + c.y + d.y;
    s.z = a.z + b.z + c.z + d.z;
    s.w = a.w + b.w + c.w + d.w;
}

// xs = LN(yf+x)*g1+b1 + LN(yb+x)*g2+b2  (also emits bf16 copy for ff1)
__global__ __launch_bounds__(256) void ln_combine(
    const float* __restrict__ yproj, const float* __restrict__ x,
    const float* __restrict__ g1, const float* __restrict__ b1,
    const float* __restrict__ g2, const float* __restrict__ b2,
    float* __restrict__ xs, unsigned short* __restrict__ xsbf)
{
    __shared__ float4 red[4];
    const int row = blockIdx.x, tid = threadIdx.x;
    const float* yf = yproj + (size_t)row * DMODEL;
    const float* yb = yproj + (size_t)(MTOT + row) * DMODEL;
    const float* xr = x + (size_t)row * DMODEL;

    float vf[2], vb[2];
#pragma unroll
    for (int j = 0; j < 2; ++j) {
        int i = tid + j * 256;
        float xi = xr[i];
        vf[j] = yf[i] + xi;
        vb[j] = yb[i] + xi;
    }
    float4 s = make_float4(vf[0] + vf[1], vf[0] * vf[0] + vf[1] * vf[1],
                           vb[0] + vb[1], vb[0] * vb[0] + vb[1] * vb[1]);
    block_reduce4(s, red, tid);
    const float inv = 1.f / DMODEL;
    float mf = s.x * inv, mb = s.z * inv;
    float rf = rsqrtf(s.y * inv - mf * mf + EPSLN);
    float rb = rsqrtf(s.w * inv - mb * mb + EPSLN);
#pragma unroll
    for (int j = 0; j < 2; ++j) {
        int i = tid + j * 256;
        float a  = (vf[j] - mf) * rf * g1[i] + b1[i];
        float bb = (vb[j] - mb) * rb * g2[i] + b2[i];
        float v = a + bb;
        xs[(size_t)row * DMODEL + i] = v;
        xsbf[(size_t)row * DMODEL + i] = f2bf(v);
    }
}

__global__ __launch_bounds__(256) void ln_final(
    const float* __restrict__ h2, const float* __restrict__ xs,
    const float* __restrict__ g3, const float* __restrict__ b3,
    float* __restrict__ out)
{
    __shared__ float4 red[4];
    const int row = blockIdx.x, tid = threadIdx.x;
    float v[2];
#pragma unroll
    for (int j = 0; j < 2; ++j) {
        int i = tid + j * 256;
        v[j] = h2[(size_t)row * DMODEL + i] + xs[(size_t)row * DMODEL + i];
    }
    float4 s = make_float4(v[0] + v[1], v[0] * v[0] + v[1] * v[1], 0.f, 0.f);
    block_reduce4(s, red, tid);
    const float inv = 1.f / DMODEL;
    float m  = s.x * inv;
    float rs = rsqrtf(s.y * inv - m * m + EPSLN);
#pragma unroll
    for (int j = 0; j < 2; ++j) {
        int i = tid + j * 256;
        out[(size_t)row * DMODEL + i] = (v[j] - m) * rs * g3[i] + b3[i];
    }
}

// ---------------------------------------------------------------------------
extern "C" void kernel_launch(void* const* d_in, const int* in_sizes, int n_in,
                              void* d_out, int out_size, void* d_ws, size_t ws_size,
                              hipStream_t stream)
{
    (void)in_sizes; (void)n_in;

    const float* x    = (const float*)d_in[28];
    const float* n1g  = (const float*)d_in[18];
    const float* n1b  = (const float*)d_in[19];
    const float* n2g  = (const float*)d_in[20];
    const float* n2b  = (const float*)d_in[21];
    const float* n3g  = (const float*)d_in[22];
    const float* n3b  = (const float*)d_in[23];
    const float* ff1w = (const float*)d_in[24];
    const float* ff1b = (const float*)d_in[25];
    const float* ff2w = (const float*)d_in[26];
    const float* ff2b = (const float*)d_in[27];

    // Workspace (same validated 178 MB footprint)
    const size_t need_floats =
        (size_t)MTOT * 2048 + (size_t)MTOT * 1024 + (size_t)MTOT * 1024 +
        (size_t)MTOT * 64 + (size_t)2 * MTOT * 512 + (size_t)MTOT * 512;
    if (ws_size < need_floats * sizeof(float)) return;
    if (out_size < MTOT * DMODEL) return;

    float* ws    = (float*)d_ws;
    float* xz    = ws;                          // MTOT*2048 (xi|z)
    float* xc    = xz    + (size_t)MTOT * 2048; // MTOT*1024
    float* delta = xc    + (size_t)MTOT * 1024; // MTOT*1024
    float* dbc   = delta + (size_t)MTOT * 1024; // MTOT*64
    float* yproj = dbc   + (size_t)MTOT * 64;   // 2*MTOT*512
    float* xs    = yproj + (size_t)2 * MTOT * 512; // MTOT*512

    // Overlays (lifetime-disjoint):
    // gbf (bf16 g, 16MB) overlays xs region (dead until ln_combine).
    // P/S summaries (2M floats each = 16MB total) overlay yproj[1], which is
    // dead until dir-1's out-proj (runs after pass2 consumed Hstart).
    // h1bf/xsbf overlay delta (dead after both scans); h2 overlays xc.
    unsigned short* gbf  = (unsigned short*)xs;
    const size_t SUMN    = (size_t)BATCH * NCH * EDIM * DSTATE;   // 2,097,152
    float* Psum  = yproj + (size_t)MTOT * 512;                    // doubles as Hstart
    float* Ssum  = Psum + SUMN;
    unsigned short* h1bf = (unsigned short*)delta;
    unsigned short* xsbf = (unsigned short*)(delta + (size_t)MTOT * 512);
    float* h2 = xc;

    // bf16 cast scratch carved from d_out (dead until ln_final):
    unsigned short* ob     = (unsigned short*)d_out;
    unsigned short* xbf    = ob;                        // 4,194,304
    unsigned short* inwf_b = ob + (size_t)4194304;      // 1,048,576
    unsigned short* inwb_b = ob + (size_t)5242880;      // 1,048,576
    unsigned short* outwf_b= ob + (size_t)6291456;      //   524,288
    unsigned short* outwb_b= ob + (size_t)6815744;      //   524,288
    unsigned short* ff1w_b = ob + (size_t)7340032;      //   524,288
    unsigned short* ff2w_b = ob + (size_t)7864320;      //   524,288

    cast_bf16<<<(MTOT * DMODEL / 8 + 255) / 256, 256, 0, stream>>>(x, xbf, MTOT * DMODEL / 8);
    cast_bf16<<<(2048 * 512 / 8 + 255) / 256, 256, 0, stream>>>((const float*)d_in[0], inwf_b, 2048 * 512 / 8);
    cast_bf16<<<(2048 * 512 / 8 + 255) / 256, 256, 0, stream>>>((const float*)d_in[9], inwb_b, 2048 * 512 / 8);
    cast_bf16<<<(512 * 1024 / 8 + 255) / 256, 256, 0, stream>>>((const float*)d_in[8], outwf_b, 512 * 1024 / 8);
    cast_bf16<<<(512 * 1024 / 8 + 255) / 256, 256, 0, stream>>>((const float*)d_in[17], outwb_b, 512 * 1024 / 8);
    cast_bf16<<<(1024 * 512 / 8 + 255) / 256, 256, 0, stream>>>(ff1w, ff1w_b, 1024 * 512 / 8);
    cast_bf16<<<(512 * 1024 / 8 + 255) / 256, 256, 0, stream>>>(ff2w, ff2w_b, 512 * 1024 / 8);

    for (int dir = 0; dir < 2; ++dir) {
        const float* cw    = (const float*)d_in[dir * 9 + 1];
        const float* cb    = (const float*)d_in[dir * 9 + 2];
        const float* xpw   = (const float*)d_in[dir * 9 + 3];
        const float* dtw   = (const float*)d_in[dir * 9 + 4];
        const float* dtb   = (const float*)d_in[dir * 9 + 5];
        const float* Alog  = (const float*)d_in[dir * 9 + 6];
        const float* Dvec  = (const float*)d_in[dir * 9 + 7];
        const unsigned short* inw_b  = dir ? inwb_b : inwf_b;
        const unsigned short* outw_b = dir ? outwb_b : outwf_b;

        // xz = x(d) @ in_w^T   (M=8192, N=2048, K=512)  [bf16 MFMA]
        gemm_bf16<<<dim3(2048 / 128, MTOT / 128), 256, 0, stream>>>(
            xbf, DMODEL, inw_b, nullptr, xz, 2048, 0, DMODEL, 0, dir);
        // xc = silu(depthwise_conv(xi) + cb)
        conv_silu<<<dim3(EDIM / 256, MTOT), 256, 0, stream>>>(xz, cw, cb, xc);
        // dbc = xc @ xproj^T   (N=64, K=1024)  [fp32]
        gemm_f32<<<dim3(64 / 64, MTOT / 64), 256, 0, stream>>>(
            xc, EDIM, xpw, nullptr, dbc, 64, 64, EDIM, 0, 0);
        // delta = softplus(dbc[:, :32] @ dt_w^T + dt_b)  (N=1024, K=32)  [fp32]
        gemm_f32<<<dim3(EDIM / 64, MTOT / 64), 256, 0, stream>>>(
            dbc, 64, dtw, dtb, delta, EDIM, EDIM, DTRANK, 2, 0);
        // chunked parallel scan (16-state-per-lane)
        scan_part1<<<dim3(EDIM / 256, BATCH, NCH), 256, 0, stream>>>(
            delta, xc, dbc, Alog, Psum, Ssum);
        scan_combine<<<(BATCH * EDIM * DSTATE) / 256, 256, 0, stream>>>(
            Psum, Ssum);
        scan_part2<<<dim3(EDIM / 256, BATCH, NCH), 256, 0, stream>>>(
            delta, xc, dbc, Alog, Dvec, xz, Psum, gbf);
        // yproj[dir] = g @ out_w^T   (N=512, K=1024)  [bf16 MFMA]
        gemm_bf16<<<dim3(512 / 128, MTOT / 128), 256, 0, stream>>>(
            gbf, EDIM, outw_b, nullptr,
            yproj + (size_t)dir * MTOT * DMODEL, DMODEL, 0, EDIM, 0, 0);
    }

    // xs = LN(yf+x)*g1+b1 + LN(yb+x)*g2+b2  (+ bf16 copy)
    ln_combine<<<MTOT, 256, 0, stream>>>(yproj, x, n1g, n1b, n2g, n2b, xs, xsbf);
    // h1bf = relu(xs @ ff1^T + ff1b)  [bf16 MFMA, bf16 out]
    gemm_bf16<<<dim3(DFF / 128, MTOT / 128), 256, 0, stream>>>(
        xsbf, DMODEL, ff1w_b, ff1b, h1bf, DFF, 1, DMODEL, 1, 0);
    // h2 = h1bf @ ff2^T + ff2b  [bf16 MFMA]
    gemm_bf16<<<dim3(DMODEL / 128, MTOT / 128), 256, 0, stream>>>(
        h1bf, DFF, ff2w_b, ff2b, h2, DMODEL, 0, DFF, 0, 0);
    // out = LN(h2 + xs)*g3 + b3
    ln_final<<<MTOT, 256, 0, stream>>>(h2, xs, n3g, n3b, (float*)d_out);
}

// Round 8
// 598.176 us; speedup vs baseline: 2.8398x; 1.0042x over previous
//
#include <hip/hip_runtime.h>
#include <hip/hip_bf16.h>

// Problem constants (fixed by reference)
#define LSEQ   1024
#define BATCH  8
#define MTOT   8192      // B*L
#define DMODEL 512
#define EDIM   1024      // EXPAND*D_MODEL
#define DSTATE 16
#define DTRANK 32
#define DFF    1024
#define EPSLN  1e-5f
#define NCH    16        // scan chunks
#define CHLEN  64        // LSEQ/NCH

typedef __attribute__((ext_vector_type(8))) short bf16x8;
typedef __attribute__((ext_vector_type(4))) float f32x4;

__device__ __forceinline__ unsigned short f2bf(float f) {
    __hip_bfloat16 h = __float2bfloat16(f);   // RNE
    unsigned short u;
    __builtin_memcpy(&u, &h, 2);
    return u;
}

__device__ __forceinline__ float softplusf(float v) {
    return fmaxf(v, 0.f) + log1pf(__expf(-fabsf(v)));
}

// ---------------------------------------------------------------------------
// f32 -> bf16 cast (8 elems/thread)
// ---------------------------------------------------------------------------
__global__ __launch_bounds__(256) void cast_bf16(
    const float* __restrict__ in, unsigned short* __restrict__ out, int n8)
{
    int i = blockIdx.x * 256 + threadIdx.x;
    if (i >= n8) return;
    float4 f0 = *(const float4*)&in[(size_t)i * 8];
    float4 f1 = *(const float4*)&in[(size_t)i * 8 + 4];
    unsigned short v[8] = {f2bf(f0.x), f2bf(f0.y), f2bf(f0.z), f2bf(f0.w),
                           f2bf(f1.x), f2bf(f1.y), f2bf(f1.z), f2bf(f1.w)};
    *(uint4*)&out[(size_t)i * 8] = *(uint4*)v;
}

// ---------------------------------------------------------------------------
// bf16 MFMA GEMM: C[M,N] = act(A[M,K] @ W[N,K]^T + bias); A,W bf16, acc f32.
// Tile 128x128, 4 waves (2x2), 4x4 16x16x32 fragments per wave.
// Round-8: BSTRIDE 72 (144B rows -> conflict-free b128 reads: 16 lanes cover
// 32 banks exactly 2x) + async-STAGE split (issue k+1 global loads before
// tile-k ds_read+MFMA; ds_write after barrier -> HBM/L2 latency hidden).
// ---------------------------------------------------------------------------
#define BSTRIDE 72

__global__ __launch_bounds__(256) void gemm_bf16(
    const unsigned short* __restrict__ A, int lda,
    const unsigned short* __restrict__ W,
    const float* __restrict__ bias,
    void* __restrict__ Cp, int ldc, int c_bf16,
    int K, int act, int flip)
{
    __shared__ unsigned short As[128][BSTRIDE];
    __shared__ unsigned short Ws[128][BSTRIDE];

    const int tid = threadIdx.x;
    const int rowbase = blockIdx.y * 128;
    const int colbase = blockIdx.x * 128;
    const int wave = tid >> 6, lane = tid & 63;
    const int wm = wave >> 1, wn = wave & 1;
    const int lr = lane & 15;
    const int lk = (lane >> 4) << 3;

    // staging coords: thread covers rows r0 and r0+64, one 16B chunk each
    const int r0 = tid >> 2;
    const int c0 = (tid & 3) << 3;
    int ar0 = rowbase + r0, ar1 = rowbase + r0 + 64;
    if (flip) {
        ar0 = (ar0 & ~(LSEQ - 1)) + (LSEQ - 1 - (ar0 & (LSEQ - 1)));
        ar1 = (ar1 & ~(LSEQ - 1)) + (LSEQ - 1 - (ar1 & (LSEQ - 1)));
    }
    const unsigned short* Arow0 = A + (size_t)ar0 * lda + c0;
    const unsigned short* Arow1 = A + (size_t)ar1 * lda + c0;
    const unsigned short* Wrow0 = W + (size_t)(colbase + r0) * K + c0;
    const unsigned short* Wrow1 = W + (size_t)(colbase + r0 + 64) * K + c0;

    f32x4 acc[4][4];
#pragma unroll
    for (int i = 0; i < 4; ++i)
#pragma unroll
        for (int j = 0; j < 4; ++j)
            acc[i][j] = (f32x4){0.f, 0.f, 0.f, 0.f};

    // prologue: stage tile k=0
    uint4 ra0 = *(const uint4*)(Arow0);
    uint4 ra1 = *(const uint4*)(Arow1);
    uint4 rw0 = *(const uint4*)(Wrow0);
    uint4 rw1 = *(const uint4*)(Wrow1);
    *(uint4*)&As[r0][c0]      = ra0;
    *(uint4*)&As[r0 + 64][c0] = ra1;
    *(uint4*)&Ws[r0][c0]      = rw0;
    *(uint4*)&Ws[r0 + 64][c0] = rw1;
    __syncthreads();

    for (int k0 = 0; k0 < K; k0 += 32) {
        const bool more = (k0 + 32) < K;
        if (more) {   // issue next tile's loads EARLY (latency hides under MFMA)
            ra0 = *(const uint4*)(Arow0 + k0 + 32);
            ra1 = *(const uint4*)(Arow1 + k0 + 32);
            rw0 = *(const uint4*)(Wrow0 + k0 + 32);
            rw1 = *(const uint4*)(Wrow1 + k0 + 32);
        }

        bf16x8 af[4], bfv[4];
#pragma unroll
        for (int i = 0; i < 4; ++i)
            af[i] = *(const bf16x8*)&As[wm * 64 + i * 16 + lr][lk];
#pragma unroll
        for (int j = 0; j < 4; ++j)
            bfv[j] = *(const bf16x8*)&Ws[wn * 64 + j * 16 + lr][lk];
#pragma unroll
        for (int i = 0; i < 4; ++i)
#pragma unroll
            for (int j = 0; j < 4; ++j)
                acc[i][j] = __builtin_amdgcn_mfma_f32_16x16x32_bf16(
                    af[i], bfv[j], acc[i][j], 0, 0, 0);

        if (more) {
            __syncthreads();   // all waves done reading this tile
            *(uint4*)&As[r0][c0]      = ra0;
            *(uint4*)&As[r0 + 64][c0] = ra1;
            *(uint4*)&Ws[r0][c0]      = rw0;
            *(uint4*)&Ws[r0 + 64][c0] = rw1;
            __syncthreads();
        }
    }

    const int crow0 = rowbase + wm * 64 + ((lane >> 4) << 2);
    const int ccol0 = colbase + wn * 64 + lr;
#pragma unroll
    for (int j = 0; j < 4; ++j) {
        int col = ccol0 + j * 16;
        float bv = bias ? bias[col] : 0.f;
#pragma unroll
        for (int i = 0; i < 4; ++i) {
#pragma unroll
            for (int r = 0; r < 4; ++r) {
                int row = crow0 + i * 16 + r;
                float v = acc[i][j][r] + bv;
                if (act == 1) v = fmaxf(v, 0.f);
                if (c_bf16)
                    ((unsigned short*)Cp)[(size_t)row * ldc + col] = f2bf(v);
                else
                    ((float*)Cp)[(size_t)row * ldc + col] = v;
            }
        }
    }
}

// ---------------------------------------------------------------------------
// fp32 GEMM (small shapes: xproj N=64, dt K=32). act: 0 none, 2 softplus.
// ---------------------------------------------------------------------------
#define LDST 76

__global__ __launch_bounds__(256) void gemm_f32(
    const float* __restrict__ A, int lda,
    const float* __restrict__ W,
    const float* __restrict__ bias,
    float* __restrict__ C, int ldc,
    int N, int K, int act, int flip)
{
    __shared__ float As[32][LDST];
    __shared__ float Ws[32][LDST];

    const int tid = threadIdx.x;
    const int tx = tid & 15;
    const int ty = tid >> 4;
    const int rowbase = blockIdx.y * 64;
    const int colbase = blockIdx.x * 64;

    float c[4][4] = {};

    for (int k0 = 0; k0 < K; k0 += 32) {
#pragma unroll
        for (int it = 0; it < 2; ++it) {
            int q  = tid + it * 256;
            int r  = q >> 3;
            int kc = (q & 7) << 2;
            int ar = rowbase + r;
            if (flip) ar = (ar & ~(LSEQ - 1)) + (LSEQ - 1 - (ar & (LSEQ - 1)));
            float4 av = *(const float4*)&A[(size_t)ar * lda + k0 + kc];
            As[kc + 0][r] = av.x; As[kc + 1][r] = av.y;
            As[kc + 2][r] = av.z; As[kc + 3][r] = av.w;
            int wr = colbase + r;
            float4 wv = *(const float4*)&W[(size_t)wr * K + k0 + kc];
            Ws[kc + 0][r] = wv.x; Ws[kc + 1][r] = wv.y;
            Ws[kc + 2][r] = wv.z; Ws[kc + 3][r] = wv.w;
        }
        __syncthreads();
#pragma unroll
        for (int k = 0; k < 32; ++k) {
            float4 a4 = *(const float4*)&As[k][ty << 2];
            float4 w4 = *(const float4*)&Ws[k][tx << 2];
            float av[4] = {a4.x, a4.y, a4.z, a4.w};
            float wv[4] = {w4.x, w4.y, w4.z, w4.w};
#pragma unroll
            for (int i = 0; i < 4; ++i)
#pragma unroll
                for (int j = 0; j < 4; ++j)
                    c[i][j] = fmaf(av[i], wv[j], c[i][j]);
        }
        __syncthreads();
    }

    float4 bv = make_float4(0.f, 0.f, 0.f, 0.f);
    if (bias) bv = *(const float4*)&bias[colbase + (tx << 2)];
#pragma unroll
    for (int i = 0; i < 4; ++i) {
        float o[4] = {c[i][0] + bv.x, c[i][1] + bv.y, c[i][2] + bv.z, c[i][3] + bv.w};
        if (act == 2) {
#pragma unroll
            for (int j = 0; j < 4; ++j) o[j] = softplusf(o[j]);
        }
        float4 ov = make_float4(o[0], o[1], o[2], o[3]);
        *(float4*)&C[(size_t)(rowbase + (ty << 2) + i) * ldc + colbase + (tx << 2)] = ov;
    }
}

// ---------------------------------------------------------------------------
// Depthwise causal conv (D_CONV=4) + bias + silu.
// ---------------------------------------------------------------------------
__global__ __launch_bounds__(256) void conv_silu(
    const float* __restrict__ xz, const float* __restrict__ cw,
    const float* __restrict__ cb, float* __restrict__ xc)
{
    int e = blockIdx.x * 256 + threadIdx.x;
    int m = blockIdx.y;
    int t = m & (LSEQ - 1);

    float4 w = *(const float4*)&cw[e * 4];
    float wk[4] = {w.x, w.y, w.z, w.w};
    float acc = cb[e];
#pragma unroll
    for (int k = 0; k < 4; ++k) {
        int tt = t - 3 + k;
        if (tt >= 0)
            acc = fmaf(wk[k], xz[(size_t)(m - 3 + k) * 2048 + e], acc);
    }
    float s = 1.f / (1.f + __expf(-acc));
    xc[(size_t)m * EDIM + e] = acc * s;
}

// ---------------------------------------------------------------------------
// Chunked selective scan, lane = channel e, 16 states in registers.
// Pass 1: per-chunk P[n]=exp(Aen[n]*sum d) and end-state S[n] (from h=0).
// ---------------------------------------------------------------------------
__global__ __launch_bounds__(256) void scan_part1(
    const float* __restrict__ delta, const float* __restrict__ xc,
    const float* __restrict__ dbc, const float* __restrict__ Alog,
    float* __restrict__ Psum, float* __restrict__ Ssum)
{
    __shared__ float sB[CHLEN][16];

    const int b  = blockIdx.y;
    const int ch = blockIdx.z;
    const int tid = threadIdx.x;
    const int e  = blockIdx.x * 256 + tid;
    const int row0 = b * LSEQ + ch * CHLEN;

#pragma unroll
    for (int it = 0; it < 4; ++it) {
        int q = tid + it * 256;
        int t = q >> 4, n = q & 15;
        sB[t][n] = dbc[(size_t)(row0 + t) * 64 + 32 + n];
    }

    float Aen[16];
#pragma unroll
    for (int k = 0; k < 4; ++k) {
        float4 a4 = *(const float4*)&Alog[e * DSTATE + k * 4];
        Aen[k * 4 + 0] = -__expf(a4.x);
        Aen[k * 4 + 1] = -__expf(a4.y);
        Aen[k * 4 + 2] = -__expf(a4.z);
        Aen[k * 4 + 3] = -__expf(a4.w);
    }

    float h[16];
#pragma unroll
    for (int n = 0; n < 16; ++n) h[n] = 0.f;
    float sumd = 0.f;

    __syncthreads();

    const size_t base = (size_t)row0 * EDIM + e;
    float dnx = delta[base];
    float xnx = xc[base];

    for (int t = 0; t < CHLEN; ++t) {
        float d = dnx, xcv = xnx;
        if (t + 1 < CHLEN) {
            dnx = delta[base + (size_t)(t + 1) * EDIM];
            xnx = xc[base + (size_t)(t + 1) * EDIM];
        }
        sumd += d;
        float dx = d * xcv;
        float Bt[16];
        *(float4*)&Bt[0]  = *(const float4*)&sB[t][0];
        *(float4*)&Bt[4]  = *(const float4*)&sB[t][4];
        *(float4*)&Bt[8]  = *(const float4*)&sB[t][8];
        *(float4*)&Bt[12] = *(const float4*)&sB[t][12];
#pragma unroll
        for (int n = 0; n < 16; ++n) {
            float da = __expf(d * Aen[n]);
            h[n] = fmaf(da, h[n], dx * Bt[n]);
        }
    }

    size_t idx = ((size_t)((b * NCH + ch) * EDIM + e)) * DSTATE;
    float P[16];
#pragma unroll
    for (int n = 0; n < 16; ++n) P[n] = __expf(Aen[n] * sumd);
#pragma unroll
    for (int k = 0; k < 4; ++k) {
        *(float4*)&Psum[idx + k * 4] = *(float4*)&P[k * 4];
        *(float4*)&Ssum[idx + k * 4] = *(float4*)&h[k * 4];
    }
}

// ---------------------------------------------------------------------------
// Combine: serial prefix over NCH chunks per (b,e,n); writes Hstart IN PLACE
// over Psum (each slot read before overwritten).
// ---------------------------------------------------------------------------
__global__ __launch_bounds__(256) void scan_combine(
    float* __restrict__ Psum, const float* __restrict__ Ssum)
{
    int i = blockIdx.x * 256 + threadIdx.x;       // 0 .. B*ED*DS-1
    int b = i >> 14;
    int r = i & 16383;                            // e*16+n
    float H = 0.f;
#pragma unroll
    for (int ch = 0; ch < NCH; ++ch) {
        size_t idx = ((size_t)(b * NCH + ch) << 14) + r;
        float p = Psum[idx];
        float s = Ssum[idx];
        Psum[idx] = H;                            // Hstart for this chunk
        H = fmaf(p, H, s);
    }
}

// ---------------------------------------------------------------------------
// Pass 2: recurrence from Hstart, in-register n-reduction, gate, write g bf16.
// ---------------------------------------------------------------------------
__global__ __launch_bounds__(256) void scan_part2(
    const float* __restrict__ delta, const float* __restrict__ xc,
    const float* __restrict__ dbc, const float* __restrict__ Alog,
    const float* __restrict__ Dvec, const float* __restrict__ xzbuf,
    const float* __restrict__ Hstart, unsigned short* __restrict__ gbf)
{
    __shared__ float sB[CHLEN][16], sC[CHLEN][16];

    const int b  = blockIdx.y;
    const int ch = blockIdx.z;
    const int tid = threadIdx.x;
    const int e  = blockIdx.x * 256 + tid;
    const int row0 = b * LSEQ + ch * CHLEN;

#pragma unroll
    for (int it = 0; it < 8; ++it) {
        int q = tid + it * 256;
        int t = q >> 5, c = q & 31;
        float v = dbc[(size_t)(row0 + t) * 64 + 32 + c];
        if (c < 16) sB[t][c] = v; else sC[t][c - 16] = v;
    }

    float Aen[16];
#pragma unroll
    for (int k = 0; k < 4; ++k) {
        float4 a4 = *(const float4*)&Alog[e * DSTATE + k * 4];
        Aen[k * 4 + 0] = -__expf(a4.x);
        Aen[k * 4 + 1] = -__expf(a4.y);
        Aen[k * 4 + 2] = -__expf(a4.z);
        Aen[k * 4 + 3] = -__expf(a4.w);
    }
    const float Dv = Dvec[e];

    float h[16];
    {
        size_t idx = ((size_t)((b * NCH + ch) * EDIM + e)) * DSTATE;
#pragma unroll
        for (int k = 0; k < 4; ++k)
            *(float4*)&h[k * 4] = *(const float4*)&Hstart[idx + k * 4];
    }

    __syncthreads();

    const size_t base = (size_t)row0 * EDIM + e;
    const size_t zbase = (size_t)row0 * 2048 + 1024 + e;
    float dnx = delta[base];
    float xnx = xc[base];
    float znx = xzbuf[zbase];

    for (int t = 0; t < CHLEN; ++t) {
        float d = dnx, xcv = xnx, zv = znx;
        if (t + 1 < CHLEN) {
            dnx = delta[base + (size_t)(t + 1) * EDIM];
            xnx = xc[base + (size_t)(t + 1) * EDIM];
            znx = xzbuf[zbase + (size_t)(t + 1) * 2048];
        }
        float dx = d * xcv;
        float Bt[16], Ct[16];
        *(float4*)&Bt[0]  = *(const float4*)&sB[t][0];
        *(float4*)&Bt[4]  = *(const float4*)&sB[t][4];
        *(float4*)&Bt[8]  = *(const float4*)&sB[t][8];
        *(float4*)&Bt[12] = *(const float4*)&sB[t][12];
        *(float4*)&Ct[0]  = *(const float4*)&sC[t][0];
        *(float4*)&Ct[4]  = *(const float4*)&sC[t][4];
        *(float4*)&Ct[8]  = *(const float4*)&sC[t][8];
        *(float4*)&Ct[12] = *(const float4*)&sC[t][12];
        float y = 0.f;
#pragma unroll
        for (int n = 0; n < 16; ++n) {
            float da = __expf(d * Aen[n]);
            h[n] = fmaf(da, h[n], dx * Bt[n]);
            y = fmaf(h[n], Ct[n], y);
        }
        y = fmaf(Dv, xcv, y);
        float sig = 1.f / (1.f + __expf(-zv));
        float zz  = zv * sig;
        gbf[(size_t)(row0 + t) * EDIM + e] = f2bf(fmaf(zz, y - xcv, xcv));
    }
}

// ---------------------------------------------------------------------------
__device__ __forceinline__ void block_reduce4(float4& s, float4* red, int tid)
{
#pragma unroll
    for (int off = 1; off < 64; off <<= 1) {
        s.x += __shfl_xor(s.x, off);
        s.y += __shfl_xor(s.y, off);
        s.z += __shfl_xor(s.z, off);
        s.w += __shfl_xor(s.w, off);
    }
    if ((tid & 63) == 0) red[tid >> 6] = s;
    __syncthreads();
    float4 a = red[0], b = red[1], c = red[2], d = red[3];
    s.x = a.x + b.x + c.x + d.x;
    s.y = a.y + b.y + c.y + d.y;
    s.z = a.z + b.z + c.z + d.z;
    s.w = a.w + b.w + c.w + d.w;
}

// xs = LN(yf+x)*g1+b1 + LN(yb+x)*g2+b2  (also emits bf16 copy for ff1)
__global__ __launch_bounds__(256) void ln_combine(
    const float* __restrict__ yproj, const float* __restrict__ x,
    const float* __restrict__ g1, const float* __restrict__ b1,
    const float* __restrict__ g2, const float* __restrict__ b2,
    float* __restrict__ xs, unsigned short* __restrict__ xsbf)
{
    __shared__ float4 red[4];
    const int row = blockIdx.x, tid = threadIdx.x;
    const float* yf = yproj + (size_t)row * DMODEL;
    const float* yb = yproj + (size_t)(MTOT + row) * DMODEL;
    const float* xr = x + (size_t)row * DMODEL;

    float vf[2], vb[2];
#pragma unroll
    for (int j = 0; j < 2; ++j) {
        int i = tid + j * 256;
        float xi = xr[i];
        vf[j] = yf[i] + xi;
        vb[j] = yb[i] + xi;
    }
    float4 s = make_float4(vf[0] + vf[1], vf[0] * vf[0] + vf[1] * vf[1],
                           vb[0] + vb[1], vb[0] * vb[0] + vb[1] * vb[1]);
    block_reduce4(s, red, tid);
    const float inv = 1.f / DMODEL;
    float mf = s.x * inv, mb = s.z * inv;
    float rf = rsqrtf(s.y * inv - mf * mf + EPSLN);
    float rb = rsqrtf(s.w * inv - mb * mb + EPSLN);
#pragma unroll
    for (int j = 0; j < 2; ++j) {
        int i = tid + j * 256;
        float a  = (vf[j] - mf) * rf * g1[i] + b1[i];
        float bb = (vb[j] - mb) * rb * g2[i] + b2[i];
        float v = a + bb;
        xs[(size_t)row * DMODEL + i] = v;
        xsbf[(size_t)row * DMODEL + i] = f2bf(v);
    }
}

__global__ __launch_bounds__(256) void ln_final(
    const float* __restrict__ h2, const float* __restrict__ xs,
    const float* __restrict__ g3, const float* __restrict__ b3,
    float* __restrict__ out)
{
    __shared__ float4 red[4];
    const int row = blockIdx.x, tid = threadIdx.x;
    float v[2];
#pragma unroll
    for (int j = 0; j < 2; ++j) {
        int i = tid + j * 256;
        v[j] = h2[(size_t)row * DMODEL + i] + xs[(size_t)row * DMODEL + i];
    }
    float4 s = make_float4(v[0] + v[1], v[0] * v[0] + v[1] * v[1], 0.f, 0.f);
    block_reduce4(s, red, tid);
    const float inv = 1.f / DMODEL;
    float m  = s.x * inv;
    float rs = rsqrtf(s.y * inv - m * m + EPSLN);
#pragma unroll
    for (int j = 0; j < 2; ++j) {
        int i = tid + j * 256;
        out[(size_t)row * DMODEL + i] = (v[j] - m) * rs * g3[i] + b3[i];
    }
}

// ---------------------------------------------------------------------------
extern "C" void kernel_launch(void* const* d_in, const int* in_sizes, int n_in,
                              void* d_out, int out_size, void* d_ws, size_t ws_size,
                              hipStream_t stream)
{
    (void)in_sizes; (void)n_in;

    const float* x    = (const float*)d_in[28];
    const float* n1g  = (const float*)d_in[18];
    const float* n1b  = (const float*)d_in[19];
    const float* n2g  = (const float*)d_in[20];
    const float* n2b  = (const float*)d_in[21];
    const float* n3g  = (const float*)d_in[22];
    const float* n3b  = (const float*)d_in[23];
    const float* ff1w = (const float*)d_in[24];
    const float* ff1b = (const float*)d_in[25];
    const float* ff2w = (const float*)d_in[26];
    const float* ff2b = (const float*)d_in[27];

    // Workspace (same validated 178 MB footprint)
    const size_t need_floats =
        (size_t)MTOT * 2048 + (size_t)MTOT * 1024 + (size_t)MTOT * 1024 +
        (size_t)MTOT * 64 + (size_t)2 * MTOT * 512 + (size_t)MTOT * 512;
    if (ws_size < need_floats * sizeof(float)) return;
    if (out_size < MTOT * DMODEL) return;

    float* ws    = (float*)d_ws;
    float* xz    = ws;                          // MTOT*2048 (xi|z)
    float* xc    = xz    + (size_t)MTOT * 2048; // MTOT*1024
    float* delta = xc    + (size_t)MTOT * 1024; // MTOT*1024
    float* dbc   = delta + (size_t)MTOT * 1024; // MTOT*64
    float* yproj = dbc   + (size_t)MTOT * 64;   // 2*MTOT*512
    float* xs    = yproj + (size_t)2 * MTOT * 512; // MTOT*512

    // Overlays (lifetime-disjoint):
    unsigned short* gbf  = (unsigned short*)xs;
    const size_t SUMN    = (size_t)BATCH * NCH * EDIM * DSTATE;   // 2,097,152
    float* Psum  = yproj + (size_t)MTOT * 512;                    // doubles as Hstart
    float* Ssum  = Psum + SUMN;
    unsigned short* h1bf = (unsigned short*)delta;
    unsigned short* xsbf = (unsigned short*)(delta + (size_t)MTOT * 512);
    float* h2 = xc;

    // bf16 cast scratch carved from d_out (dead until ln_final):
    unsigned short* ob     = (unsigned short*)d_out;
    unsigned short* xbf    = ob;                        // 4,194,304
    unsigned short* inwf_b = ob + (size_t)4194304;      // 1,048,576
    unsigned short* inwb_b = ob + (size_t)5242880;      // 1,048,576
    unsigned short* outwf_b= ob + (size_t)6291456;      //   524,288
    unsigned short* outwb_b= ob + (size_t)6815744;      //   524,288
    unsigned short* ff1w_b = ob + (size_t)7340032;      //   524,288
    unsigned short* ff2w_b = ob + (size_t)7864320;      //   524,288

    cast_bf16<<<(MTOT * DMODEL / 8 + 255) / 256, 256, 0, stream>>>(x, xbf, MTOT * DMODEL / 8);
    cast_bf16<<<(2048 * 512 / 8 + 255) / 256, 256, 0, stream>>>((const float*)d_in[0], inwf_b, 2048 * 512 / 8);
    cast_bf16<<<(2048 * 512 / 8 + 255) / 256, 256, 0, stream>>>((const float*)d_in[9], inwb_b, 2048 * 512 / 8);
    cast_bf16<<<(512 * 1024 / 8 + 255) / 256, 256, 0, stream>>>((const float*)d_in[8], outwf_b, 512 * 1024 / 8);
    cast_bf16<<<(512 * 1024 / 8 + 255) / 256, 256, 0, stream>>>((const float*)d_in[17], outwb_b, 512 * 1024 / 8);
    cast_bf16<<<(1024 * 512 / 8 + 255) / 256, 256, 0, stream>>>(ff1w, ff1w_b, 1024 * 512 / 8);
    cast_bf16<<<(512 * 1024 / 8 + 255) / 256, 256, 0, stream>>>(ff2w, ff2w_b, 512 * 1024 / 8);

    for (int dir = 0; dir < 2; ++dir) {
        const float* cw    = (const float*)d_in[dir * 9 + 1];
        const float* cb    = (const float*)d_in[dir * 9 + 2];
        const float* xpw   = (const float*)d_in[dir * 9 + 3];
        const float* dtw   = (const float*)d_in[dir * 9 + 4];
        const float* dtb   = (const float*)d_in[dir * 9 + 5];
        const float* Alog  = (const float*)d_in[dir * 9 + 6];
        const float* Dvec  = (const float*)d_in[dir * 9 + 7];
        const unsigned short* inw_b  = dir ? inwb_b : inwf_b;
        const unsigned short* outw_b = dir ? outwb_b : outwf_b;

        // xz = x(d) @ in_w^T   (M=8192, N=2048, K=512)  [bf16 MFMA]
        gemm_bf16<<<dim3(2048 / 128, MTOT / 128), 256, 0, stream>>>(
            xbf, DMODEL, inw_b, nullptr, xz, 2048, 0, DMODEL, 0, dir);
        // xc = silu(depthwise_conv(xi) + cb)
        conv_silu<<<dim3(EDIM / 256, MTOT), 256, 0, stream>>>(xz, cw, cb, xc);
        // dbc = xc @ xproj^T   (N=64, K=1024)  [fp32]
        gemm_f32<<<dim3(64 / 64, MTOT / 64), 256, 0, stream>>>(
            xc, EDIM, xpw, nullptr, dbc, 64, 64, EDIM, 0, 0);
        // delta = softplus(dbc[:, :32] @ dt_w^T + dt_b)  (N=1024, K=32)  [fp32]
        gemm_f32<<<dim3(EDIM / 64, MTOT / 64), 256, 0, stream>>>(
            dbc, 64, dtw, dtb, delta, EDIM, EDIM, DTRANK, 2, 0);
        // chunked parallel scan (16-state-per-lane)
        scan_part1<<<dim3(EDIM / 256, BATCH, NCH), 256, 0, stream>>>(
            delta, xc, dbc, Alog, Psum, Ssum);
        scan_combine<<<(BATCH * EDIM * DSTATE) / 256, 256, 0, stream>>>(
            Psum, Ssum);
        scan_part2<<<dim3(EDIM / 256, BATCH, NCH), 256, 0, stream>>>(
            delta, xc, dbc, Alog, Dvec, xz, Psum, gbf);
        // yproj[dir] = g @ out_w^T   (N=512, K=1024)  [bf16 MFMA]
        gemm_bf16<<<dim3(512 / 128, MTOT / 128), 256, 0, stream>>>(
            gbf, EDIM, outw_b, nullptr,
            yproj + (size_t)dir * MTOT * DMODEL, DMODEL, 0, EDIM, 0, 0);
    }

    // xs = LN(yf+x)*g1+b1 + LN(yb+x)*g2+b2  (+ bf16 copy)
    ln_combine<<<MTOT, 256, 0, stream>>>(yproj, x, n1g, n1b, n2g, n2b, xs, xsbf);
    // h1bf = relu(xs @ ff1^T + ff1b)  [bf16 MFMA, bf16 out]
    gemm_bf16<<<dim3(DFF / 128, MTOT / 128), 256, 0, stream>>>(
        xsbf, DMODEL, ff1w_b, ff1b, h1bf, DFF, 1, DMODEL, 1, 0);
    // h2 = h1bf @ ff2^T + ff2b  [bf16 MFMA]
    gemm_bf16<<<dim3(DMODEL / 128, MTOT / 128), 256, 0, stream>>>(
        h1bf, DFF, ff2w_b, ff2b, h2, DMODEL, 0, DFF, 0, 0);
    // out = LN(h2 + xs)*g3 + b3
    ln_final<<<MTOT, 256, 0, stream>>>(h2, xs, n3g, n3b, (float*)d_out);
}

// Round 10
// 550.535 us; speedup vs baseline: 3.0856x; 1.0865x over previous
//
#include <hip/hip_runtime.h>
#include <hip/hip_bf16.h>

// Problem constants (fixed by reference)
#define LSEQ   1024
#define BATCH  8
#define MTOT   8192      // B*L
#define DMODEL 512
#define EDIM   1024      // EXPAND*D_MODEL
#define DSTATE 16
#define DTRANK 32
#define DFF    1024
#define EPSLN  1e-5f
#define NCH    16        // scan chunks
#define CHLEN  64        // LSEQ/NCH

typedef __attribute__((ext_vector_type(8))) short bf16x8;
typedef __attribute__((ext_vector_type(4))) float f32x4;

__device__ __forceinline__ unsigned short f2bf(float f) {
    __hip_bfloat16 h = __float2bfloat16(f);   // RNE
    unsigned short u;
    __builtin_memcpy(&u, &h, 2);
    return u;
}

__device__ __forceinline__ float softplusf(float v) {
    return fmaxf(v, 0.f) + log1pf(__expf(-fabsf(v)));
}

// async global->LDS, 16B per lane. LDS dest = wave-uniform base + lane*16.
__device__ __forceinline__ void gload16(const unsigned short* g, unsigned short* l) {
    __builtin_amdgcn_global_load_lds(
        (const __attribute__((address_space(1))) void*)g,
        (__attribute__((address_space(3))) void*)l, 16, 0, 0);
}

// ---------------------------------------------------------------------------
// f32 -> bf16 cast (8 elems/thread)
// ---------------------------------------------------------------------------
__global__ __launch_bounds__(256) void cast_bf16(
    const float* __restrict__ in, unsigned short* __restrict__ out, int n8)
{
    int i = blockIdx.x * 256 + threadIdx.x;
    if (i >= n8) return;
    float4 f0 = *(const float4*)&in[(size_t)i * 8];
    float4 f1 = *(const float4*)&in[(size_t)i * 8 + 4];
    unsigned short v[8] = {f2bf(f0.x), f2bf(f0.y), f2bf(f0.z), f2bf(f0.w),
                           f2bf(f1.x), f2bf(f1.y), f2bf(f1.z), f2bf(f1.w)};
    *(uint4*)&out[(size_t)i * 8] = *(uint4*)v;
}

// ---------------------------------------------------------------------------
// bf16 MFMA GEMM v3.1: C[M,N] = act(A[M,K] @ W[N,K]^T + bias)
// Tile 128x128, 4 waves (2x2), 4x4 16x16x32 frags. LDS [128][32] linear
// (8KB/matrix), staged via global_load_lds: each wave stages rows
// [w*16, w*16+16) and [64+w*16, 64+w*16+16) of both tiles (FULL 128 rows —
// round-9 bug staged only 64). 16B-chunk XOR swizzle pc = c ^ ((row>>1)&3)
// baked into the per-lane GLOBAL address (m173); frag reads use the same
// swizzle -> 2-way reads (free floor). The +64 row shares the swizzle term.
// ---------------------------------------------------------------------------
__global__ __launch_bounds__(256) void gemm_bf16(
    const unsigned short* __restrict__ A, int lda,
    const unsigned short* __restrict__ W,
    const float* __restrict__ bias,
    void* __restrict__ Cp, int ldc, int c_bf16,
    int K, int act, int flip)
{
    __shared__ unsigned short As[128][32];
    __shared__ unsigned short Ws[128][32];

    const int tid = threadIdx.x;
    const int rowbase = blockIdx.y * 128;
    const int colbase = blockIdx.x * 128;
    const int wave = tid >> 6, lane = tid & 63;
    const int wm = wave >> 1, wn = wave & 1;
    const int lr = lane & 15;
    const int lc = lane >> 4;                 // logical chunk for frag reads

    // staging: row r0 = tid>>2 (0..63) and r0+64; physical chunk tid&3 holds
    // logical chunk cl (swizzle term identical for r0 and r0+64).
    const int r0 = tid >> 2;
    const int cl = (tid & 3) ^ ((r0 >> 1) & 3);
    int ar0 = rowbase + r0, ar1 = rowbase + r0 + 64;
    if (flip) {
        ar0 = (ar0 & ~(LSEQ - 1)) + (LSEQ - 1 - (ar0 & (LSEQ - 1)));
        ar1 = (ar1 & ~(LSEQ - 1)) + (LSEQ - 1 - (ar1 & (LSEQ - 1)));
    }
    const unsigned short* Ag0 = A + (size_t)ar0 * lda + (cl << 3);
    const unsigned short* Ag1 = A + (size_t)ar1 * lda + (cl << 3);
    const unsigned short* Wg0 = W + (size_t)(colbase + r0) * K + (cl << 3);
    const unsigned short* Wg1 = W + (size_t)(colbase + r0 + 64) * K + (cl << 3);
    unsigned short* Asl0 = &As[wave << 4][0];       // wave-uniform LDS bases
    unsigned short* Asl1 = &As[64 + (wave << 4)][0];
    unsigned short* Wsl0 = &Ws[wave << 4][0];
    unsigned short* Wsl1 = &Ws[64 + (wave << 4)][0];

    f32x4 acc[4][4];
#pragma unroll
    for (int i = 0; i < 4; ++i)
#pragma unroll
        for (int j = 0; j < 4; ++j)
            acc[i][j] = (f32x4){0.f, 0.f, 0.f, 0.f};

    for (int k0 = 0; k0 < K; k0 += 32) {
        __syncthreads();                      // prior tile's reads complete
        gload16(Ag0 + k0, Asl0);
        gload16(Ag1 + k0, Asl1);
        gload16(Wg0 + k0, Wsl0);
        gload16(Wg1 + k0, Wsl1);
        __syncthreads();                      // vmcnt drain + barrier

        bf16x8 af[4], bfv[4];
#pragma unroll
        for (int i = 0; i < 4; ++i) {
            int R = wm * 64 + i * 16 + lr;
            int pc = lc ^ ((R >> 1) & 3);
            af[i] = *(const bf16x8*)&As[R][pc << 3];
        }
#pragma unroll
        for (int j = 0; j < 4; ++j) {
            int R = wn * 64 + j * 16 + lr;
            int pc = lc ^ ((R >> 1) & 3);
            bfv[j] = *(const bf16x8*)&Ws[R][pc << 3];
        }
#pragma unroll
        for (int i = 0; i < 4; ++i)
#pragma unroll
            for (int j = 0; j < 4; ++j)
                acc[i][j] = __builtin_amdgcn_mfma_f32_16x16x32_bf16(
                    af[i], bfv[j], acc[i][j], 0, 0, 0);
    }

    const int crow0 = rowbase + wm * 64 + ((lane >> 4) << 2);
    const int ccol0 = colbase + wn * 64 + lr;
#pragma unroll
    for (int j = 0; j < 4; ++j) {
        int col = ccol0 + j * 16;
        float bv = bias ? bias[col] : 0.f;
#pragma unroll
        for (int i = 0; i < 4; ++i) {
#pragma unroll
            for (int r = 0; r < 4; ++r) {
                int row = crow0 + i * 16 + r;
                float v = acc[i][j][r] + bv;
                if (act == 1) v = fmaxf(v, 0.f);
                if (c_bf16)
                    ((unsigned short*)Cp)[(size_t)row * ldc + col] = f2bf(v);
                else
                    ((float*)Cp)[(size_t)row * ldc + col] = v;
            }
        }
    }
}

// ---------------------------------------------------------------------------
// xproj MFMA with split-K: dbc[M,64] += xcbf[M,1024] @ xpw_b[64,1024]^T
// Tile 128x64, grid (M/128, KSPLIT=4), K-slice 256 per z. 4 waves 2x2 ->
// wave tile 64x32 (A frags 4, B frags 2). Epilogue atomicAdd (dbc pre-zeroed).
// ---------------------------------------------------------------------------
__global__ __launch_bounds__(256) void xproj_bf16(
    const unsigned short* __restrict__ A,
    const unsigned short* __restrict__ W,
    float* __restrict__ Cp)
{
    __shared__ unsigned short As[128][32];
    __shared__ unsigned short Ws[64][32];

    const int tid = threadIdx.x;
    const int rowbase = blockIdx.x * 128;
    const int kbase = blockIdx.y * 256;
    const int wave = tid >> 6, lane = tid & 63;
    const int wm = wave >> 1, wn = wave & 1;
    const int lr = lane & 15;
    const int lc = lane >> 4;

    const int r0 = tid >> 2;
    const int cl = (tid & 3) ^ ((r0 >> 1) & 3);    // same for r0 and r0+64
    const unsigned short* Ag0 = A + (size_t)(rowbase + r0) * EDIM + kbase + (cl << 3);
    const unsigned short* Ag1 = A + (size_t)(rowbase + r0 + 64) * EDIM + kbase + (cl << 3);
    const unsigned short* Wg  = W + (size_t)r0 * EDIM + kbase + (cl << 3);
    unsigned short* Asl0 = &As[wave << 4][0];
    unsigned short* Asl1 = &As[64 + (wave << 4)][0];
    unsigned short* Wsl  = &Ws[wave << 4][0];

    f32x4 acc[4][2];
#pragma unroll
    for (int i = 0; i < 4; ++i)
#pragma unroll
        for (int j = 0; j < 2; ++j)
            acc[i][j] = (f32x4){0.f, 0.f, 0.f, 0.f};

    for (int k0 = 0; k0 < 256; k0 += 32) {
        __syncthreads();
        gload16(Ag0 + k0, Asl0);
        gload16(Ag1 + k0, Asl1);
        gload16(Wg + k0, Wsl);
        __syncthreads();

        bf16x8 af[4], bfv[2];
#pragma unroll
        for (int i = 0; i < 4; ++i) {
            int R = wm * 64 + i * 16 + lr;
            int pc = lc ^ ((R >> 1) & 3);
            af[i] = *(const bf16x8*)&As[R][pc << 3];
        }
#pragma unroll
        for (int j = 0; j < 2; ++j) {
            int R = wn * 32 + j * 16 + lr;
            int pc = lc ^ ((R >> 1) & 3);
            bfv[j] = *(const bf16x8*)&Ws[R][pc << 3];
        }
#pragma unroll
        for (int i = 0; i < 4; ++i)
#pragma unroll
            for (int j = 0; j < 2; ++j)
                acc[i][j] = __builtin_amdgcn_mfma_f32_16x16x32_bf16(
                    af[i], bfv[j], acc[i][j], 0, 0, 0);
    }

    const int crow0 = rowbase + wm * 64 + ((lane >> 4) << 2);
    const int ccol0 = wn * 32 + lr;
#pragma unroll
    for (int i = 0; i < 4; ++i)
#pragma unroll
        for (int j = 0; j < 2; ++j)
#pragma unroll
            for (int r = 0; r < 4; ++r)
                atomicAdd(&Cp[(size_t)(crow0 + i * 16 + r) * 64 + ccol0 + j * 16],
                          acc[i][j][r]);
}

// ---------------------------------------------------------------------------
// fp32 GEMM (kept for dt: N=1024, K=32, softplus)
// ---------------------------------------------------------------------------
#define LDST 76

__global__ __launch_bounds__(256) void gemm_f32(
    const float* __restrict__ A, int lda,
    const float* __restrict__ W,
    const float* __restrict__ bias,
    float* __restrict__ C, int ldc,
    int N, int K, int act, int flip)
{
    __shared__ float As[32][LDST];
    __shared__ float Ws[32][LDST];

    const int tid = threadIdx.x;
    const int tx = tid & 15;
    const int ty = tid >> 4;
    const int rowbase = blockIdx.y * 64;
    const int colbase = blockIdx.x * 64;

    float c[4][4] = {};

    for (int k0 = 0; k0 < K; k0 += 32) {
#pragma unroll
        for (int it = 0; it < 2; ++it) {
            int q  = tid + it * 256;
            int r  = q >> 3;
            int kc = (q & 7) << 2;
            int ar = rowbase + r;
            if (flip) ar = (ar & ~(LSEQ - 1)) + (LSEQ - 1 - (ar & (LSEQ - 1)));
            float4 av = *(const float4*)&A[(size_t)ar * lda + k0 + kc];
            As[kc + 0][r] = av.x; As[kc + 1][r] = av.y;
            As[kc + 2][r] = av.z; As[kc + 3][r] = av.w;
            int wr = colbase + r;
            float4 wv = *(const float4*)&W[(size_t)wr * K + k0 + kc];
            Ws[kc + 0][r] = wv.x; Ws[kc + 1][r] = wv.y;
            Ws[kc + 2][r] = wv.z; Ws[kc + 3][r] = wv.w;
        }
        __syncthreads();
#pragma unroll
        for (int k = 0; k < 32; ++k) {
            float4 a4 = *(const float4*)&As[k][ty << 2];
            float4 w4 = *(const float4*)&Ws[k][tx << 2];
            float av[4] = {a4.x, a4.y, a4.z, a4.w};
            float wv[4] = {w4.x, w4.y, w4.z, w4.w};
#pragma unroll
            for (int i = 0; i < 4; ++i)
#pragma unroll
                for (int j = 0; j < 4; ++j)
                    c[i][j] = fmaf(av[i], wv[j], c[i][j]);
        }
        __syncthreads();
    }

    float4 bv = make_float4(0.f, 0.f, 0.f, 0.f);
    if (bias) bv = *(const float4*)&bias[colbase + (tx << 2)];
#pragma unroll
    for (int i = 0; i < 4; ++i) {
        float o[4] = {c[i][0] + bv.x, c[i][1] + bv.y, c[i][2] + bv.z, c[i][3] + bv.w};
        if (act == 2) {
#pragma unroll
            for (int j = 0; j < 4; ++j) o[j] = softplusf(o[j]);
        }
        float4 ov = make_float4(o[0], o[1], o[2], o[3]);
        *(float4*)&C[(size_t)(rowbase + (ty << 2) + i) * ldc + colbase + (tx << 2)] = ov;
    }
}

// ---------------------------------------------------------------------------
// Depthwise causal conv (D_CONV=4) + bias + silu; writes f32 xc + bf16 xcbf.
// ---------------------------------------------------------------------------
__global__ __launch_bounds__(256) void conv_silu(
    const float* __restrict__ xz, const float* __restrict__ cw,
    const float* __restrict__ cb, float* __restrict__ xc,
    unsigned short* __restrict__ xcbf)
{
    const int e = threadIdx.x << 2;           // 0..1020
    const int m = blockIdx.x;                 // 0..8191
    const int t = m & (LSEQ - 1);

    float4 w0 = *(const float4*)&cw[e * 4];
    float4 w1 = *(const float4*)&cw[e * 4 + 4];
    float4 w2 = *(const float4*)&cw[e * 4 + 8];
    float4 w3 = *(const float4*)&cw[e * 4 + 12];
    float4 acc = *(const float4*)&cb[e];
#pragma unroll
    for (int k = 0; k < 4; ++k) {
        if (t - 3 + k >= 0) {
            float4 xv = *(const float4*)&xz[(size_t)(m - 3 + k) * 2048 + e];
            acc.x = fmaf((&w0.x)[k], xv.x, acc.x);
            acc.y = fmaf((&w1.x)[k], xv.y, acc.y);
            acc.z = fmaf((&w2.x)[k], xv.z, acc.z);
            acc.w = fmaf((&w3.x)[k], xv.w, acc.w);
        }
    }
    float4 o;
    o.x = acc.x / (1.f + __expf(-acc.x));
    o.y = acc.y / (1.f + __expf(-acc.y));
    o.z = acc.z / (1.f + __expf(-acc.z));
    o.w = acc.w / (1.f + __expf(-acc.w));
    *(float4*)&xc[(size_t)m * EDIM + e] = o;
    unsigned short b4[4] = {f2bf(o.x), f2bf(o.y), f2bf(o.z), f2bf(o.w)};
    *(uint2*)&xcbf[(size_t)m * EDIM + e] = *(uint2*)b4;
}

// ---------------------------------------------------------------------------
// Chunked selective scan, lane = channel e, 16 states in registers.
// ---------------------------------------------------------------------------
__global__ __launch_bounds__(256) void scan_part1(
    const float* __restrict__ delta, const float* __restrict__ xc,
    const float* __restrict__ dbc, const float* __restrict__ Alog,
    float* __restrict__ Psum, float* __restrict__ Ssum)
{
    __shared__ float sB[CHLEN][16];

    const int b  = blockIdx.y;
    const int ch = blockIdx.z;
    const int tid = threadIdx.x;
    const int e  = blockIdx.x * 256 + tid;
    const int row0 = b * LSEQ + ch * CHLEN;

#pragma unroll
    for (int it = 0; it < 4; ++it) {
        int q = tid + it * 256;
        int t = q >> 4, n = q & 15;
        sB[t][n] = dbc[(size_t)(row0 + t) * 64 + 32 + n];
    }

    float Aen[16];
#pragma unroll
    for (int k = 0; k < 4; ++k) {
        float4 a4 = *(const float4*)&Alog[e * DSTATE + k * 4];
        Aen[k * 4 + 0] = -__expf(a4.x);
        Aen[k * 4 + 1] = -__expf(a4.y);
        Aen[k * 4 + 2] = -__expf(a4.z);
        Aen[k * 4 + 3] = -__expf(a4.w);
    }

    float h[16];
#pragma unroll
    for (int n = 0; n < 16; ++n) h[n] = 0.f;
    float sumd = 0.f;

    __syncthreads();

    const size_t base = (size_t)row0 * EDIM + e;
    float dnx = delta[base];
    float xnx = xc[base];

    for (int t = 0; t < CHLEN; ++t) {
        float d = dnx, xcv = xnx;
        if (t + 1 < CHLEN) {
            dnx = delta[base + (size_t)(t + 1) * EDIM];
            xnx = xc[base + (size_t)(t + 1) * EDIM];
        }
        sumd += d;
        float dx = d * xcv;
        float Bt[16];
        *(float4*)&Bt[0]  = *(const float4*)&sB[t][0];
        *(float4*)&Bt[4]  = *(const float4*)&sB[t][4];
        *(float4*)&Bt[8]  = *(const float4*)&sB[t][8];
        *(float4*)&Bt[12] = *(const float4*)&sB[t][12];
#pragma unroll
        for (int n = 0; n < 16; ++n) {
            float da = __expf(d * Aen[n]);
            h[n] = fmaf(da, h[n], dx * Bt[n]);
        }
    }

    size_t idx = ((size_t)((b * NCH + ch) * EDIM + e)) * DSTATE;
    float P[16];
#pragma unroll
    for (int n = 0; n < 16; ++n) P[n] = __expf(Aen[n] * sumd);
#pragma unroll
    for (int k = 0; k < 4; ++k) {
        *(float4*)&Psum[idx + k * 4] = *(float4*)&P[k * 4];
        *(float4*)&Ssum[idx + k * 4] = *(float4*)&h[k * 4];
    }
}

__global__ __launch_bounds__(256) void scan_combine(
    float* __restrict__ Psum, const float* __restrict__ Ssum)
{
    int i = blockIdx.x * 256 + threadIdx.x;       // 0 .. B*ED*DS-1
    int b = i >> 14;
    int r = i & 16383;                            // e*16+n
    float H = 0.f;
#pragma unroll
    for (int ch = 0; ch < NCH; ++ch) {
        size_t idx = ((size_t)(b * NCH + ch) << 14) + r;
        float p = Psum[idx];
        float s = Ssum[idx];
        Psum[idx] = H;                            // Hstart for this chunk
        H = fmaf(p, H, s);
    }
}

__global__ __launch_bounds__(256) void scan_part2(
    const float* __restrict__ delta, const float* __restrict__ xc,
    const float* __restrict__ dbc, const float* __restrict__ Alog,
    const float* __restrict__ Dvec, const float* __restrict__ xzbuf,
    const float* __restrict__ Hstart, unsigned short* __restrict__ gbf)
{
    __shared__ float sB[CHLEN][16], sC[CHLEN][16];

    const int b  = blockIdx.y;
    const int ch = blockIdx.z;
    const int tid = threadIdx.x;
    const int e  = blockIdx.x * 256 + tid;
    const int row0 = b * LSEQ + ch * CHLEN;

#pragma unroll
    for (int it = 0; it < 8; ++it) {
        int q = tid + it * 256;
        int t = q >> 5, c = q & 31;
        float v = dbc[(size_t)(row0 + t) * 64 + 32 + c];
        if (c < 16) sB[t][c] = v; else sC[t][c - 16] = v;
    }

    float Aen[16];
#pragma unroll
    for (int k = 0; k < 4; ++k) {
        float4 a4 = *(const float4*)&Alog[e * DSTATE + k * 4];
        Aen[k * 4 + 0] = -__expf(a4.x);
        Aen[k * 4 + 1] = -__expf(a4.y);
        Aen[k * 4 + 2] = -__expf(a4.z);
        Aen[k * 4 + 3] = -__expf(a4.w);
    }
    const float Dv = Dvec[e];

    float h[16];
    {
        size_t idx = ((size_t)((b * NCH + ch) * EDIM + e)) * DSTATE;
#pragma unroll
        for (int k = 0; k < 4; ++k)
            *(float4*)&h[k * 4] = *(const float4*)&Hstart[idx + k * 4];
    }

    __syncthreads();

    const size_t base = (size_t)row0 * EDIM + e;
    const size_t zbase = (size_t)row0 * 2048 + 1024 + e;
    float dnx = delta[base];
    float xnx = xc[base];
    float znx = xzbuf[zbase];

    for (int t = 0; t < CHLEN; ++t) {
        float d = dnx, xcv = xnx, zv = znx;
        if (t + 1 < CHLEN) {
            dnx = delta[base + (size_t)(t + 1) * EDIM];
            xnx = xc[base + (size_t)(t + 1) * EDIM];
            znx = xzbuf[zbase + (size_t)(t + 1) * 2048];
        }
        float dx = d * xcv;
        float Bt[16], Ct[16];
        *(float4*)&Bt[0]  = *(const float4*)&sB[t][0];
        *(float4*)&Bt[4]  = *(const float4*)&sB[t][4];
        *(float4*)&Bt[8]  = *(const float4*)&sB[t][8];
        *(float4*)&Bt[12] = *(const float4*)&sB[t][12];
        *(float4*)&Ct[0]  = *(const float4*)&sC[t][0];
        *(float4*)&Ct[4]  = *(const float4*)&sC[t][4];
        *(float4*)&Ct[8]  = *(const float4*)&sC[t][8];
        *(float4*)&Ct[12] = *(const float4*)&sC[t][12];
        float y = 0.f;
#pragma unroll
        for (int n = 0; n < 16; ++n) {
            float da = __expf(d * Aen[n]);
            h[n] = fmaf(da, h[n], dx * Bt[n]);
            y = fmaf(h[n], Ct[n], y);
        }
        y = fmaf(Dv, xcv, y);
        float sig = 1.f / (1.f + __expf(-zv));
        float zz  = zv * sig;
        gbf[(size_t)(row0 + t) * EDIM + e] = f2bf(fmaf(zz, y - xcv, xcv));
    }
}

// ---------------------------------------------------------------------------
__device__ __forceinline__ void block_reduce4(float4& s, float4* red, int tid)
{
#pragma unroll
    for (int off = 1; off < 64; off <<= 1) {
        s.x += __shfl_xor(s.x, off);
        s.y += __shfl_xor(s.y, off);
        s.z += __shfl_xor(s.z, off);
        s.w += __shfl_xor(s.w, off);
    }
    if ((tid & 63) == 0) red[tid >> 6] = s;
    __syncthreads();
    float4 a = red[0], b = red[1], c = red[2], d = red[3];
    s.x = a.x + b.x + c.x + d.x;
    s.y = a.y + b.y + c.y + d.y;
    s.z = a.z + b.z + c.z + d.z;
    s.w = a.w + b.w + c.w + d.w;
}

__global__ __launch_bounds__(256) void ln_combine(
    const float* __restrict__ yproj, const float* __restrict__ x,
    const float* __restrict__ g1, const float* __restrict__ b1,
    const float* __restrict__ g2, const float* __restrict__ b2,
    float* __restrict__ xs, unsigned short* __restrict__ xsbf)
{
    __shared__ float4 red[4];
    const int row = blockIdx.x, tid = threadIdx.x;
    const float* yf = yproj + (size_t)row * DMODEL;
    const float* yb = yproj + (size_t)(MTOT + row) * DMODEL;
    const float* xr = x + (size_t)row * DMODEL;

    float vf[2], vb[2];
#pragma unroll
    for (int j = 0; j < 2; ++j) {
        int i = tid + j * 256;
        float xi = xr[i];
        vf[j] = yf[i] + xi;
        vb[j] = yb[i] + xi;
    }
    float4 s = make_float4(vf[0] + vf[1], vf[0] * vf[0] + vf[1] * vf[1],
                           vb[0] + vb[1], vb[0] * vb[0] + vb[1] * vb[1]);
    block_reduce4(s, red, tid);
    const float inv = 1.f / DMODEL;
    float mf = s.x * inv, mb = s.z * inv;
    float rf = rsqrtf(s.y * inv - mf * mf + EPSLN);
    float rb = rsqrtf(s.w * inv - mb * mb + EPSLN);
#pragma unroll
    for (int j = 0; j < 2; ++j) {
        int i = tid + j * 256;
        float a  = (vf[j] - mf) * rf * g1[i] + b1[i];
        float bb = (vb[j] - mb) * rb * g2[i] + b2[i];
        float v = a + bb;
        xs[(size_t)row * DMODEL + i] = v;
        xsbf[(size_t)row * DMODEL + i] = f2bf(v);
    }
}

__global__ __launch_bounds__(256) void ln_final(
    const float* __restrict__ h2, const float* __restrict__ xs,
    const float* __restrict__ g3, const float* __restrict__ b3,
    float* __restrict__ out)
{
    __shared__ float4 red[4];
    const int row = blockIdx.x, tid = threadIdx.x;
    float v[2];
#pragma unroll
    for (int j = 0; j < 2; ++j) {
        int i = tid + j * 256;
        v[j] = h2[(size_t)row * DMODEL + i] + xs[(size_t)row * DMODEL + i];
    }
    float4 s = make_float4(v[0] + v[1], v[0] * v[0] + v[1] * v[1], 0.f, 0.f);
    block_reduce4(s, red, tid);
    const float inv = 1.f / DMODEL;
    float m  = s.x * inv;
    float rs = rsqrtf(s.y * inv - m * m + EPSLN);
#pragma unroll
    for (int j = 0; j < 2; ++j) {
        int i = tid + j * 256;
        out[(size_t)row * DMODEL + i] = (v[j] - m) * rs * g3[i] + b3[i];
    }
}

// ---------------------------------------------------------------------------
extern "C" void kernel_launch(void* const* d_in, const int* in_sizes, int n_in,
                              void* d_out, int out_size, void* d_ws, size_t ws_size,
                              hipStream_t stream)
{
    (void)in_sizes; (void)n_in;

    const float* x    = (const float*)d_in[28];
    const float* n1g  = (const float*)d_in[18];
    const float* n1b  = (const float*)d_in[19];
    const float* n2g  = (const float*)d_in[20];
    const float* n2b  = (const float*)d_in[21];
    const float* n3g  = (const float*)d_in[22];
    const float* n3b  = (const float*)d_in[23];
    const float* ff1w = (const float*)d_in[24];
    const float* ff1b = (const float*)d_in[25];
    const float* ff2w = (const float*)d_in[26];
    const float* ff2b = (const float*)d_in[27];

    // Workspace (same validated 178 MB footprint)
    const size_t need_floats =
        (size_t)MTOT * 2048 + (size_t)MTOT * 1024 + (size_t)MTOT * 1024 +
        (size_t)MTOT * 64 + (size_t)2 * MTOT * 512 + (size_t)MTOT * 512;
    if (ws_size < need_floats * sizeof(float)) return;
    if (out_size < MTOT * DMODEL) return;

    float* ws    = (float*)d_ws;
    float* xz    = ws;                          // MTOT*2048 (xi|z)
    float* xc    = xz    + (size_t)MTOT * 2048; // MTOT*1024
    float* delta = xc    + (size_t)MTOT * 1024; // MTOT*1024
    float* dbc   = delta + (size_t)MTOT * 1024; // MTOT*64
    float* yproj = dbc   + (size_t)MTOT * 64;   // 2*MTOT*512
    float* xs    = yproj + (size_t)2 * MTOT * 512; // MTOT*512

    // Overlays (lifetime-disjoint):
    // xcbf (bf16 xc) overlays delta 1st half: conv->xproj, then dt clobbers.
    // gbf overlays xs (dead until ln_combine). Psum/Ssum overlay yproj[1]
    // (dead until dir-1 out-proj); xpwb overlays Psum start (dead until
    // scan_part1 of same dir). h1bf = delta 1st half, xsbf = delta[4M..6M).
    unsigned short* xcbf = (unsigned short*)delta;
    unsigned short* gbf  = (unsigned short*)xs;
    const size_t SUMN    = (size_t)BATCH * NCH * EDIM * DSTATE;   // 2,097,152
    float* Psum  = yproj + (size_t)MTOT * 512;
    float* Ssum  = Psum + SUMN;
    unsigned short* xpwb = (unsigned short*)Psum;   // per-dir scratch (64K ush)
    unsigned short* h1bf = (unsigned short*)delta;
    unsigned short* xsbf = (unsigned short*)(delta + (size_t)MTOT * 512);
    float* h2 = xc;

    // bf16 cast scratch carved from d_out (dead until ln_final): 16MB exact
    unsigned short* ob     = (unsigned short*)d_out;
    unsigned short* xbf    = ob;                        // 4,194,304
    unsigned short* inwf_b = ob + (size_t)4194304;      // 1,048,576
    unsigned short* inwb_b = ob + (size_t)5242880;      // 1,048,576
    unsigned short* outwf_b= ob + (size_t)6291456;      //   524,288
    unsigned short* outwb_b= ob + (size_t)6815744;      //   524,288
    unsigned short* ff1w_b = ob + (size_t)7340032;      //   524,288
    unsigned short* ff2w_b = ob + (size_t)7864320;      //   524,288

    cast_bf16<<<(MTOT * DMODEL / 8 + 255) / 256, 256, 0, stream>>>(x, xbf, MTOT * DMODEL / 8);
    cast_bf16<<<(2048 * 512 / 8 + 255) / 256, 256, 0, stream>>>((const float*)d_in[0], inwf_b, 2048 * 512 / 8);
    cast_bf16<<<(2048 * 512 / 8 + 255) / 256, 256, 0, stream>>>((const float*)d_in[9], inwb_b, 2048 * 512 / 8);
    cast_bf16<<<(512 * 1024 / 8 + 255) / 256, 256, 0, stream>>>((const float*)d_in[8], outwf_b, 512 * 1024 / 8);
    cast_bf16<<<(512 * 1024 / 8 + 255) / 256, 256, 0, stream>>>((const float*)d_in[17], outwb_b, 512 * 1024 / 8);
    cast_bf16<<<(1024 * 512 / 8 + 255) / 256, 256, 0, stream>>>(ff1w, ff1w_b, 1024 * 512 / 8);
    cast_bf16<<<(512 * 1024 / 8 + 255) / 256, 256, 0, stream>>>(ff2w, ff2w_b, 512 * 1024 / 8);

    for (int dir = 0; dir < 2; ++dir) {
        const float* cw    = (const float*)d_in[dir * 9 + 1];
        const float* cb    = (const float*)d_in[dir * 9 + 2];
        const float* xpw   = (const float*)d_in[dir * 9 + 3];
        const float* dtw   = (const float*)d_in[dir * 9 + 4];
        const float* dtb   = (const float*)d_in[dir * 9 + 5];
        const float* Alog  = (const float*)d_in[dir * 9 + 6];
        const float* Dvec  = (const float*)d_in[dir * 9 + 7];
        const unsigned short* inw_b  = dir ? inwb_b : inwf_b;
        const unsigned short* outw_b = dir ? outwb_b : outwf_b;

        // xz = x(d) @ in_w^T   (M=8192, N=2048, K=512)  [bf16 MFMA v3.1]
        gemm_bf16<<<dim3(2048 / 128, MTOT / 128), 256, 0, stream>>>(
            xbf, DMODEL, inw_b, nullptr, xz, 2048, 0, DMODEL, 0, dir);
        // xc = silu(conv(xi)+cb)  (+ bf16 copy xcbf)
        conv_silu<<<MTOT, 256, 0, stream>>>(xz, cw, cb, xc, xcbf);
        // dbc = xcbf @ xpw^T   (N=64, K=1024)  [bf16 MFMA, split-K=4 + atomics]
        cast_bf16<<<(64 * EDIM / 8 + 255) / 256, 256, 0, stream>>>(xpw, xpwb, 64 * EDIM / 8);
        hipMemsetAsync(dbc, 0, (size_t)MTOT * 64 * sizeof(float), stream);
        xproj_bf16<<<dim3(MTOT / 128, 4), 256, 0, stream>>>(xcbf, xpwb, dbc);
        // delta = softplus(dbc[:, :32] @ dt_w^T + dt_b)  (N=1024, K=32)  [fp32]
        gemm_f32<<<dim3(EDIM / 64, MTOT / 64), 256, 0, stream>>>(
            dbc, 64, dtw, dtb, delta, EDIM, EDIM, DTRANK, 2, 0);
        // chunked parallel scan (16-state-per-lane)
        scan_part1<<<dim3(EDIM / 256, BATCH, NCH), 256, 0, stream>>>(
            delta, xc, dbc, Alog, Psum, Ssum);
        scan_combine<<<(BATCH * EDIM * DSTATE) / 256, 256, 0, stream>>>(
            Psum, Ssum);
        scan_part2<<<dim3(EDIM / 256, BATCH, NCH), 256, 0, stream>>>(
            delta, xc, dbc, Alog, Dvec, xz, Psum, gbf);
        // yproj[dir] = g @ out_w^T   (N=512, K=1024)  [bf16 MFMA v3.1]
        gemm_bf16<<<dim3(512 / 128, MTOT / 128), 256, 0, stream>>>(
            gbf, EDIM, outw_b, nullptr,
            yproj + (size_t)dir * MTOT * DMODEL, DMODEL, 0, EDIM, 0, 0);
    }

    // xs = LN(yf+x)*g1+b1 + LN(yb+x)*g2+b2  (+ bf16 copy)
    ln_combine<<<MTOT, 256, 0, stream>>>(yproj, x, n1g, n1b, n2g, n2b, xs, xsbf);
    // h1bf = relu(xs @ ff1^T + ff1b)  [bf16 MFMA, bf16 out]
    gemm_bf16<<<dim3(DFF / 128, MTOT / 128), 256, 0, stream>>>(
        xsbf, DMODEL, ff1w_b, ff1b, h1bf, DFF, 1, DMODEL, 1, 0);
    // h2 = h1bf @ ff2^T + ff2b  [bf16 MFMA]
    gemm_bf16<<<dim3(DMODEL / 128, MTOT / 128), 256, 0, stream>>>(
        h1bf, DFF, ff2w_b, ff2b, h2, DMODEL, 0, DFF, 0, 0);
    // out = LN(h2 + xs)*g3 + b3
    ln_final<<<MTOT, 256, 0, stream>>>(h2, xs, n3g, n3b, (float*)d_out);
}

// Round 11
// 535.651 us; speedup vs baseline: 3.1713x; 1.0278x over previous
//
#include <hip/hip_runtime.h>
#include <hip/hip_bf16.h>

// Problem constants (fixed by reference)
#define LSEQ   1024
#define BATCH  8
#define MTOT   8192      // B*L
#define DMODEL 512
#define EDIM   1024      // EXPAND*D_MODEL
#define DSTATE 16
#define DTRANK 32
#define DFF    1024
#define EPSLN  1e-5f
#define NCH    16        // scan chunks
#define CHLEN  64        // LSEQ/NCH

typedef __attribute__((ext_vector_type(8))) short bf16x8;
typedef __attribute__((ext_vector_type(4))) float f32x4;

__device__ __forceinline__ unsigned short f2bf(float f) {
    __hip_bfloat16 h = __float2bfloat16(f);   // RNE
    unsigned short u;
    __builtin_memcpy(&u, &h, 2);
    return u;
}

__device__ __forceinline__ float softplusf(float v) {
    return fmaxf(v, 0.f) + log1pf(__expf(-fabsf(v)));
}

// async global->LDS, 16B per lane. LDS dest = wave-uniform base + lane*16.
__device__ __forceinline__ void gload16(const unsigned short* g, unsigned short* l) {
    __builtin_amdgcn_global_load_lds(
        (const __attribute__((address_space(1))) void*)g,
        (__attribute__((address_space(3))) void*)l, 16, 0, 0);
}

// ---------------------------------------------------------------------------
// f32 -> bf16 cast (8 elems/thread)
// ---------------------------------------------------------------------------
__global__ __launch_bounds__(256) void cast_bf16(
    const float* __restrict__ in, unsigned short* __restrict__ out, int n8)
{
    int i = blockIdx.x * 256 + threadIdx.x;
    if (i >= n8) return;
    float4 f0 = *(const float4*)&in[(size_t)i * 8];
    float4 f1 = *(const float4*)&in[(size_t)i * 8 + 4];
    unsigned short v[8] = {f2bf(f0.x), f2bf(f0.y), f2bf(f0.z), f2bf(f0.w),
                           f2bf(f1.x), f2bf(f1.y), f2bf(f1.z), f2bf(f1.w)};
    *(uint4*)&out[(size_t)i * 8] = *(uint4*)v;
}

// ---------------------------------------------------------------------------
// bf16 MFMA GEMM v4: C[M,N] = act(A[M,K] @ W[N,K]^T + bias)
// Tile 128x128, 4 waves (2x2), 4x4 16x16x32 frags. Double-buffered LDS
// [2][128][32] + global_load_lds. 2-phase schedule (T3-minimum, plain HIP):
// per K-step {issue next-tile loads -> compute current -> one __syncthreads}
// so the vmcnt(0) drain at the barrier lands AFTER ~350cy of ds_read+MFMA —
// load latency overlaps compute instead of serializing between two barriers
// (round-10 structure was stage/sync/compute/sync: 67us, MfmaUtil 10%).
// XOR chunk swizzle pc = c ^ ((row>>1)&3) on the GLOBAL address (m173);
// frag reads use the same swizzle -> bank-conflict-free (verified r10: 0).
// Requires K % 64 == 0 (all call sites: 512/1024).
// ---------------------------------------------------------------------------
__global__ __launch_bounds__(256) void gemm_bf16(
    const unsigned short* __restrict__ A, int lda,
    const unsigned short* __restrict__ W,
    const float* __restrict__ bias,
    void* __restrict__ Cp, int ldc, int c_bf16,
    int K, int act, int flip)
{
    __shared__ unsigned short As[2][128][32];
    __shared__ unsigned short Ws[2][128][32];

    const int tid = threadIdx.x;
    const int rowbase = blockIdx.y * 128;
    const int colbase = blockIdx.x * 128;
    const int wave = tid >> 6, lane = tid & 63;
    const int wm = wave >> 1, wn = wave & 1;
    const int lr = lane & 15;
    const int lc = lane >> 4;                 // logical chunk for frag reads

    // staging: rows r0 and r0+64 of both tiles; physical chunk tid&3 holds
    // logical chunk cl (swizzle term identical for r0 and r0+64).
    const int r0 = tid >> 2;
    const int cl = (tid & 3) ^ ((r0 >> 1) & 3);
    int ar0 = rowbase + r0, ar1 = rowbase + r0 + 64;
    if (flip) {
        ar0 = (ar0 & ~(LSEQ - 1)) + (LSEQ - 1 - (ar0 & (LSEQ - 1)));
        ar1 = (ar1 & ~(LSEQ - 1)) + (LSEQ - 1 - (ar1 & (LSEQ - 1)));
    }
    const unsigned short* Ag0 = A + (size_t)ar0 * lda + (cl << 3);
    const unsigned short* Ag1 = A + (size_t)ar1 * lda + (cl << 3);
    const unsigned short* Wg0 = W + (size_t)(colbase + r0) * K + (cl << 3);
    const unsigned short* Wg1 = W + (size_t)(colbase + r0 + 64) * K + (cl << 3);

    f32x4 acc[4][4];
#pragma unroll
    for (int i = 0; i < 4; ++i)
#pragma unroll
        for (int j = 0; j < 4; ++j)
            acc[i][j] = (f32x4){0.f, 0.f, 0.f, 0.f};

#define G_STAGE(bi, ko) do {                                   \
        gload16(Ag0 + (ko), &As[bi][wave << 4][0]);            \
        gload16(Ag1 + (ko), &As[bi][64 + (wave << 4)][0]);     \
        gload16(Wg0 + (ko), &Ws[bi][wave << 4][0]);            \
        gload16(Wg1 + (ko), &Ws[bi][64 + (wave << 4)][0]);     \
    } while (0)

#define G_COMPUTE(bi) do {                                     \
        bf16x8 af[4], bfv[4];                                  \
        _Pragma("unroll")                                      \
        for (int i = 0; i < 4; ++i) {                          \
            int R = wm * 64 + i * 16 + lr;                     \
            int pc = lc ^ ((R >> 1) & 3);                      \
            af[i] = *(const bf16x8*)&As[bi][R][pc << 3];       \
        }                                                      \
        _Pragma("unroll")                                      \
        for (int j = 0; j < 4; ++j) {                          \
            int R = wn * 64 + j * 16 + lr;                     \
            int pc = lc ^ ((R >> 1) & 3);                      \
            bfv[j] = *(const bf16x8*)&Ws[bi][R][pc << 3];      \
        }                                                      \
        _Pragma("unroll")                                      \
        for (int i = 0; i < 4; ++i)                            \
            _Pragma("unroll")                                  \
            for (int j = 0; j < 4; ++j)                        \
                acc[i][j] = __builtin_amdgcn_mfma_f32_16x16x32_bf16( \
                    af[i], bfv[j], acc[i][j], 0, 0, 0);        \
    } while (0)

    // prologue: stage tile 0 into buf 0
    G_STAGE(0, 0);
    __syncthreads();

    for (int k0 = 0; k0 < K; k0 += 64) {
        // even step: stage k0+32 -> buf1 (always valid: K%64==0), compute buf0
        G_STAGE(1, k0 + 32);
        __builtin_amdgcn_sched_barrier(0);   // keep load issue ahead of compute
        G_COMPUTE(0);
        __syncthreads();                     // drains vmcnt -> buf1 ready
        // odd step: stage k0+64 -> buf0 (unless last), compute buf1
        if (k0 + 64 < K) G_STAGE(0, k0 + 64);
        __builtin_amdgcn_sched_barrier(0);
        G_COMPUTE(1);
        __syncthreads();
    }
#undef G_STAGE
#undef G_COMPUTE

    const int crow0 = rowbase + wm * 64 + ((lane >> 4) << 2);
    const int ccol0 = colbase + wn * 64 + lr;
#pragma unroll
    for (int j = 0; j < 4; ++j) {
        int col = ccol0 + j * 16;
        float bv = bias ? bias[col] : 0.f;
#pragma unroll
        for (int i = 0; i < 4; ++i) {
#pragma unroll
            for (int r = 0; r < 4; ++r) {
                int row = crow0 + i * 16 + r;
                float v = acc[i][j][r] + bv;
                if (act == 1) v = fmaxf(v, 0.f);
                if (c_bf16)
                    ((unsigned short*)Cp)[(size_t)row * ldc + col] = f2bf(v);
                else
                    ((float*)Cp)[(size_t)row * ldc + col] = v;
            }
        }
    }
}

// ---------------------------------------------------------------------------
// xproj MFMA with split-K: dbc[M,64] += xcbf[M,1024] @ xpw_b[64,1024]^T
// Tile 128x64, grid (M/128, KSPLIT=4), K-slice 256 per z; same 2-phase
// double-buffered schedule as gemm_bf16. Epilogue atomicAdd (dbc pre-zeroed).
// ---------------------------------------------------------------------------
__global__ __launch_bounds__(256) void xproj_bf16(
    const unsigned short* __restrict__ A,
    const unsigned short* __restrict__ W,
    float* __restrict__ Cp)
{
    __shared__ unsigned short As[2][128][32];
    __shared__ unsigned short Ws[2][64][32];

    const int tid = threadIdx.x;
    const int rowbase = blockIdx.x * 128;
    const int kbase = blockIdx.y * 256;
    const int wave = tid >> 6, lane = tid & 63;
    const int wm = wave >> 1, wn = wave & 1;
    const int lr = lane & 15;
    const int lc = lane >> 4;

    const int r0 = tid >> 2;
    const int cl = (tid & 3) ^ ((r0 >> 1) & 3);    // same for r0 and r0+64
    const unsigned short* Ag0 = A + (size_t)(rowbase + r0) * EDIM + kbase + (cl << 3);
    const unsigned short* Ag1 = A + (size_t)(rowbase + r0 + 64) * EDIM + kbase + (cl << 3);
    const unsigned short* Wg  = W + (size_t)r0 * EDIM + kbase + (cl << 3);

    f32x4 acc[4][2];
#pragma unroll
    for (int i = 0; i < 4; ++i)
#pragma unroll
        for (int j = 0; j < 2; ++j)
            acc[i][j] = (f32x4){0.f, 0.f, 0.f, 0.f};

#define X_STAGE(bi, ko) do {                                   \
        gload16(Ag0 + (ko), &As[bi][wave << 4][0]);            \
        gload16(Ag1 + (ko), &As[bi][64 + (wave << 4)][0]);     \
        gload16(Wg  + (ko), &Ws[bi][wave << 4][0]);            \
    } while (0)

#define X_COMPUTE(bi) do {                                     \
        bf16x8 af[4], bfv[2];                                  \
        _Pragma("unroll")                                      \
        for (int i = 0; i < 4; ++i) {                          \
            int R = wm * 64 + i * 16 + lr;                     \
            int pc = lc ^ ((R >> 1) & 3);                      \
            af[i] = *(const bf16x8*)&As[bi][R][pc << 3];       \
        }                                                      \
        _Pragma("unroll")                                      \
        for (int j = 0; j < 2; ++j) {                          \
            int R = wn * 32 + j * 16 + lr;                     \
            int pc = lc ^ ((R >> 1) & 3);                      \
            bfv[j] = *(const bf16x8*)&Ws[bi][R][pc << 3];      \
        }                                                      \
        _Pragma("unroll")                                      \
        for (int i = 0; i < 4; ++i)                            \
            _Pragma("unroll")                                  \
            for (int j = 0; j < 2; ++j)                        \
                acc[i][j] = __builtin_amdgcn_mfma_f32_16x16x32_bf16( \
                    af[i], bfv[j], acc[i][j], 0, 0, 0);        \
    } while (0)

    X_STAGE(0, 0);
    __syncthreads();

    for (int k0 = 0; k0 < 256; k0 += 64) {
        X_STAGE(1, k0 + 32);
        __builtin_amdgcn_sched_barrier(0);
        X_COMPUTE(0);
        __syncthreads();
        if (k0 + 64 < 256) X_STAGE(0, k0 + 64);
        __builtin_amdgcn_sched_barrier(0);
        X_COMPUTE(1);
        __syncthreads();
    }
#undef X_STAGE
#undef X_COMPUTE

    const int crow0 = rowbase + wm * 64 + ((lane >> 4) << 2);
    const int ccol0 = wn * 32 + lr;
#pragma unroll
    for (int i = 0; i < 4; ++i)
#pragma unroll
        for (int j = 0; j < 2; ++j)
#pragma unroll
            for (int r = 0; r < 4; ++r)
                atomicAdd(&Cp[(size_t)(crow0 + i * 16 + r) * 64 + ccol0 + j * 16],
                          acc[i][j][r]);
}

// ---------------------------------------------------------------------------
// fp32 GEMM (kept for dt: N=1024, K=32, softplus)
// ---------------------------------------------------------------------------
#define LDST 76

__global__ __launch_bounds__(256) void gemm_f32(
    const float* __restrict__ A, int lda,
    const float* __restrict__ W,
    const float* __restrict__ bias,
    float* __restrict__ C, int ldc,
    int N, int K, int act, int flip)
{
    __shared__ float As[32][LDST];
    __shared__ float Ws[32][LDST];

    const int tid = threadIdx.x;
    const int tx = tid & 15;
    const int ty = tid >> 4;
    const int rowbase = blockIdx.y * 64;
    const int colbase = blockIdx.x * 64;

    float c[4][4] = {};

    for (int k0 = 0; k0 < K; k0 += 32) {
#pragma unroll
        for (int it = 0; it < 2; ++it) {
            int q  = tid + it * 256;
            int r  = q >> 3;
            int kc = (q & 7) << 2;
            int ar = rowbase + r;
            if (flip) ar = (ar & ~(LSEQ - 1)) + (LSEQ - 1 - (ar & (LSEQ - 1)));
            float4 av = *(const float4*)&A[(size_t)ar * lda + k0 + kc];
            As[kc + 0][r] = av.x; As[kc + 1][r] = av.y;
            As[kc + 2][r] = av.z; As[kc + 3][r] = av.w;
            int wr = colbase + r;
            float4 wv = *(const float4*)&W[(size_t)wr * K + k0 + kc];
            Ws[kc + 0][r] = wv.x; Ws[kc + 1][r] = wv.y;
            Ws[kc + 2][r] = wv.z; Ws[kc + 3][r] = wv.w;
        }
        __syncthreads();
#pragma unroll
        for (int k = 0; k < 32; ++k) {
            float4 a4 = *(const float4*)&As[k][ty << 2];
            float4 w4 = *(const float4*)&Ws[k][tx << 2];
            float av[4] = {a4.x, a4.y, a4.z, a4.w};
            float wv[4] = {w4.x, w4.y, w4.z, w4.w};
#pragma unroll
            for (int i = 0; i < 4; ++i)
#pragma unroll
                for (int j = 0; j < 4; ++j)
                    c[i][j] = fmaf(av[i], wv[j], c[i][j]);
        }
        __syncthreads();
    }

    float4 bv = make_float4(0.f, 0.f, 0.f, 0.f);
    if (bias) bv = *(const float4*)&bias[colbase + (tx << 2)];
#pragma unroll
    for (int i = 0; i < 4; ++i) {
        float o[4] = {c[i][0] + bv.x, c[i][1] + bv.y, c[i][2] + bv.z, c[i][3] + bv.w};
        if (act == 2) {
#pragma unroll
            for (int j = 0; j < 4; ++j) o[j] = softplusf(o[j]);
        }
        float4 ov = make_float4(o[0], o[1], o[2], o[3]);
        *(float4*)&C[(size_t)(rowbase + (ty << 2) + i) * ldc + colbase + (tx << 2)] = ov;
    }
}

// ---------------------------------------------------------------------------
// Depthwise causal conv (D_CONV=4) + bias + silu; writes f32 xc + bf16 xcbf.
// ---------------------------------------------------------------------------
__global__ __launch_bounds__(256) void conv_silu(
    const float* __restrict__ xz, const float* __restrict__ cw,
    const float* __restrict__ cb, float* __restrict__ xc,
    unsigned short* __restrict__ xcbf)
{
    const int e = threadIdx.x << 2;           // 0..1020
    const int m = blockIdx.x;                 // 0..8191
    const int t = m & (LSEQ - 1);

    float4 w0 = *(const float4*)&cw[e * 4];
    float4 w1 = *(const float4*)&cw[e * 4 + 4];
    float4 w2 = *(const float4*)&cw[e * 4 + 8];
    float4 w3 = *(const float4*)&cw[e * 4 + 12];
    float4 acc = *(const float4*)&cb[e];
#pragma unroll
    for (int k = 0; k < 4; ++k) {
        if (t - 3 + k >= 0) {
            float4 xv = *(const float4*)&xz[(size_t)(m - 3 + k) * 2048 + e];
            acc.x = fmaf((&w0.x)[k], xv.x, acc.x);
            acc.y = fmaf((&w1.x)[k], xv.y, acc.y);
            acc.z = fmaf((&w2.x)[k], xv.z, acc.z);
            acc.w = fmaf((&w3.x)[k], xv.w, acc.w);
        }
    }
    float4 o;
    o.x = acc.x / (1.f + __expf(-acc.x));
    o.y = acc.y / (1.f + __expf(-acc.y));
    o.z = acc.z / (1.f + __expf(-acc.z));
    o.w = acc.w / (1.f + __expf(-acc.w));
    *(float4*)&xc[(size_t)m * EDIM + e] = o;
    unsigned short b4[4] = {f2bf(o.x), f2bf(o.y), f2bf(o.z), f2bf(o.w)};
    *(uint2*)&xcbf[(size_t)m * EDIM + e] = *(uint2*)b4;
}

// ---------------------------------------------------------------------------
// Chunked selective scan, lane = channel e, 16 states in registers.
// ---------------------------------------------------------------------------
__global__ __launch_bounds__(256) void scan_part1(
    const float* __restrict__ delta, const float* __restrict__ xc,
    const float* __restrict__ dbc, const float* __restrict__ Alog,
    float* __restrict__ Psum, float* __restrict__ Ssum)
{
    __shared__ float sB[CHLEN][16];

    const int b  = blockIdx.y;
    const int ch = blockIdx.z;
    const int tid = threadIdx.x;
    const int e  = blockIdx.x * 256 + tid;
    const int row0 = b * LSEQ + ch * CHLEN;

#pragma unroll
    for (int it = 0; it < 4; ++it) {
        int q = tid + it * 256;
        int t = q >> 4, n = q & 15;
        sB[t][n] = dbc[(size_t)(row0 + t) * 64 + 32 + n];
    }

    float Aen[16];
#pragma unroll
    for (int k = 0; k < 4; ++k) {
        float4 a4 = *(const float4*)&Alog[e * DSTATE + k * 4];
        Aen[k * 4 + 0] = -__expf(a4.x);
        Aen[k * 4 + 1] = -__expf(a4.y);
        Aen[k * 4 + 2] = -__expf(a4.z);
        Aen[k * 4 + 3] = -__expf(a4.w);
    }

    float h[16];
#pragma unroll
    for (int n = 0; n < 16; ++n) h[n] = 0.f;
    float sumd = 0.f;

    __syncthreads();

    const size_t base = (size_t)row0 * EDIM + e;
    float dnx = delta[base];
    float xnx = xc[base];

    for (int t = 0; t < CHLEN; ++t) {
        float d = dnx, xcv = xnx;
        if (t + 1 < CHLEN) {
            dnx = delta[base + (size_t)(t + 1) * EDIM];
            xnx = xc[base + (size_t)(t + 1) * EDIM];
        }
        sumd += d;
        float dx = d * xcv;
        float Bt[16];
        *(float4*)&Bt[0]  = *(const float4*)&sB[t][0];
        *(float4*)&Bt[4]  = *(const float4*)&sB[t][4];
        *(float4*)&Bt[8]  = *(const float4*)&sB[t][8];
        *(float4*)&Bt[12] = *(const float4*)&sB[t][12];
#pragma unroll
        for (int n = 0; n < 16; ++n) {
            float da = __expf(d * Aen[n]);
            h[n] = fmaf(da, h[n], dx * Bt[n]);
        }
    }

    size_t idx = ((size_t)((b * NCH + ch) * EDIM + e)) * DSTATE;
    float P[16];
#pragma unroll
    for (int n = 0; n < 16; ++n) P[n] = __expf(Aen[n] * sumd);
#pragma unroll
    for (int k = 0; k < 4; ++k) {
        *(float4*)&Psum[idx + k * 4] = *(float4*)&P[k * 4];
        *(float4*)&Ssum[idx + k * 4] = *(float4*)&h[k * 4];
    }
}

__global__ __launch_bounds__(256) void scan_combine(
    float* __restrict__ Psum, const float* __restrict__ Ssum)
{
    int i = blockIdx.x * 256 + threadIdx.x;       // 0 .. B*ED*DS-1
    int b = i >> 14;
    int r = i & 16383;                            // e*16+n
    float H = 0.f;
#pragma unroll
    for (int ch = 0; ch < NCH; ++ch) {
        size_t idx = ((size_t)(b * NCH + ch) << 14) + r;
        float p = Psum[idx];
        float s = Ssum[idx];
        Psum[idx] = H;                            // Hstart for this chunk
        H = fmaf(p, H, s);
    }
}

__global__ __launch_bounds__(256) void scan_part2(
    const float* __restrict__ delta, const float* __restrict__ xc,
    const float* __restrict__ dbc, const float* __restrict__ Alog,
    const float* __restrict__ Dvec, const float* __restrict__ xzbuf,
    const float* __restrict__ Hstart, unsigned short* __restrict__ gbf)
{
    __shared__ float sB[CHLEN][16], sC[CHLEN][16];

    const int b  = blockIdx.y;
    const int ch = blockIdx.z;
    const int tid = threadIdx.x;
    const int e  = blockIdx.x * 256 + tid;
    const int row0 = b * LSEQ + ch * CHLEN;

#pragma unroll
    for (int it = 0; it < 8; ++it) {
        int q = tid + it * 256;
        int t = q >> 5, c = q & 31;
        float v = dbc[(size_t)(row0 + t) * 64 + 32 + c];
        if (c < 16) sB[t][c] = v; else sC[t][c - 16] = v;
    }

    float Aen[16];
#pragma unroll
    for (int k = 0; k < 4; ++k) {
        float4 a4 = *(const float4*)&Alog[e * DSTATE + k * 4];
        Aen[k * 4 + 0] = -__expf(a4.x);
        Aen[k * 4 + 1] = -__expf(a4.y);
        Aen[k * 4 + 2] = -__expf(a4.z);
        Aen[k * 4 + 3] = -__expf(a4.w);
    }
    const float Dv = Dvec[e];

    float h[16];
    {
        size_t idx = ((size_t)((b * NCH + ch) * EDIM + e)) * DSTATE;
#pragma unroll
        for (int k = 0; k < 4; ++k)
            *(float4*)&h[k * 4] = *(const float4*)&Hstart[idx + k * 4];
    }

    __syncthreads();

    const size_t base = (size_t)row0 * EDIM + e;
    const size_t zbase = (size_t)row0 * 2048 + 1024 + e;
    float dnx = delta[base];
    float xnx = xc[base];
    float znx = xzbuf[zbase];

    for (int t = 0; t < CHLEN; ++t) {
        float d = dnx, xcv = xnx, zv = znx;
        if (t + 1 < CHLEN) {
            dnx = delta[base + (size_t)(t + 1) * EDIM];
            xnx = xc[base + (size_t)(t + 1) * EDIM];
            znx = xzbuf[zbase + (size_t)(t + 1) * 2048];
        }
        float dx = d * xcv;
        float Bt[16], Ct[16];
        *(float4*)&Bt[0]  = *(const float4*)&sB[t][0];
        *(float4*)&Bt[4]  = *(const float4*)&sB[t][4];
        *(float4*)&Bt[8]  = *(const float4*)&sB[t][8];
        *(float4*)&Bt[12] = *(const float4*)&sB[t][12];
        *(float4*)&Ct[0]  = *(const float4*)&sC[t][0];
        *(float4*)&Ct[4]  = *(const float4*)&sC[t][4];
        *(float4*)&Ct[8]  = *(const float4*)&sC[t][8];
        *(float4*)&Ct[12] = *(const float4*)&sC[t][12];
        float y = 0.f;
#pragma unroll
        for (int n = 0; n < 16; ++n) {
            float da = __expf(d * Aen[n]);
            h[n] = fmaf(da, h[n], dx * Bt[n]);
            y = fmaf(h[n], Ct[n], y);
        }
        y = fmaf(Dv, xcv, y);
        float sig = 1.f / (1.f + __expf(-zv));
        float zz  = zv * sig;
        gbf[(size_t)(row0 + t) * EDIM + e] = f2bf(fmaf(zz, y - xcv, xcv));
    }
}

// ---------------------------------------------------------------------------
__device__ __forceinline__ void block_reduce4(float4& s, float4* red, int tid)
{
#pragma unroll
    for (int off = 1; off < 64; off <<= 1) {
        s.x += __shfl_xor(s.x, off);
        s.y += __shfl_xor(s.y, off);
        s.z += __shfl_xor(s.z, off);
        s.w += __shfl_xor(s.w, off);
    }
    if ((tid & 63) == 0) red[tid >> 6] = s;
    __syncthreads();
    float4 a = red[0], b = red[1], c = red[2], d = red[3];
    s.x = a.x + b.x + c.x + d.x;
    s.y = a.y + b.y + c.y + d.y;
    s.z = a.z + b.z + c.z + d.z;
    s.w = a.w + b.w + c.w + d.w;
}

__global__ __launch_bounds__(256) void ln_combine(
    const float* __restrict__ yproj, const float* __restrict__ x,
    const float* __restrict__ g1, const float* __restrict__ b1,
    const float* __restrict__ g2, const float* __restrict__ b2,
    float* __restrict__ xs, unsigned short* __restrict__ xsbf)
{
    __shared__ float4 red[4];
    const int row = blockIdx.x, tid = threadIdx.x;
    const float* yf = yproj + (size_t)row * DMODEL;
    const float* yb = yproj + (size_t)(MTOT + row) * DMODEL;
    const float* xr = x + (size_t)row * DMODEL;

    float vf[2], vb[2];
#pragma unroll
    for (int j = 0; j < 2; ++j) {
        int i = tid + j * 256;
        float xi = xr[i];
        vf[j] = yf[i] + xi;
        vb[j] = yb[i] + xi;
    }
    float4 s = make_float4(vf[0] + vf[1], vf[0] * vf[0] + vf[1] * vf[1],
                           vb[0] + vb[1], vb[0] * vb[0] + vb[1] * vb[1]);
    block_reduce4(s, red, tid);
    const float inv = 1.f / DMODEL;
    float mf = s.x * inv, mb = s.z * inv;
    float rf = rsqrtf(s.y * inv - mf * mf + EPSLN);
    float rb = rsqrtf(s.w * inv - mb * mb + EPSLN);
#pragma unroll
    for (int j = 0; j < 2; ++j) {
        int i = tid + j * 256;
        float a  = (vf[j] - mf) * rf * g1[i] + b1[i];
        float bb = (vb[j] - mb) * rb * g2[i] + b2[i];
        float v = a + bb;
        xs[(size_t)row * DMODEL + i] = v;
        xsbf[(size_t)row * DMODEL + i] = f2bf(v);
    }
}

__global__ __launch_bounds__(256) void ln_final(
    const float* __restrict__ h2, const float* __restrict__ xs,
    const float* __restrict__ g3, const float* __restrict__ b3,
    float* __restrict__ out)
{
    __shared__ float4 red[4];
    const int row = blockIdx.x, tid = threadIdx.x;
    float v[2];
#pragma unroll
    for (int j = 0; j < 2; ++j) {
        int i = tid + j * 256;
        v[j] = h2[(size_t)row * DMODEL + i] + xs[(size_t)row * DMODEL + i];
    }
    float4 s = make_float4(v[0] + v[1], v[0] * v[0] + v[1] * v[1], 0.f, 0.f);
    block_reduce4(s, red, tid);
    const float inv = 1.f / DMODEL;
    float m  = s.x * inv;
    float rs = rsqrtf(s.y * inv - m * m + EPSLN);
#pragma unroll
    for (int j = 0; j < 2; ++j) {
        int i = tid + j * 256;
        out[(size_t)row * DMODEL + i] = (v[j] - m) * rs * g3[i] + b3[i];
    }
}

// ---------------------------------------------------------------------------
extern "C" void kernel_launch(void* const* d_in, const int* in_sizes, int n_in,
                              void* d_out, int out_size, void* d_ws, size_t ws_size,
                              hipStream_t stream)
{
    (void)in_sizes; (void)n_in;

    const float* x    = (const float*)d_in[28];
    const float* n1g  = (const float*)d_in[18];
    const float* n1b  = (const float*)d_in[19];
    const float* n2g  = (const float*)d_in[20];
    const float* n2b  = (const float*)d_in[21];
    const float* n3g  = (const float*)d_in[22];
    const float* n3b  = (const float*)d_in[23];
    const float* ff1w = (const float*)d_in[24];
    const float* ff1b = (const float*)d_in[25];
    const float* ff2w = (const float*)d_in[26];
    const float* ff2b = (const float*)d_in[27];

    // Workspace (same validated 178 MB footprint)
    const size_t need_floats =
        (size_t)MTOT * 2048 + (size_t)MTOT * 1024 + (size_t)MTOT * 1024 +
        (size_t)MTOT * 64 + (size_t)2 * MTOT * 512 + (size_t)MTOT * 512;
    if (ws_size < need_floats * sizeof(float)) return;
    if (out_size < MTOT * DMODEL) return;

    float* ws    = (float*)d_ws;
    float* xz    = ws;                          // MTOT*2048 (xi|z)
    float* xc    = xz    + (size_t)MTOT * 2048; // MTOT*1024
    float* delta = xc    + (size_t)MTOT * 1024; // MTOT*1024
    float* dbc   = delta + (size_t)MTOT * 1024; // MTOT*64
    float* yproj = dbc   + (size_t)MTOT * 64;   // 2*MTOT*512
    float* xs    = yproj + (size_t)2 * MTOT * 512; // MTOT*512

    // Overlays (lifetime-disjoint):
    // xcbf (bf16 xc) overlays delta 1st half: conv->xproj, then dt clobbers.
    // gbf overlays xs (dead until ln_combine). Psum/Ssum overlay yproj[1]
    // (dead until dir-1 out-proj); xpwb overlays Psum start (dead until
    // scan_part1 of same dir). h1bf = delta 1st half, xsbf = delta[4M..6M).
    unsigned short* xcbf = (unsigned short*)delta;
    unsigned short* gbf  = (unsigned short*)xs;
    const size_t SUMN    = (size_t)BATCH * NCH * EDIM * DSTATE;   // 2,097,152
    float* Psum  = yproj + (size_t)MTOT * 512;
    float* Ssum  = Psum + SUMN;
    unsigned short* xpwb = (unsigned short*)Psum;   // per-dir scratch (64K ush)
    unsigned short* h1bf = (unsigned short*)delta;
    unsigned short* xsbf = (unsigned short*)(delta + (size_t)MTOT * 512);
    float* h2 = xc;

    // bf16 cast scratch carved from d_out (dead until ln_final): 16MB exact
    unsigned short* ob     = (unsigned short*)d_out;
    unsigned short* xbf    = ob;                        // 4,194,304
    unsigned short* inwf_b = ob + (size_t)4194304;      // 1,048,576
    unsigned short* inwb_b = ob + (size_t)5242880;      // 1,048,576
    unsigned short* outwf_b= ob + (size_t)6291456;      //   524,288
    unsigned short* outwb_b= ob + (size_t)6815744;      //   524,288
    unsigned short* ff1w_b = ob + (size_t)7340032;      //   524,288
    unsigned short* ff2w_b = ob + (size_t)7864320;      //   524,288

    cast_bf16<<<(MTOT * DMODEL / 8 + 255) / 256, 256, 0, stream>>>(x, xbf, MTOT * DMODEL / 8);
    cast_bf16<<<(2048 * 512 / 8 + 255) / 256, 256, 0, stream>>>((const float*)d_in[0], inwf_b, 2048 * 512 / 8);
    cast_bf16<<<(2048 * 512 / 8 + 255) / 256, 256, 0, stream>>>((const float*)d_in[9], inwb_b, 2048 * 512 / 8);
    cast_bf16<<<(512 * 1024 / 8 + 255) / 256, 256, 0, stream>>>((const float*)d_in[8], outwf_b, 512 * 1024 / 8);
    cast_bf16<<<(512 * 1024 / 8 + 255) / 256, 256, 0, stream>>>((const float*)d_in[17], outwb_b, 512 * 1024 / 8);
    cast_bf16<<<(1024 * 512 / 8 + 255) / 256, 256, 0, stream>>>(ff1w, ff1w_b, 1024 * 512 / 8);
    cast_bf16<<<(512 * 1024 / 8 + 255) / 256, 256, 0, stream>>>(ff2w, ff2w_b, 512 * 1024 / 8);

    for (int dir = 0; dir < 2; ++dir) {
        const float* cw    = (const float*)d_in[dir * 9 + 1];
        const float* cb    = (const float*)d_in[dir * 9 + 2];
        const float* xpw   = (const float*)d_in[dir * 9 + 3];
        const float* dtw   = (const float*)d_in[dir * 9 + 4];
        const float* dtb   = (const float*)d_in[dir * 9 + 5];
        const float* Alog  = (const float*)d_in[dir * 9 + 6];
        const float* Dvec  = (const float*)d_in[dir * 9 + 7];
        const unsigned short* inw_b  = dir ? inwb_b : inwf_b;
        const unsigned short* outw_b = dir ? outwb_b : outwf_b;

        // xz = x(d) @ in_w^T   (M=8192, N=2048, K=512)  [bf16 MFMA v4]
        gemm_bf16<<<dim3(2048 / 128, MTOT / 128), 256, 0, stream>>>(
            xbf, DMODEL, inw_b, nullptr, xz, 2048, 0, DMODEL, 0, dir);
        // xc = silu(conv(xi)+cb)  (+ bf16 copy xcbf)
        conv_silu<<<MTOT, 256, 0, stream>>>(xz, cw, cb, xc, xcbf);
        // dbc = xcbf @ xpw^T   (N=64, K=1024)  [bf16 MFMA, split-K=4 + atomics]
        cast_bf16<<<(64 * EDIM / 8 + 255) / 256, 256, 0, stream>>>(xpw, xpwb, 64 * EDIM / 8);
        hipMemsetAsync(dbc, 0, (size_t)MTOT * 64 * sizeof(float), stream);
        xproj_bf16<<<dim3(MTOT / 128, 4), 256, 0, stream>>>(xcbf, xpwb, dbc);
        // delta = softplus(dbc[:, :32] @ dt_w^T + dt_b)  (N=1024, K=32)  [fp32]
        gemm_f32<<<dim3(EDIM / 64, MTOT / 64), 256, 0, stream>>>(
            dbc, 64, dtw, dtb, delta, EDIM, EDIM, DTRANK, 2, 0);
        // chunked parallel scan (16-state-per-lane)
        scan_part1<<<dim3(EDIM / 256, BATCH, NCH), 256, 0, stream>>>(
            delta, xc, dbc, Alog, Psum, Ssum);
        scan_combine<<<(BATCH * EDIM * DSTATE) / 256, 256, 0, stream>>>(
            Psum, Ssum);
        scan_part2<<<dim3(EDIM / 256, BATCH, NCH), 256, 0, stream>>>(
            delta, xc, dbc, Alog, Dvec, xz, Psum, gbf);
        // yproj[dir] = g @ out_w^T   (N=512, K=1024)  [bf16 MFMA v4]
        gemm_bf16<<<dim3(512 / 128, MTOT / 128), 256, 0, stream>>>(
            gbf, EDIM, outw_b, nullptr,
            yproj + (size_t)dir * MTOT * DMODEL, DMODEL, 0, EDIM, 0, 0);
    }

    // xs = LN(yf+x)*g1+b1 + LN(yb+x)*g2+b2  (+ bf16 copy)
    ln_combine<<<MTOT, 256, 0, stream>>>(yproj, x, n1g, n1b, n2g, n2b, xs, xsbf);
    // h1bf = relu(xs @ ff1^T + ff1b)  [bf16 MFMA, bf16 out]
    gemm_bf16<<<dim3(DFF / 128, MTOT / 128), 256, 0, stream>>>(
        xsbf, DMODEL, ff1w_b, ff1b, h1bf, DFF, 1, DMODEL, 1, 0);
    // h2 = h1bf @ ff2^T + ff2b  [bf16 MFMA]
    gemm_bf16<<<dim3(DMODEL / 128, MTOT / 128), 256, 0, stream>>>(
        h1bf, DFF, ff2w_b, ff2b, h2, DMODEL, 0, DFF, 0, 0);
    // out = LN(h2 + xs)*g3 + b3
    ln_final<<<MTOT, 256, 0, stream>>>(h2, xs, n3g, n3b, (float*)d_out);
}

// Round 12
// 497.162 us; speedup vs baseline: 3.4168x; 1.0774x over previous
//
#include <hip/hip_runtime.h>
#include <hip/hip_bf16.h>

// Problem constants (fixed by reference)
#define LSEQ   1024
#define BATCH  8
#define MTOT   8192      // B*L
#define DMODEL 512
#define EDIM   1024      // EXPAND*D_MODEL
#define DSTATE 16
#define DTRANK 32
#define DFF    1024
#define EPSLN  1e-5f
#define NCH    16        // scan chunks
#define CHLEN  64        // LSEQ/NCH

typedef __attribute__((ext_vector_type(8))) short bf16x8;
typedef __attribute__((ext_vector_type(4))) float f32x4;

__device__ __forceinline__ unsigned short f2bf(float f) {
    __hip_bfloat16 h = __float2bfloat16(f);   // RNE
    unsigned short u;
    __builtin_memcpy(&u, &h, 2);
    return u;
}
__device__ __forceinline__ float bf2f(unsigned short u) {
    unsigned int x = ((unsigned int)u) << 16;
    float f;
    __builtin_memcpy(&f, &x, 4);
    return f;
}

__device__ __forceinline__ float softplusf(float v) {
    return fmaxf(v, 0.f) + log1pf(__expf(-fabsf(v)));
}

// async global->LDS, 16B per lane. LDS dest = wave-uniform base + lane*16.
__device__ __forceinline__ void gload16(const unsigned short* g, unsigned short* l) {
    __builtin_amdgcn_global_load_lds(
        (const __attribute__((address_space(1))) void*)g,
        (__attribute__((address_space(3))) void*)l, 16, 0, 0);
}

// ---------------------------------------------------------------------------
// f32 -> bf16 cast (8 elems/thread)
// ---------------------------------------------------------------------------
__global__ __launch_bounds__(256) void cast_bf16(
    const float* __restrict__ in, unsigned short* __restrict__ out, int n8)
{
    int i = blockIdx.x * 256 + threadIdx.x;
    if (i >= n8) return;
    float4 f0 = *(const float4*)&in[(size_t)i * 8];
    float4 f1 = *(const float4*)&in[(size_t)i * 8 + 4];
    unsigned short v[8] = {f2bf(f0.x), f2bf(f0.y), f2bf(f0.z), f2bf(f0.w),
                           f2bf(f1.x), f2bf(f1.y), f2bf(f1.z), f2bf(f1.w)};
    *(uint4*)&out[(size_t)i * 8] = *(uint4*)v;
}

// ---------------------------------------------------------------------------
// Fused dual-direction in-projection: for blocks with colg<2048 compute
// x @ W_f^T -> Cf[m]; for colg>=2048 compute x @ W_b^T -> Cb[flip(m)]
// (flip the WRITE, share unflipped A: x[flip(m)]@W == store x[m]@W at flip(m)).
// Same v4 structure: 128x128 tile, dbuf LDS, global_load_lds, XOR swizzle,
// 2-phase schedule. C written bf16. K=512.
// ---------------------------------------------------------------------------
__global__ __launch_bounds__(256) void inproj_bf16(
    const unsigned short* __restrict__ A,
    const unsigned short* __restrict__ Wf,
    const unsigned short* __restrict__ Wb,
    unsigned short* __restrict__ Cf,
    unsigned short* __restrict__ Cb)
{
    __shared__ unsigned short As[2][128][32];
    __shared__ unsigned short Ws[2][128][32];

    const int K = DMODEL;                     // 512
    const int tid = threadIdx.x;
    const int rowbase = blockIdx.y * 128;
    const int colg = blockIdx.x * 128;        // 0..4095
    const int back = colg >= 2048;
    const unsigned short* W = back ? Wb : Wf;
    const int colbase = colg - (back ? 2048 : 0);
    unsigned short* Cout = back ? Cb : Cf;

    const int wave = tid >> 6, lane = tid & 63;
    const int wm = wave >> 1, wn = wave & 1;
    const int lr = lane & 15;
    const int lc = lane >> 4;

    const int r0 = tid >> 2;
    const int cl = (tid & 3) ^ ((r0 >> 1) & 3);
    const unsigned short* Ag0 = A + (size_t)(rowbase + r0) * K + (cl << 3);
    const unsigned short* Ag1 = A + (size_t)(rowbase + r0 + 64) * K + (cl << 3);
    const unsigned short* Wg0 = W + (size_t)(colbase + r0) * K + (cl << 3);
    const unsigned short* Wg1 = W + (size_t)(colbase + r0 + 64) * K + (cl << 3);

    f32x4 acc[4][4];
#pragma unroll
    for (int i = 0; i < 4; ++i)
#pragma unroll
        for (int j = 0; j < 4; ++j)
            acc[i][j] = (f32x4){0.f, 0.f, 0.f, 0.f};

#define G_STAGE(bi, ko) do {                                   \
        gload16(Ag0 + (ko), &As[bi][wave << 4][0]);            \
        gload16(Ag1 + (ko), &As[bi][64 + (wave << 4)][0]);     \
        gload16(Wg0 + (ko), &Ws[bi][wave << 4][0]);            \
        gload16(Wg1 + (ko), &Ws[bi][64 + (wave << 4)][0]);     \
    } while (0)

#define G_COMPUTE(bi) do {                                     \
        bf16x8 af[4], bfv[4];                                  \
        _Pragma("unroll")                                      \
        for (int i = 0; i < 4; ++i) {                          \
            int R = wm * 64 + i * 16 + lr;                     \
            int pc = lc ^ ((R >> 1) & 3);                      \
            af[i] = *(const bf16x8*)&As[bi][R][pc << 3];       \
        }                                                      \
        _Pragma("unroll")                                      \
        for (int j = 0; j < 4; ++j) {                          \
            int R = wn * 64 + j * 16 + lr;                     \
            int pc = lc ^ ((R >> 1) & 3);                      \
            bfv[j] = *(const bf16x8*)&Ws[bi][R][pc << 3];      \
        }                                                      \
        _Pragma("unroll")                                      \
        for (int i = 0; i < 4; ++i)                            \
            _Pragma("unroll")                                  \
            for (int j = 0; j < 4; ++j)                        \
                acc[i][j] = __builtin_amdgcn_mfma_f32_16x16x32_bf16( \
                    af[i], bfv[j], acc[i][j], 0, 0, 0);        \
    } while (0)

    G_STAGE(0, 0);
    __syncthreads();
    for (int k0 = 0; k0 < K; k0 += 64) {
        G_STAGE(1, k0 + 32);
        __builtin_amdgcn_sched_barrier(0);
        G_COMPUTE(0);
        __syncthreads();
        if (k0 + 64 < K) G_STAGE(0, k0 + 64);
        __builtin_amdgcn_sched_barrier(0);
        G_COMPUTE(1);
        __syncthreads();
    }
#undef G_STAGE
#undef G_COMPUTE

    const int crow0 = rowbase + wm * 64 + ((lane >> 4) << 2);
    const int ccol0 = colbase + wn * 64 + lr;
#pragma unroll
    for (int j = 0; j < 4; ++j) {
        int col = ccol0 + j * 16;
#pragma unroll
        for (int i = 0; i < 4; ++i) {
#pragma unroll
            for (int r = 0; r < 4; ++r) {
                int row = crow0 + i * 16 + r;
                if (back) row = (row & ~(LSEQ - 1)) + (LSEQ - 1 - (row & (LSEQ - 1)));
                Cout[(size_t)row * 2048 + col] = f2bf(acc[i][j][r]);
            }
        }
    }
}

// ---------------------------------------------------------------------------
// bf16 MFMA GEMM v4 (out-proj / ff1 / ff2): C = act(A @ W^T + bias)
// 128x128 tile, dbuf LDS, global_load_lds, XOR swizzle, 2-phase. K%64==0.
// ---------------------------------------------------------------------------
__global__ __launch_bounds__(256) void gemm_bf16(
    const unsigned short* __restrict__ A, int lda,
    const unsigned short* __restrict__ W,
    const float* __restrict__ bias,
    void* __restrict__ Cp, int ldc, int c_bf16,
    int K, int act)
{
    __shared__ unsigned short As[2][128][32];
    __shared__ unsigned short Ws[2][128][32];

    const int tid = threadIdx.x;
    const int rowbase = blockIdx.y * 128;
    const int colbase = blockIdx.x * 128;
    const int wave = tid >> 6, lane = tid & 63;
    const int wm = wave >> 1, wn = wave & 1;
    const int lr = lane & 15;
    const int lc = lane >> 4;

    const int r0 = tid >> 2;
    const int cl = (tid & 3) ^ ((r0 >> 1) & 3);
    const unsigned short* Ag0 = A + (size_t)(rowbase + r0) * lda + (cl << 3);
    const unsigned short* Ag1 = A + (size_t)(rowbase + r0 + 64) * lda + (cl << 3);
    const unsigned short* Wg0 = W + (size_t)(colbase + r0) * K + (cl << 3);
    const unsigned short* Wg1 = W + (size_t)(colbase + r0 + 64) * K + (cl << 3);

    f32x4 acc[4][4];
#pragma unroll
    for (int i = 0; i < 4; ++i)
#pragma unroll
        for (int j = 0; j < 4; ++j)
            acc[i][j] = (f32x4){0.f, 0.f, 0.f, 0.f};

#define G_STAGE(bi, ko) do {                                   \
        gload16(Ag0 + (ko), &As[bi][wave << 4][0]);            \
        gload16(Ag1 + (ko), &As[bi][64 + (wave << 4)][0]);     \
        gload16(Wg0 + (ko), &Ws[bi][wave << 4][0]);            \
        gload16(Wg1 + (ko), &Ws[bi][64 + (wave << 4)][0]);     \
    } while (0)

#define G_COMPUTE(bi) do {                                     \
        bf16x8 af[4], bfv[4];                                  \
        _Pragma("unroll")                                      \
        for (int i = 0; i < 4; ++i) {                          \
            int R = wm * 64 + i * 16 + lr;                     \
            int pc = lc ^ ((R >> 1) & 3);                      \
            af[i] = *(const bf16x8*)&As[bi][R][pc << 3];       \
        }                                                      \
        _Pragma("unroll")                                      \
        for (int j = 0; j < 4; ++j) {                          \
            int R = wn * 64 + j * 16 + lr;                     \
            int pc = lc ^ ((R >> 1) & 3);                      \
            bfv[j] = *(const bf16x8*)&Ws[bi][R][pc << 3];      \
        }                                                      \
        _Pragma("unroll")                                      \
        for (int i = 0; i < 4; ++i)                            \
            _Pragma("unroll")                                  \
            for (int j = 0; j < 4; ++j)                        \
                acc[i][j] = __builtin_amdgcn_mfma_f32_16x16x32_bf16( \
                    af[i], bfv[j], acc[i][j], 0, 0, 0);        \
    } while (0)

    G_STAGE(0, 0);
    __syncthreads();
    for (int k0 = 0; k0 < K; k0 += 64) {
        G_STAGE(1, k0 + 32);
        __builtin_amdgcn_sched_barrier(0);
        G_COMPUTE(0);
        __syncthreads();
        if (k0 + 64 < K) G_STAGE(0, k0 + 64);
        __builtin_amdgcn_sched_barrier(0);
        G_COMPUTE(1);
        __syncthreads();
    }
#undef G_STAGE
#undef G_COMPUTE

    const int crow0 = rowbase + wm * 64 + ((lane >> 4) << 2);
    const int ccol0 = colbase + wn * 64 + lr;
#pragma unroll
    for (int j = 0; j < 4; ++j) {
        int col = ccol0 + j * 16;
        float bv = bias ? bias[col] : 0.f;
#pragma unroll
        for (int i = 0; i < 4; ++i) {
#pragma unroll
            for (int r = 0; r < 4; ++r) {
                int row = crow0 + i * 16 + r;
                float v = acc[i][j][r] + bv;
                if (act == 1) v = fmaxf(v, 0.f);
                if (c_bf16)
                    ((unsigned short*)Cp)[(size_t)row * ldc + col] = f2bf(v);
                else
                    ((float*)Cp)[(size_t)row * ldc + col] = v;
            }
        }
    }
}

// ---------------------------------------------------------------------------
// xproj MFMA with split-K: dbc[M,64] += xcbf[M,1024] @ xpw_b[64,1024]^T
// ---------------------------------------------------------------------------
__global__ __launch_bounds__(256) void xproj_bf16(
    const unsigned short* __restrict__ A,
    const unsigned short* __restrict__ W,
    float* __restrict__ Cp)
{
    __shared__ unsigned short As[2][128][32];
    __shared__ unsigned short Ws[2][64][32];

    const int tid = threadIdx.x;
    const int rowbase = blockIdx.x * 128;
    const int kbase = blockIdx.y * 256;
    const int wave = tid >> 6, lane = tid & 63;
    const int wm = wave >> 1, wn = wave & 1;
    const int lr = lane & 15;
    const int lc = lane >> 4;

    const int r0 = tid >> 2;
    const int cl = (tid & 3) ^ ((r0 >> 1) & 3);
    const unsigned short* Ag0 = A + (size_t)(rowbase + r0) * EDIM + kbase + (cl << 3);
    const unsigned short* Ag1 = A + (size_t)(rowbase + r0 + 64) * EDIM + kbase + (cl << 3);
    const unsigned short* Wg  = W + (size_t)r0 * EDIM + kbase + (cl << 3);

    f32x4 acc[4][2];
#pragma unroll
    for (int i = 0; i < 4; ++i)
#pragma unroll
        for (int j = 0; j < 2; ++j)
            acc[i][j] = (f32x4){0.f, 0.f, 0.f, 0.f};

#define X_STAGE(bi, ko) do {                                   \
        gload16(Ag0 + (ko), &As[bi][wave << 4][0]);            \
        gload16(Ag1 + (ko), &As[bi][64 + (wave << 4)][0]);     \
        gload16(Wg  + (ko), &Ws[bi][wave << 4][0]);            \
    } while (0)

#define X_COMPUTE(bi) do {                                     \
        bf16x8 af[4], bfv[2];                                  \
        _Pragma("unroll")                                      \
        for (int i = 0; i < 4; ++i) {                          \
            int R = wm * 64 + i * 16 + lr;                     \
            int pc = lc ^ ((R >> 1) & 3);                      \
            af[i] = *(const bf16x8*)&As[bi][R][pc << 3];       \
        }                                                      \
        _Pragma("unroll")                                      \
        for (int j = 0; j < 2; ++j) {                          \
            int R = wn * 32 + j * 16 + lr;                     \
            int pc = lc ^ ((R >> 1) & 3);                      \
            bfv[j] = *(const bf16x8*)&Ws[bi][R][pc << 3];      \
        }                                                      \
        _Pragma("unroll")                                      \
        for (int i = 0; i < 4; ++i)                            \
            _Pragma("unroll")                                  \
            for (int j = 0; j < 2; ++j)                        \
                acc[i][j] = __builtin_amdgcn_mfma_f32_16x16x32_bf16( \
                    af[i], bfv[j], acc[i][j], 0, 0, 0);        \
    } while (0)

    X_STAGE(0, 0);
    __syncthreads();
    for (int k0 = 0; k0 < 256; k0 += 64) {
        X_STAGE(1, k0 + 32);
        __builtin_amdgcn_sched_barrier(0);
        X_COMPUTE(0);
        __syncthreads();
        if (k0 + 64 < 256) X_STAGE(0, k0 + 64);
        __builtin_amdgcn_sched_barrier(0);
        X_COMPUTE(1);
        __syncthreads();
    }
#undef X_STAGE
#undef X_COMPUTE

    const int crow0 = rowbase + wm * 64 + ((lane >> 4) << 2);
    const int ccol0 = wn * 32 + lr;
#pragma unroll
    for (int i = 0; i < 4; ++i)
#pragma unroll
        for (int j = 0; j < 2; ++j)
#pragma unroll
            for (int r = 0; r < 4; ++r)
                atomicAdd(&Cp[(size_t)(crow0 + i * 16 + r) * 64 + ccol0 + j * 16],
                          acc[i][j][r]);
}

// ---------------------------------------------------------------------------
// dt projection (single K-step MFMA): delta[M,1024] = softplus(dbc[:, :32] @
// dtw^T + dtb). K=32 == one 16x16x32 MFMA. dbc f32 cast in staging.
// ---------------------------------------------------------------------------
__global__ __launch_bounds__(256) void dt_bf16(
    const float* __restrict__ A,              // dbc [M][64], cols 0..31
    const unsigned short* __restrict__ W,     // dtwb [1024][32]
    const float* __restrict__ bias,           // dtb [1024]
    float* __restrict__ C)                    // delta [M][1024]
{
    __shared__ unsigned short As[128][32];
    __shared__ unsigned short Ws[128][32];

    const int tid = threadIdx.x;
    const int rowbase = blockIdx.y * 128;
    const int colbase = blockIdx.x * 128;
    const int wave = tid >> 6, lane = tid & 63;
    const int wm = wave >> 1, wn = wave & 1;
    const int lr = lane & 15;
    const int lc = lane >> 4;

    {   // stage both tiles: 2 threads/row, 2 chunks (8 elems) each
        const int r = tid >> 1;
        const int hf = tid & 1;
        const float* ar = A + (size_t)(rowbase + r) * 64;
#pragma unroll
        for (int cc = 0; cc < 2; ++cc) {
            int c = 2 * hf + cc;
            int pc = c ^ ((r >> 1) & 3);
            float4 f0 = *(const float4*)&ar[c * 8];
            float4 f1 = *(const float4*)&ar[c * 8 + 4];
            unsigned short v[8] = {f2bf(f0.x), f2bf(f0.y), f2bf(f0.z), f2bf(f0.w),
                                   f2bf(f1.x), f2bf(f1.y), f2bf(f1.z), f2bf(f1.w)};
            *(uint4*)&As[r][pc << 3] = *(uint4*)v;
            *(uint4*)&Ws[r][pc << 3] =
                *(const uint4*)&W[(size_t)(colbase + r) * 32 + c * 8];
        }
    }
    __syncthreads();

    f32x4 acc[4][4];
#pragma unroll
    for (int i = 0; i < 4; ++i)
#pragma unroll
        for (int j = 0; j < 4; ++j)
            acc[i][j] = (f32x4){0.f, 0.f, 0.f, 0.f};

    bf16x8 af[4], bfv[4];
#pragma unroll
    for (int i = 0; i < 4; ++i) {
        int R = wm * 64 + i * 16 + lr;
        int pc = lc ^ ((R >> 1) & 3);
        af[i] = *(const bf16x8*)&As[R][pc << 3];
    }
#pragma unroll
    for (int j = 0; j < 4; ++j) {
        int R = wn * 64 + j * 16 + lr;
        int pc = lc ^ ((R >> 1) & 3);
        bfv[j] = *(const bf16x8*)&Ws[R][pc << 3];
    }
#pragma unroll
    for (int i = 0; i < 4; ++i)
#pragma unroll
        for (int j = 0; j < 4; ++j)
            acc[i][j] = __builtin_amdgcn_mfma_f32_16x16x32_bf16(
                af[i], bfv[j], acc[i][j], 0, 0, 0);

    const int crow0 = rowbase + wm * 64 + ((lane >> 4) << 2);
    const int ccol0 = colbase + wn * 64 + lr;
#pragma unroll
    for (int j = 0; j < 4; ++j) {
        int col = ccol0 + j * 16;
        float bv = bias[col];
#pragma unroll
        for (int i = 0; i < 4; ++i)
#pragma unroll
            for (int r = 0; r < 4; ++r)
                C[(size_t)(crow0 + i * 16 + r) * EDIM + col] =
                    softplusf(acc[i][j][r] + bv);
    }
}

// ---------------------------------------------------------------------------
// Depthwise causal conv (D_CONV=4) + bias + silu; bf16 input (xi half of xz),
// writes f32 xc + bf16 xcbf.
// ---------------------------------------------------------------------------
__global__ __launch_bounds__(256) void conv_silu(
    const unsigned short* __restrict__ xzb, const float* __restrict__ cw,
    const float* __restrict__ cb, float* __restrict__ xc,
    unsigned short* __restrict__ xcbf)
{
    const int e = threadIdx.x << 2;           // 0..1020
    const int m = blockIdx.x;                 // 0..8191
    const int t = m & (LSEQ - 1);

    float4 w0 = *(const float4*)&cw[e * 4];
    float4 w1 = *(const float4*)&cw[e * 4 + 4];
    float4 w2 = *(const float4*)&cw[e * 4 + 8];
    float4 w3 = *(const float4*)&cw[e * 4 + 12];
    float4 acc = *(const float4*)&cb[e];
#pragma unroll
    for (int k = 0; k < 4; ++k) {
        if (t - 3 + k >= 0) {
            const unsigned short* p = &xzb[(size_t)(m - 3 + k) * 2048 + e];
            uint2 raw = *(const uint2*)p;
            float x0 = bf2f((unsigned short)(raw.x & 0xffff));
            float x1 = bf2f((unsigned short)(raw.x >> 16));
            float x2 = bf2f((unsigned short)(raw.y & 0xffff));
            float x3 = bf2f((unsigned short)(raw.y >> 16));
            acc.x = fmaf((&w0.x)[k], x0, acc.x);
            acc.y = fmaf((&w1.x)[k], x1, acc.y);
            acc.z = fmaf((&w2.x)[k], x2, acc.z);
            acc.w = fmaf((&w3.x)[k], x3, acc.w);
        }
    }
    float4 o;
    o.x = acc.x / (1.f + __expf(-acc.x));
    o.y = acc.y / (1.f + __expf(-acc.y));
    o.z = acc.z / (1.f + __expf(-acc.z));
    o.w = acc.w / (1.f + __expf(-acc.w));
    *(float4*)&xc[(size_t)m * EDIM + e] = o;
    unsigned short b4[4] = {f2bf(o.x), f2bf(o.y), f2bf(o.z), f2bf(o.w)};
    *(uint2*)&xcbf[(size_t)m * EDIM + e] = *(uint2*)b4;
}

// ---------------------------------------------------------------------------
// Chunked selective scan, lane = channel e, 16 states in registers.
// ---------------------------------------------------------------------------
__global__ __launch_bounds__(256) void scan_part1(
    const float* __restrict__ delta, const float* __restrict__ xc,
    const float* __restrict__ dbc, const float* __restrict__ Alog,
    float* __restrict__ Psum, float* __restrict__ Ssum)
{
    __shared__ float sB[CHLEN][16];

    const int b  = blockIdx.y;
    const int ch = blockIdx.z;
    const int tid = threadIdx.x;
    const int e  = blockIdx.x * 256 + tid;
    const int row0 = b * LSEQ + ch * CHLEN;

#pragma unroll
    for (int it = 0; it < 4; ++it) {
        int q = tid + it * 256;
        int t = q >> 4, n = q & 15;
        sB[t][n] = dbc[(size_t)(row0 + t) * 64 + 32 + n];
    }

    float Aen[16];
#pragma unroll
    for (int k = 0; k < 4; ++k) {
        float4 a4 = *(const float4*)&Alog[e * DSTATE + k * 4];
        Aen[k * 4 + 0] = -__expf(a4.x);
        Aen[k * 4 + 1] = -__expf(a4.y);
        Aen[k * 4 + 2] = -__expf(a4.z);
        Aen[k * 4 + 3] = -__expf(a4.w);
    }

    float h[16];
#pragma unroll
    for (int n = 0; n < 16; ++n) h[n] = 0.f;
    float sumd = 0.f;

    __syncthreads();

    const size_t base = (size_t)row0 * EDIM + e;
    float dnx = delta[base];
    float xnx = xc[base];

    for (int t = 0; t < CHLEN; ++t) {
        float d = dnx, xcv = xnx;
        if (t + 1 < CHLEN) {
            dnx = delta[base + (size_t)(t + 1) * EDIM];
            xnx = xc[base + (size_t)(t + 1) * EDIM];
        }
        sumd += d;
        float dx = d * xcv;
        float Bt[16];
        *(float4*)&Bt[0]  = *(const float4*)&sB[t][0];
        *(float4*)&Bt[4]  = *(const float4*)&sB[t][4];
        *(float4*)&Bt[8]  = *(const float4*)&sB[t][8];
        *(float4*)&Bt[12] = *(const float4*)&sB[t][12];
#pragma unroll
        for (int n = 0; n < 16; ++n) {
            float da = __expf(d * Aen[n]);
            h[n] = fmaf(da, h[n], dx * Bt[n]);
        }
    }

    size_t idx = ((size_t)((b * NCH + ch) * EDIM + e)) * DSTATE;
    float P[16];
#pragma unroll
    for (int n = 0; n < 16; ++n) P[n] = __expf(Aen[n] * sumd);
#pragma unroll
    for (int k = 0; k < 4; ++k) {
        *(float4*)&Psum[idx + k * 4] = *(float4*)&P[k * 4];
        *(float4*)&Ssum[idx + k * 4] = *(float4*)&h[k * 4];
    }
}

__global__ __launch_bounds__(256) void scan_combine(
    float* __restrict__ Psum, const float* __restrict__ Ssum)
{
    int i = blockIdx.x * 256 + threadIdx.x;       // 0 .. B*ED*DS-1
    int b = i >> 14;
    int r = i & 16383;                            // e*16+n
    float H = 0.f;
#pragma unroll
    for (int ch = 0; ch < NCH; ++ch) {
        size_t idx = ((size_t)(b * NCH + ch) << 14) + r;
        float p = Psum[idx];
        float s = Ssum[idx];
        Psum[idx] = H;                            // Hstart for this chunk
        H = fmaf(p, H, s);
    }
}

__global__ __launch_bounds__(256) void scan_part2(
    const float* __restrict__ delta, const float* __restrict__ xc,
    const float* __restrict__ dbc, const float* __restrict__ Alog,
    const float* __restrict__ Dvec, const unsigned short* __restrict__ zbuf,
    const float* __restrict__ Hstart, unsigned short* __restrict__ gbf)
{
    __shared__ float sB[CHLEN][16], sC[CHLEN][16];

    const int b  = blockIdx.y;
    const int ch = blockIdx.z;
    const int tid = threadIdx.x;
    const int e  = blockIdx.x * 256 + tid;
    const int row0 = b * LSEQ + ch * CHLEN;

#pragma unroll
    for (int it = 0; it < 8; ++it) {
        int q = tid + it * 256;
        int t = q >> 5, c = q & 31;
        float v = dbc[(size_t)(row0 + t) * 64 + 32 + c];
        if (c < 16) sB[t][c] = v; else sC[t][c - 16] = v;
    }

    float Aen[16];
#pragma unroll
    for (int k = 0; k < 4; ++k) {
        float4 a4 = *(const float4*)&Alog[e * DSTATE + k * 4];
        Aen[k * 4 + 0] = -__expf(a4.x);
        Aen[k * 4 + 1] = -__expf(a4.y);
        Aen[k * 4 + 2] = -__expf(a4.z);
        Aen[k * 4 + 3] = -__expf(a4.w);
    }
    const float Dv = Dvec[e];

    float h[16];
    {
        size_t idx = ((size_t)((b * NCH + ch) * EDIM + e)) * DSTATE;
#pragma unroll
        for (int k = 0; k < 4; ++k)
            *(float4*)&h[k * 4] = *(const float4*)&Hstart[idx + k * 4];
    }

    __syncthreads();

    const size_t base = (size_t)row0 * EDIM + e;
    const size_t zbase = (size_t)row0 * 2048 + 1024 + e;
    float dnx = delta[base];
    float xnx = xc[base];
    float znx = bf2f(zbuf[zbase]);

    for (int t = 0; t < CHLEN; ++t) {
        float d = dnx, xcv = xnx, zv = znx;
        if (t + 1 < CHLEN) {
            dnx = delta[base + (size_t)(t + 1) * EDIM];
            xnx = xc[base + (size_t)(t + 1) * EDIM];
            znx = bf2f(zbuf[zbase + (size_t)(t + 1) * 2048]);
        }
        float dx = d * xcv;
        float Bt[16], Ct[16];
        *(float4*)&Bt[0]  = *(const float4*)&sB[t][0];
        *(float4*)&Bt[4]  = *(const float4*)&sB[t][4];
        *(float4*)&Bt[8]  = *(const float4*)&sB[t][8];
        *(float4*)&Bt[12] = *(const float4*)&sB[t][12];
        *(float4*)&Ct[0]  = *(const float4*)&sC[t][0];
        *(float4*)&Ct[4]  = *(const float4*)&sC[t][4];
        *(float4*)&Ct[8]  = *(const float4*)&sC[t][8];
        *(float4*)&Ct[12] = *(const float4*)&sC[t][12];
        float y = 0.f;
#pragma unroll
        for (int n = 0; n < 16; ++n) {
            float da = __expf(d * Aen[n]);
            h[n] = fmaf(da, h[n], dx * Bt[n]);
            y = fmaf(h[n], Ct[n], y);
        }
        y = fmaf(Dv, xcv, y);
        float sig = 1.f / (1.f + __expf(-zv));
        float zz  = zv * sig;
        gbf[(size_t)(row0 + t) * EDIM + e] = f2bf(fmaf(zz, y - xcv, xcv));
    }
}

// ---------------------------------------------------------------------------
__device__ __forceinline__ void block_reduce4(float4& s, float4* red, int tid)
{
#pragma unroll
    for (int off = 1; off < 64; off <<= 1) {
        s.x += __shfl_xor(s.x, off);
        s.y += __shfl_xor(s.y, off);
        s.z += __shfl_xor(s.z, off);
        s.w += __shfl_xor(s.w, off);
    }
    if ((tid & 63) == 0) red[tid >> 6] = s;
    __syncthreads();
    float4 a = red[0], b = red[1], c = red[2], d = red[3];
    s.x = a.x + b.x + c.x + d.x;
    s.y = a.y + b.y + c.y + d.y;
    s.z = a.z + b.z + c.z + d.z;
    s.w = a.w + b.w + c.w + d.w;
}

__global__ __launch_bounds__(256) void ln_combine(
    const float* __restrict__ yproj, const float* __restrict__ x,
    const float* __restrict__ g1, const float* __restrict__ b1,
    const float* __restrict__ g2, const float* __restrict__ b2,
    float* __restrict__ xs, unsigned short* __restrict__ xsbf)
{
    __shared__ float4 red[4];
    const int row = blockIdx.x, tid = threadIdx.x;
    const float* yf = yproj + (size_t)row * DMODEL;
    const float* yb = yproj + (size_t)(MTOT + row) * DMODEL;
    const float* xr = x + (size_t)row * DMODEL;

    float vf[2], vb[2];
#pragma unroll
    for (int j = 0; j < 2; ++j) {
        int i = tid + j * 256;
        float xi = xr[i];
        vf[j] = yf[i] + xi;
        vb[j] = yb[i] + xi;
    }
    float4 s = make_float4(vf[0] + vf[1], vf[0] * vf[0] + vf[1] * vf[1],
                           vb[0] + vb[1], vb[0] * vb[0] + vb[1] * vb[1]);
    block_reduce4(s, red, tid);
    const float inv = 1.f / DMODEL;
    float mf = s.x * inv, mb = s.z * inv;
    float rf = rsqrtf(s.y * inv - mf * mf + EPSLN);
    float rb = rsqrtf(s.w * inv - mb * mb + EPSLN);
#pragma unroll
    for (int j = 0; j < 2; ++j) {
        int i = tid + j * 256;
        float a  = (vf[j] - mf) * rf * g1[i] + b1[i];
        float bb = (vb[j] - mb) * rb * g2[i] + b2[i];
        float v = a + bb;
        xs[(size_t)row * DMODEL + i] = v;
        xsbf[(size_t)row * DMODEL + i] = f2bf(v);
    }
}

__global__ __launch_bounds__(256) void ln_final(
    const float* __restrict__ h2, const float* __restrict__ xs,
    const float* __restrict__ g3, const float* __restrict__ b3,
    float* __restrict__ out)
{
    __shared__ float4 red[4];
    const int row = blockIdx.x, tid = threadIdx.x;
    float v[2];
#pragma unroll
    for (int j = 0; j < 2; ++j) {
        int i = tid + j * 256;
        v[j] = h2[(size_t)row * DMODEL + i] + xs[(size_t)row * DMODEL + i];
    }
    float4 s = make_float4(v[0] + v[1], v[0] * v[0] + v[1] * v[1], 0.f, 0.f);
    block_reduce4(s, red, tid);
    const float inv = 1.f / DMODEL;
    float m  = s.x * inv;
    float rs = rsqrtf(s.y * inv - m * m + EPSLN);
#pragma unroll
    for (int j = 0; j < 2; ++j) {
        int i = tid + j * 256;
        out[(size_t)row * DMODEL + i] = (v[j] - m) * rs * g3[i] + b3[i];
    }
}

// ---------------------------------------------------------------------------
extern "C" void kernel_launch(void* const* d_in, const int* in_sizes, int n_in,
                              void* d_out, int out_size, void* d_ws, size_t ws_size,
                              hipStream_t stream)
{
    (void)in_sizes; (void)n_in;

    const float* x    = (const float*)d_in[28];
    const float* n1g  = (const float*)d_in[18];
    const float* n1b  = (const float*)d_in[19];
    const float* n2g  = (const float*)d_in[20];
    const float* n2b  = (const float*)d_in[21];
    const float* n3g  = (const float*)d_in[22];
    const float* n3b  = (const float*)d_in[23];
    const float* ff1w = (const float*)d_in[24];
    const float* ff1b = (const float*)d_in[25];
    const float* ff2w = (const float*)d_in[26];
    const float* ff2b = (const float*)d_in[27];

    // Workspace (same validated 178 MB footprint)
    const size_t need_floats =
        (size_t)MTOT * 2048 + (size_t)MTOT * 1024 + (size_t)MTOT * 1024 +
        (size_t)MTOT * 64 + (size_t)2 * MTOT * 512 + (size_t)MTOT * 512;
    if (ws_size < need_floats * sizeof(float)) return;
    if (out_size < MTOT * DMODEL) return;

    float* ws    = (float*)d_ws;
    float* xz    = ws;                          // MTOT*2048 f32 region, reused
    float* xc    = xz    + (size_t)MTOT * 2048; // MTOT*1024
    float* delta = xc    + (size_t)MTOT * 1024; // MTOT*1024
    float* dbc   = delta + (size_t)MTOT * 1024; // MTOT*64
    float* yproj = dbc   + (size_t)MTOT * 64;   // 2*MTOT*512
    float* xs    = yproj + (size_t)2 * MTOT * 512; // MTOT*512

    // xz region now holds TWO bf16 xz buffers [M][2048] (xi|z), one per dir:
    unsigned short* xzf_bf = (unsigned short*)xz;
    unsigned short* xzb_bf = xzf_bf + (size_t)MTOT * 2048;

    // Overlays (lifetime-disjoint):
    unsigned short* xcbf = (unsigned short*)delta;  // conv->xproj, dt clobbers
    unsigned short* gbf  = (unsigned short*)xs;     // scan out, dead til ln_combine
    const size_t SUMN    = (size_t)BATCH * NCH * EDIM * DSTATE;   // 2,097,152
    float* Psum  = yproj + (size_t)MTOT * 512;      // doubles as Hstart
    float* Ssum  = Psum + SUMN;
    unsigned short* xpwb = (unsigned short*)Psum;   // per-dir (64K ush)
    unsigned short* dtwb = xpwb + 65536;            // per-dir (32K ush)
    unsigned short* h1bf = (unsigned short*)delta;
    unsigned short* xsbf = (unsigned short*)(delta + (size_t)MTOT * 512);
    float* h2 = xc;

    // bf16 cast scratch carved from d_out (dead until ln_final): 16MB exact
    unsigned short* ob     = (unsigned short*)d_out;
    unsigned short* xbf    = ob;                        // 4,194,304
    unsigned short* inwf_b = ob + (size_t)4194304;      // 1,048,576
    unsigned short* inwb_b = ob + (size_t)5242880;      // 1,048,576
    unsigned short* outwf_b= ob + (size_t)6291456;      //   524,288
    unsigned short* outwb_b= ob + (size_t)6815744;      //   524,288
    unsigned short* ff1w_b = ob + (size_t)7340032;      //   524,288
    unsigned short* ff2w_b = ob + (size_t)7864320;      //   524,288

    cast_bf16<<<(MTOT * DMODEL / 8 + 255) / 256, 256, 0, stream>>>(x, xbf, MTOT * DMODEL / 8);
    cast_bf16<<<(2048 * 512 / 8 + 255) / 256, 256, 0, stream>>>((const float*)d_in[0], inwf_b, 2048 * 512 / 8);
    cast_bf16<<<(2048 * 512 / 8 + 255) / 256, 256, 0, stream>>>((const float*)d_in[9], inwb_b, 2048 * 512 / 8);
    cast_bf16<<<(512 * 1024 / 8 + 255) / 256, 256, 0, stream>>>((const float*)d_in[8], outwf_b, 512 * 1024 / 8);
    cast_bf16<<<(512 * 1024 / 8 + 255) / 256, 256, 0, stream>>>((const float*)d_in[17], outwb_b, 512 * 1024 / 8);
    cast_bf16<<<(1024 * 512 / 8 + 255) / 256, 256, 0, stream>>>(ff1w, ff1w_b, 1024 * 512 / 8);
    cast_bf16<<<(512 * 1024 / 8 + 255) / 256, 256, 0, stream>>>(ff2w, ff2w_b, 512 * 1024 / 8);

    // Fused dual-direction in-projection (shared A, flipped write for bwd)
    inproj_bf16<<<dim3(4096 / 128, MTOT / 128), 256, 0, stream>>>(
        xbf, inwf_b, inwb_b, xzf_bf, xzb_bf);

    for (int dir = 0; dir < 2; ++dir) {
        const float* cw    = (const float*)d_in[dir * 9 + 1];
        const float* cb    = (const float*)d_in[dir * 9 + 2];
        const float* xpw   = (const float*)d_in[dir * 9 + 3];
        const float* dtw   = (const float*)d_in[dir * 9 + 4];
        const float* dtb   = (const float*)d_in[dir * 9 + 5];
        const float* Alog  = (const float*)d_in[dir * 9 + 6];
        const float* Dvec  = (const float*)d_in[dir * 9 + 7];
        const unsigned short* outw_b = dir ? outwb_b : outwf_b;
        const unsigned short* xz_bf  = dir ? xzb_bf : xzf_bf;

        // xc = silu(conv(xi)+cb)  (+ bf16 copy xcbf)
        conv_silu<<<MTOT, 256, 0, stream>>>(xz_bf, cw, cb, xc, xcbf);
        // dbc = xcbf @ xpw^T   (N=64, K=1024)  [MFMA split-K=4 + atomics]
        cast_bf16<<<(64 * EDIM / 8 + 255) / 256, 256, 0, stream>>>(xpw, xpwb, 64 * EDIM / 8);
        cast_bf16<<<(EDIM * DTRANK / 8 + 255) / 256, 256, 0, stream>>>(dtw, dtwb, EDIM * DTRANK / 8);
        hipMemsetAsync(dbc, 0, (size_t)MTOT * 64 * sizeof(float), stream);
        xproj_bf16<<<dim3(MTOT / 128, 4), 256, 0, stream>>>(xcbf, xpwb, dbc);
        // delta = softplus(dbc[:, :32] @ dtw^T + dtb)  [single K-step MFMA]
        dt_bf16<<<dim3(EDIM / 128, MTOT / 128), 256, 0, stream>>>(
            dbc, dtwb, dtb, delta);
        // chunked parallel scan (16-state-per-lane)
        scan_part1<<<dim3(EDIM / 256, BATCH, NCH), 256, 0, stream>>>(
            delta, xc, dbc, Alog, Psum, Ssum);
        scan_combine<<<(BATCH * EDIM * DSTATE) / 256, 256, 0, stream>>>(
            Psum, Ssum);
        scan_part2<<<dim3(EDIM / 256, BATCH, NCH), 256, 0, stream>>>(
            delta, xc, dbc, Alog, Dvec, xz_bf, Psum, gbf);
        // yproj[dir] = g @ out_w^T   (N=512, K=1024)
        gemm_bf16<<<dim3(512 / 128, MTOT / 128), 256, 0, stream>>>(
            gbf, EDIM, outw_b, nullptr,
            yproj + (size_t)dir * MTOT * DMODEL, DMODEL, 0, EDIM, 0);
    }

    // xs = LN(yf+x)*g1+b1 + LN(yb+x)*g2+b2  (+ bf16 copy)
    ln_combine<<<MTOT, 256, 0, stream>>>(yproj, x, n1g, n1b, n2g, n2b, xs, xsbf);
    // h1bf = relu(xs @ ff1^T + ff1b)
    gemm_bf16<<<dim3(DFF / 128, MTOT / 128), 256, 0, stream>>>(
        xsbf, DMODEL, ff1w_b, ff1b, h1bf, DFF, 1, DMODEL, 1);
    // h2 = h1bf @ ff2^T + ff2b
    gemm_bf16<<<dim3(DMODEL / 128, MTOT / 128), 256, 0, stream>>>(
        h1bf, DFF, ff2w_b, ff2b, h2, DMODEL, 0, DFF, 0);
    // out = LN(h2 + xs)*g3 + b3
    ln_final<<<MTOT, 256, 0, stream>>>(h2, xs, n3g, n3b, (float*)d_out);
}